// Round 11
// baseline (340.304 us; speedup 1.0000x reference)
//
#include <hip/hip_runtime.h>
#include <math.h>

#define NEG_SLOPE 0.2f

typedef __attribute__((ext_vector_type(8))) short bf16x8;
typedef __attribute__((ext_vector_type(4))) float f32x4;
typedef __attribute__((ext_vector_type(8))) unsigned short ushort8;
typedef __attribute__((ext_vector_type(4))) unsigned short ushort4v;

__device__ __forceinline__ float b2f(unsigned short u){
  return __uint_as_float(((unsigned)u) << 16);
}
__device__ __forceinline__ unsigned short f2b(float f){
  unsigned u = __float_as_uint(f);
  return (unsigned short)((u + 0x7FFFu + ((u >> 16) & 1u)) >> 16);
}

// ---------------- init: cnt=1 (self loop) ----------------
extern "C" __global__ void k_init(int N, int* cnt){
  int n = blockIdx.x*blockDim.x + threadIdx.x;
  if(n < N) cnt[n] = 1;
}

// ---------------- CSR build ----------------
extern "C" __global__ void k_count(const int* __restrict__ dsts, int E, int* cnt){
  int e = blockIdx.x*blockDim.x + threadIdx.x;
  if(e >= E) return;
  atomicAdd(&cnt[dsts[e]], 1);
}

extern "C" __global__ void k_scan_partial(const int* __restrict__ cnt, int* part, int N){
  __shared__ int sh[256];
  int t = threadIdx.x, i = blockIdx.x*256 + t;
  sh[t] = (i < N) ? cnt[i] : 0;
  __syncthreads();
  for(int s=128; s>0; s>>=1){
    if(t < s) sh[t] += sh[t+s];
    __syncthreads();
  }
  if(t == 0) part[blockIdx.x] = sh[0];
}

extern "C" __global__ void k_scan_ex(int* part, int NB){
  __shared__ int sh[256];
  int t = threadIdx.x;
  int v = (t < NB) ? part[t] : 0;
  sh[t] = v; __syncthreads();
  for(int s=1; s<256; s<<=1){
    int u = (t >= s) ? sh[t-s] : 0;
    __syncthreads();
    sh[t] += u;
    __syncthreads();
  }
  if(t < NB) part[t] = sh[t] - v;  // exclusive
}

// also writes the scatter cursor (merged k_cursor)
extern "C" __global__ void k_scan_final(const int* __restrict__ cnt, const int* __restrict__ part,
                                        int* offs, int* cur, int N){
  __shared__ int sh[256];
  int t = threadIdx.x, i = blockIdx.x*256 + t;
  int v = (i < N) ? cnt[i] : 0;
  sh[t] = v; __syncthreads();
  for(int s=1; s<256; s<<=1){
    int u = (t >= s) ? sh[t-s] : 0;
    __syncthreads();
    sh[t] += u;
    __syncthreads();
  }
  int ex = part[blockIdx.x] + sh[t] - v;
  if(i < N){ offs[i] = ex; cur[i] = ex; }
  if(i == N-1) offs[N] = ex + v;
}

extern "C" __global__ void k_scatter(const int* __restrict__ srcs, const int* __restrict__ dsts,
                                     int E, int N, int* cur, int* csr){
  int i = blockIdx.x*blockDim.x + threadIdx.x;
  if(i >= E + N) return;
  int s, d;
  if(i < E){ s = srcs[i]; d = dsts[i]; } else { s = d = i - E; }
  int pos = atomicAdd(&cur[d], 1);
  csr[pos] = s;
}

// ---------------- fp32 -> bf16 cast (8 elems/thread) ----------------
extern "C" __global__ void k_cast_x(const float* __restrict__ x, unsigned short* __restrict__ xb, int n8){
  int i = blockIdx.x*blockDim.x + threadIdx.x;
  if(i >= n8) return;
  const float4* p = (const float4*)(x + (size_t)i*8);
  float4 v0 = p[0], v1 = p[1];
  ushort8 o;
  o[0]=f2b(v0.x); o[1]=f2b(v0.y); o[2]=f2b(v0.z); o[3]=f2b(v0.w);
  o[4]=f2b(v1.x); o[5]=f2b(v1.y); o[6]=f2b(v1.z); o[7]=f2b(v1.w);
  *(ushort8*)(xb + (size_t)i*8) = o;
}

// ---------------- weight transpose+concat (both layers, one launch) ----------------
extern "C" __global__ void k_wt2(const float* __restrict__ W0, const float* __restrict__ Wr0,
                                 const float* __restrict__ W1, const float* __restrict__ Wr1,
                                 unsigned short* __restrict__ WT0, unsigned short* __restrict__ WT1){
  int idx = blockIdx.x*256 + threadIdx.x;
  const int tot0 = 512*256;
  if(idx < tot0){
    int n = idx >> 8, k = idx & 255;
    const float* W = (n < 256) ? W0 : Wr0;
    int c = (n < 256) ? n : n - 256;
    WT0[idx] = f2b(W[(size_t)k*256 + c]);
  } else {
    idx -= tot0;
    if(idx >= 128*256) return;
    int n = idx >> 8, k = idx & 255;
    const float* W = (n < 64) ? W1 : Wr1;
    int c = (n < 64) ? n : n - 64;
    WT1[idx] = f2b(W[(size_t)k*64 + c]);
  }
}

// ---------------- bf16 MFMA GEMM: C[M][NC] = A[M][256] @ WT[NC][256]^T ----------------
// 1-D grid; for NCB=4 the 4 col-blocks of a row-tile get linear ids differing by 8
// (same XCD under round-robin dispatch) so the shared A tile stays in that XCD's L2.
__launch_bounds__(256)
extern "C" __global__ void k_mgemm(const unsigned short* __restrict__ A,
                                   const unsigned short* __restrict__ WT,
                                   unsigned short* __restrict__ C, int ldc, int M,
                                   int MB, int NCB){
  int id = blockIdx.x;
  int row_blk, col_blk;
  if(NCB == 4){
    int group = id >> 5;            // 32 blocks = 8 row-tiles x 4 col-tiles
    int r8 = id & 7;
    col_blk = (id >> 3) & 3;
    row_blk = group*8 + r8;
  } else {
    row_blk = id; col_blk = 0;
  }
  if(row_blk >= MB) return;

  __shared__ unsigned short As[128*64];
  __shared__ unsigned short Bs[128*64];
  int t = threadIdx.x;
  int lane = t & 63, wid = t >> 6;
  int wr = wid >> 1, wc = wid & 1;
  int row0 = row_blk*128, col0 = col_blk*128;
  f32x4 acc[4][4] = {};

  for(int k0 = 0; k0 < 256; k0 += 64){
    #pragma unroll
    for(int i=0; i<4; i++){
      int t2 = i*256 + t;
      int r = t2 >> 3;
      int dslot = (t2 & 7) ^ (r & 7);
      int gr = row0 + r; if(gr >= M) gr = M - 1;
      const unsigned short* ga = A + (size_t)gr*256 + k0 + dslot*8;
      __builtin_amdgcn_global_load_lds((const __attribute__((address_space(1))) unsigned*)ga,
          (__attribute__((address_space(3))) unsigned*)(As + i*2048 + wid*512), 16, 0, 0);
      const unsigned short* gb = WT + (size_t)(col0 + r)*256 + k0 + dslot*8;
      __builtin_amdgcn_global_load_lds((const __attribute__((address_space(1))) unsigned*)gb,
          (__attribute__((address_space(3))) unsigned*)(Bs + i*2048 + wid*512), 16, 0, 0);
    }
    __syncthreads();
    #pragma unroll
    for(int kc=0; kc<2; kc++){
      bf16x8 a[4], b[4];
      int kb = kc*4 + (lane >> 4);
      #pragma unroll
      for(int f=0; f<4; f++){
        int ar = wr*64 + f*16 + (lane & 15);
        a[f] = *(const bf16x8*)&As[ar*64 + ((kb ^ (ar & 7))*8)];
        int br = wc*64 + f*16 + (lane & 15);
        b[f] = *(const bf16x8*)&Bs[br*64 + ((kb ^ (br & 7))*8)];
      }
      #pragma unroll
      for(int fm=0; fm<4; fm++)
        #pragma unroll
        for(int fn=0; fn<4; fn++)
          acc[fm][fn] = __builtin_amdgcn_mfma_f32_16x16x32_bf16(a[fm], b[fn], acc[fm][fn], 0, 0, 0);
    }
    __syncthreads();
  }

  int rb = row0 + wr*64 + ((lane >> 4) << 2);
  int cb = col0 + wc*64 + (lane & 15);
  #pragma unroll
  for(int fm=0; fm<4; fm++){
    #pragma unroll
    for(int r=0; r<4; r++){
      int row = rb + fm*16 + r;
      if(row < M){
        #pragma unroll
        for(int fn=0; fn<4; fn++)
          C[(size_t)row*ldc + cb + fn*16] = f2b(acc[fm][fn][r]);
      }
    }
  }
}

// ---------------- attention logits layer0 (bf16 h0) ----------------
extern "C" __global__ void k_al0(const unsigned short* __restrict__ buf0b, const float* __restrict__ as0,
                                 const float* __restrict__ ad0, float* als0, float* ald0, int N){
  int i = blockIdx.x*blockDim.x + threadIdx.x;   // n*8+h
  if(i >= N*8) return;
  int n = i >> 3, h = i & 7;
  const uint4* hp = (const uint4*)(buf0b + (size_t)n*512 + h*32);
  const float* av = as0 + h*32;
  const float* dv = ad0 + h*32;
  float s = 0.f, d = 0.f;
  #pragma unroll
  for(int q=0; q<4; q++){
    uint4 u = hp[q];
    unsigned w[4] = {u.x, u.y, u.z, u.w};
    #pragma unroll
    for(int j=0; j<4; j++){
      float lo = __uint_as_float(w[j] << 16);
      float hi = __uint_as_float(w[j] & 0xFFFF0000u);
      int c = q*8 + j*2;
      s += lo*av[c] + hi*av[c+1];
      d += lo*dv[c] + hi*dv[c+1];
    }
  }
  als0[i] = s; ald0[i] = d;
}

// ---- gather layer0: fused LDS-alpha (chunked) + 8-wide MLP weighted gather ----
// block per node; lane owns channels c=lane*4..lane*4+3, head h=lane>>3.
// No max subtraction: logits are O(+-10) (unit-variance tensors), exp fp32-safe,
// softmax shift-invariant.
#define CH 64
__launch_bounds__(256)
extern "C" __global__ void k_gather0(const unsigned short* __restrict__ buf0b,
                                     const float* __restrict__ als0, const float* __restrict__ ald0,
                                     const int* __restrict__ offs, const int* __restrict__ csr,
                                     const float* __restrict__ b0, const float* __restrict__ br0,
                                     unsigned short* __restrict__ h1b, int N){
  __shared__ float s_alpha[CH][8];
  __shared__ int   s_src[CH];
  __shared__ float s_den[8];
  __shared__ float4 smv[3][64];
  int n = blockIdx.x;
  int t = threadIdx.x;
  int lane = t & 63, w = t >> 6;
  int h = lane >> 3;
  int c = lane*4;
  int beg = offs[n], end = offs[n+1];
  int hh = t & 7;                       // head this thread computes alpha for
  float ald_n = ald0[n*8 + hh];

  if(t < 8) s_den[t] = 0.f;

  float a0=0.f, a1=0.f, a2=0.f, a3=0.f;

  for(int chunk = beg; chunk < end; chunk += CH){
    int m = end - chunk; if(m > CH) m = CH;
    __syncthreads();                    // den-init visible / prev phase B done
    // phase A: alpha for m edges x 8 heads (each computed exactly once)
    float dpart = 0.f;
    for(int idx = t; idx < m*8; idx += 256){
      int e = idx >> 3;
      int s = csr[chunk + e];
      if(hh == 0) s_src[e] = s;
      float v = als0[s*8 + hh] + ald_n;
      v = v > 0.f ? v : NEG_SLOPE*v;
      float p = expf(v);
      s_alpha[e][hh] = p;
      dpart += p;
    }
    // sum over lanes sharing hh within the wave (lanes l, l^8, l^16, l^32)
    dpart += __shfl_xor(dpart, 8);
    dpart += __shfl_xor(dpart, 16);
    dpart += __shfl_xor(dpart, 32);
    if(lane < 8) atomicAdd(&s_den[lane], dpart);   // 8 atomics per wave
    __syncthreads();
    // phase B: 8 edges per wave-iteration, all loads issued before the FMAs
    for(int base = w*8; base < m; base += 32){
      int sv[8]; float pv[8];
      #pragma unroll
      for(int i=0; i<8; i++){
        int e = base + i;
        bool ok = e < m;
        sv[i] = ok ? s_src[e] : s_src[base];
        pv[i] = ok ? s_alpha[e][h] : 0.f;
      }
      uint2 uv[8];
      #pragma unroll
      for(int i=0; i<8; i++)
        uv[i] = *(const uint2*)(buf0b + (size_t)sv[i]*512 + c);
      #pragma unroll
      for(int i=0; i<8; i++){
        a0 = fmaf(pv[i], __uint_as_float(uv[i].x << 16),         a0);
        a1 = fmaf(pv[i], __uint_as_float(uv[i].x & 0xFFFF0000u), a1);
        a2 = fmaf(pv[i], __uint_as_float(uv[i].y << 16),         a2);
        a3 = fmaf(pv[i], __uint_as_float(uv[i].y & 0xFFFF0000u), a3);
      }
    }
  }

  if(w != 0){
    float4 v; v.x=a0; v.y=a1; v.z=a2; v.w=a3;
    smv[w-1][lane] = v;
  }
  __syncthreads();
  if(w != 0) return;
  #pragma unroll
  for(int jj=0; jj<3; jj++){
    float4 v = smv[jj][lane];
    a0 += v.x; a1 += v.y; a2 += v.z; a3 += v.w;
  }
  float rden = 1.f/(s_den[h] + 1e-16f);
  a0 *= rden; a1 *= rden; a2 *= rden; a3 *= rden;

  float4 bb = *(const float4*)(b0 + c);
  float4 rb = *(const float4*)(br0 + c);
  uint2 ru = *(const uint2*)(buf0b + (size_t)n*512 + 256 + c);
  float o0 = a0 + bb.x + __uint_as_float(ru.x << 16)         + rb.x;
  float o1 = a1 + bb.y + __uint_as_float(ru.x & 0xFFFF0000u) + rb.y;
  float o2 = a2 + bb.z + __uint_as_float(ru.y << 16)         + rb.z;
  float o3 = a3 + bb.w + __uint_as_float(ru.y & 0xFFFF0000u) + rb.w;
  ushort4v o;
  o[0] = f2b(o0 > 0.f ? o0 : expf(o0) - 1.f);
  o[1] = f2b(o1 > 0.f ? o1 : expf(o1) - 1.f);
  o[2] = f2b(o2 > 0.f ? o2 : expf(o2) - 1.f);
  o[3] = f2b(o3 > 0.f ? o3 : expf(o3) - 1.f);
  *(ushort4v*)(h1b + (size_t)n*256 + c) = o;
}

// ---------------- layer1 logits (bf16 g1) ----------------
extern "C" __global__ void k_al1(const unsigned short* __restrict__ buf1b, const float* __restrict__ as1,
                                 const float* __restrict__ ad1, float* als1, float* ald1, int N){
  int n = blockIdx.x*4 + (threadIdx.x >> 6);
  if(n >= N) return;
  int lane = threadIdx.x & 63;
  float g = b2f(buf1b[(size_t)n*128 + lane]);
  float s = g*as1[lane], d = g*ad1[lane];
  #pragma unroll
  for(int o=32; o>0; o>>=1){ s += __shfl_xor(s,o); d += __shfl_xor(d,o); }
  if(lane == 0){ als1[n] = s; ald1[n] = d; }
}

// ---- gather layer1: fused LDS-alpha + 8-wide gather + bias + residual + log_softmax ----
__launch_bounds__(256)
extern "C" __global__ void k_gather1(const unsigned short* __restrict__ buf1b,
                                     const float* __restrict__ als1, const float* __restrict__ ald1,
                                     const int* __restrict__ offs, const int* __restrict__ csr,
                                     const float* __restrict__ b1, const float* __restrict__ br1,
                                     float* __restrict__ out, int N){
  __shared__ float s_alpha[CH];
  __shared__ int   s_src[CH];
  __shared__ float s_den[1];
  __shared__ float smv[3][64];
  int n = blockIdx.x;
  int t = threadIdx.x;
  int lane = t & 63, w = t >> 6;
  int beg = offs[n], end = offs[n+1];
  float ald_n = ald1[n];

  if(t == 0) s_den[0] = 0.f;

  float acc = 0.f;

  for(int chunk = beg; chunk < end; chunk += CH){
    int m = end - chunk; if(m > CH) m = CH;
    __syncthreads();
    float dpart = 0.f;
    if(t < m){
      int s = csr[chunk + t];
      s_src[t] = s;
      float v = als1[s] + ald_n;
      v = v > 0.f ? v : NEG_SLOPE*v;
      float p = expf(v);
      s_alpha[t] = p;
      dpart = p;
    }
    #pragma unroll
    for(int o=32; o>0; o>>=1) dpart += __shfl_xor(dpart, o);
    if(lane == 0 && w == 0) atomicAdd(&s_den[0], dpart);
    __syncthreads();
    for(int base = w*8; base < m; base += 32){
      int sv[8]; float pv[8];
      #pragma unroll
      for(int i=0; i<8; i++){
        int e = base + i;
        bool ok = e < m;
        sv[i] = ok ? s_src[e] : s_src[base];
        pv[i] = ok ? s_alpha[e] : 0.f;
      }
      unsigned short fv[8];
      #pragma unroll
      for(int i=0; i<8; i++)
        fv[i] = buf1b[(size_t)sv[i]*128 + lane];
      #pragma unroll
      for(int i=0; i<8; i++)
        acc = fmaf(pv[i], b2f(fv[i]), acc);
    }
  }

  if(w != 0) smv[w-1][lane] = acc;
  __syncthreads();
  if(w != 0) return;
  #pragma unroll
  for(int jj=0; jj<3; jj++) acc += smv[jj][lane];
  acc *= 1.f/(s_den[0] + 1e-16f);

  float val = acc + b1[lane] + b2f(buf1b[(size_t)n*128 + 64 + lane]) + br1[lane];
  float mx = val;
  #pragma unroll
  for(int o=32; o>0; o>>=1) mx = fmaxf(mx, __shfl_xor(mx,o));
  float ex = expf(val - mx), smn = ex;
  #pragma unroll
  for(int o=32; o>0; o>>=1) smn += __shfl_xor(smn,o);
  out[(size_t)n*64 + lane] = val - mx - logf(smn);
}

// ---------------- launch ----------------
extern "C" void kernel_launch(void* const* d_in, const int* in_sizes, int n_in,
                              void* d_out, int out_size, void* d_ws, size_t ws_size,
                              hipStream_t stream){
  const float* x   = (const float*)d_in[0];
  const int*   ei  = (const int*)  d_in[1];
  const float* W0  = (const float*)d_in[2];
  const float* as0 = (const float*)d_in[3];
  const float* ad0 = (const float*)d_in[4];
  const float* b0  = (const float*)d_in[5];
  const float* Wr0 = (const float*)d_in[6];
  const float* br0 = (const float*)d_in[7];
  const float* W1  = (const float*)d_in[8];
  const float* as1 = (const float*)d_in[9];
  const float* ad1 = (const float*)d_in[10];
  const float* b1  = (const float*)d_in[11];
  const float* Wr1 = (const float*)d_in[12];
  const float* br1 = (const float*)d_in[13];
  int N = in_sizes[0] / 256;
  int E = in_sizes[1] / 2;
  const int* srcs = ei;
  const int* dsts = ei + E;
  float* out = (float*)d_out;

  // workspace layout (bf16 feature buffers)
  unsigned short* buf0b = (unsigned short*)d_ws;        // N*512 bf16 (h0 | r0)
  unsigned short* xb    = buf0b + (size_t)N*512;        // N*256 bf16 (dead after mgemm0)
  unsigned short* h1b   = xb    + (size_t)N*256;        // N*256 bf16
  unsigned short* buf1b = h1b   + (size_t)N*256;        // N*128 bf16 (g1 | r1)
  unsigned short* WT0   = buf1b + (size_t)N*128;        // 512*256 bf16
  unsigned short* WT1   = WT0   + 512*256;              // 128*256 bf16
  float*    als0 = (float*)(WT1 + 128*256);             // N*8
  float*    ald0 = als0 + (size_t)N*8;                  // N*8
  float*    als1 = ald0 + (size_t)N*8;                  // N
  float*    ald1 = als1 + N;                            // N
  int*      cnt  = (int*)(ald1 + N);                    // N (also cursor)
  int*      offs = cnt + N;                             // N+1
  int*      part = offs + N + 1;                        // 256
  int*      csr  = part + 256;                          // E+N

  int NB = (N + 255) / 256;
  int ET = E + N;

  // CSR build
  hipLaunchKernelGGL(k_init, dim3((N+255)/256), dim3(256), 0, stream, N, cnt);
  hipLaunchKernelGGL(k_count, dim3((E+255)/256), dim3(256), 0, stream, dsts, E, cnt);
  hipLaunchKernelGGL(k_scan_partial, dim3(NB), dim3(256), 0, stream, cnt, part, N);
  hipLaunchKernelGGL(k_scan_ex, dim3(1), dim3(256), 0, stream, part, NB);
  hipLaunchKernelGGL(k_scan_final, dim3(NB), dim3(256), 0, stream, cnt, part, offs, cnt, N);
  hipLaunchKernelGGL(k_scatter, dim3((ET+255)/256), dim3(256), 0, stream, srcs, dsts, E, N, cnt, csr);

  // casts / weight prep
  int n8 = N*256/8;
  hipLaunchKernelGGL(k_cast_x, dim3((n8+255)/256), dim3(256), 0, stream, x, xb, n8);
  hipLaunchKernelGGL(k_wt2, dim3((512*256+128*256+255)/256), dim3(256), 0, stream, W0, Wr0, W1, Wr1, WT0, WT1);

  int MB = (N + 127) / 128;
  int g0 = ((MB + 7) / 8) * 32;
  // layer0: buf0b[N][512] = xb @ [W0|Wr0]
  hipLaunchKernelGGL(k_mgemm, dim3(g0), dim3(256), 0, stream, xb, WT0, buf0b, 512, N, MB, 4);
  hipLaunchKernelGGL(k_al0, dim3((N*8+255)/256), dim3(256), 0, stream, buf0b, as0, ad0, als0, ald0, N);
  hipLaunchKernelGGL(k_gather0, dim3(N), dim3(256), 0, stream, buf0b, als0, ald0, offs, csr, b0, br0, h1b, N);

  // layer1: buf1b[N][128] = h1b @ [W1|Wr1]
  hipLaunchKernelGGL(k_mgemm, dim3(MB), dim3(256), 0, stream, h1b, WT1, buf1b, 128, N, MB, 1);
  hipLaunchKernelGGL(k_al1, dim3((N+3)/4), dim3(256), 0, stream, buf1b, as1, ad1, als1, ald1, N);
  hipLaunchKernelGGL(k_gather1, dim3(N), dim3(256), 0, stream, buf1b, als1, ald1, offs, csr, b1, br1, out, N);
}

// Round 13
// 335.197 us; speedup vs baseline: 1.0152x; 1.0152x over previous
//
#include <hip/hip_runtime.h>
#include <math.h>

#define NEG_SLOPE 0.2f

typedef __attribute__((ext_vector_type(8))) short bf16x8;
typedef __attribute__((ext_vector_type(4))) float f32x4;
typedef __attribute__((ext_vector_type(2))) float f32x2;
typedef __attribute__((ext_vector_type(8))) unsigned short ushort8;
typedef __attribute__((ext_vector_type(4))) unsigned short ushort4v;

__device__ __forceinline__ float b2f(unsigned short u){
  return __uint_as_float(((unsigned)u) << 16);
}
__device__ __forceinline__ unsigned short f2b(float f){
  unsigned u = __float_as_uint(f);
  return (unsigned short)((u + 0x7FFFu + ((u >> 16) & 1u)) >> 16);
}

// ---- fp8 e4m3fn helpers (hardware cvt if available, bit-twiddle fallback) ----
#if __has_builtin(__builtin_amdgcn_cvt_pk_f32_fp8) && __has_builtin(__builtin_amdgcn_cvt_pk_fp8_f32)
#define HW_FP8 1
#else
#define HW_FP8 0
#endif

#if !HW_FP8
__device__ __forceinline__ unsigned enc8_one(float f){
  unsigned bits = __float_as_uint(f);
  unsigned s = bits >> 31;
  unsigned e = (bits >> 23) & 255;
  unsigned mant = bits & 0x7FFFFF;
  if(e < 121){                       // subnormal e4m3 (|f| < 2^-6)
    float af = fabsf(f);
    int m = (int)(af * 512.f + 0.5f);
    if(m > 7) m = 7;
    return (s << 7) | (unsigned)m;
  }
  unsigned lsb = (mant >> 20) & 1;
  mant += 0x7FFFF + lsb;
  if(mant >> 23){ e += 1; mant = 0; }
  unsigned m3 = mant >> 20;
  unsigned e8 = e - 120;
  if(e8 > 15 || (e8 == 15 && m3 == 7)) return (s << 7) | 0x7E;  // sat 448
  return (s << 7) | (e8 << 3) | m3;
}
#endif

template<bool HI>
__device__ __forceinline__ unsigned enc8_pair(float a, float b, unsigned old){
#if HW_FP8
  return __builtin_amdgcn_cvt_pk_fp8_f32(a, b, old, HI);  // HI is a literal here
#else
  unsigned p = enc8_one(a) | (enc8_one(b) << 8);
  return HI ? ((old & 0x0000FFFFu) | (p << 16)) : ((old & 0xFFFF0000u) | p);
#endif
}

__device__ __forceinline__ void dec8x4(unsigned q, float& f0, float& f1, float& f2, float& f3){
#if HW_FP8
  f32x2 lo = __builtin_amdgcn_cvt_pk_f32_fp8(q, false);
  f32x2 hi = __builtin_amdgcn_cvt_pk_f32_fp8(q, true);
  f0 = lo[0]; f1 = lo[1]; f2 = hi[0]; f3 = hi[1];
#else
  auto dec1 = [](unsigned b)->float{
    unsigned s = (b >> 7) & 1, e = (b >> 3) & 15, m = b & 7;
    float v = (e == 0) ? (float)m * 0.001953125f
                       : __uint_as_float(((e + 120) << 23) | (m << 20));
    return s ? -v : v;
  };
  f0 = dec1(q & 255); f1 = dec1((q >> 8) & 255);
  f2 = dec1((q >> 16) & 255); f3 = dec1(q >> 24);
#endif
}

// ---------------- init: cnt=1 (self loop) ----------------
extern "C" __global__ void k_init(int N, int* cnt){
  int n = blockIdx.x*blockDim.x + threadIdx.x;
  if(n < N) cnt[n] = 1;
}

// ---------------- CSR build ----------------
extern "C" __global__ void k_count(const int* __restrict__ dsts, int E, int* cnt){
  int e = blockIdx.x*blockDim.x + threadIdx.x;
  if(e >= E) return;
  atomicAdd(&cnt[dsts[e]], 1);
}

extern "C" __global__ void k_scan_partial(const int* __restrict__ cnt, int* part, int N){
  __shared__ int sh[256];
  int t = threadIdx.x, i = blockIdx.x*256 + t;
  sh[t] = (i < N) ? cnt[i] : 0;
  __syncthreads();
  for(int s=128; s>0; s>>=1){
    if(t < s) sh[t] += sh[t+s];
    __syncthreads();
  }
  if(t == 0) part[blockIdx.x] = sh[0];
}

extern "C" __global__ void k_scan_ex(int* part, int NB){
  __shared__ int sh[256];
  int t = threadIdx.x;
  int v = (t < NB) ? part[t] : 0;
  sh[t] = v; __syncthreads();
  for(int s=1; s<256; s<<=1){
    int u = (t >= s) ? sh[t-s] : 0;
    __syncthreads();
    sh[t] += u;
    __syncthreads();
  }
  if(t < NB) part[t] = sh[t] - v;  // exclusive
}

// also writes the scatter cursor (merged k_cursor)
extern "C" __global__ void k_scan_final(const int* __restrict__ cnt, const int* __restrict__ part,
                                        int* offs, int* cur, int N){
  __shared__ int sh[256];
  int t = threadIdx.x, i = blockIdx.x*256 + t;
  int v = (i < N) ? cnt[i] : 0;
  sh[t] = v; __syncthreads();
  for(int s=1; s<256; s<<=1){
    int u = (t >= s) ? sh[t-s] : 0;
    __syncthreads();
    sh[t] += u;
    __syncthreads();
  }
  int ex = part[blockIdx.x] + sh[t] - v;
  if(i < N){ offs[i] = ex; cur[i] = ex; }
  if(i == N-1) offs[N] = ex + v;
}

extern "C" __global__ void k_scatter(const int* __restrict__ srcs, const int* __restrict__ dsts,
                                     int E, int N, int* cur, int* csr){
  int i = blockIdx.x*blockDim.x + threadIdx.x;
  if(i >= E + N) return;
  int s, d;
  if(i < E){ s = srcs[i]; d = dsts[i]; } else { s = d = i - E; }
  int pos = atomicAdd(&cur[d], 1);
  csr[pos] = s;
}

// ---------------- fp32 -> bf16 cast (8 elems/thread) ----------------
extern "C" __global__ void k_cast_x(const float* __restrict__ x, unsigned short* __restrict__ xb, int n8){
  int i = blockIdx.x*blockDim.x + threadIdx.x;
  if(i >= n8) return;
  const float4* p = (const float4*)(x + (size_t)i*8);
  float4 v0 = p[0], v1 = p[1];
  ushort8 o;
  o[0]=f2b(v0.x); o[1]=f2b(v0.y); o[2]=f2b(v0.z); o[3]=f2b(v0.w);
  o[4]=f2b(v1.x); o[5]=f2b(v1.y); o[6]=f2b(v1.z); o[7]=f2b(v1.w);
  *(ushort8*)(xb + (size_t)i*8) = o;
}

// ---------------- h0 bf16 -> fp8 copy for the gather feature stream ----------------
// thread handles 8 channels: reads uint4 (8 bf16) writes uint2 (8 fp8)
extern "C" __global__ void k_cast8(const unsigned short* __restrict__ buf0b,
                                   unsigned char* __restrict__ h0q, int n8){
  int i = blockIdx.x*blockDim.x + threadIdx.x;
  if(i >= n8) return;
  int i8 = i*8;
  int n = i8 >> 8, c = i8 & 255;
  uint4 u = *(const uint4*)(buf0b + (size_t)n*512 + c);
  float f0 = __uint_as_float(u.x << 16), f1 = __uint_as_float(u.x & 0xFFFF0000u);
  float f2 = __uint_as_float(u.y << 16), f3 = __uint_as_float(u.y & 0xFFFF0000u);
  float f4 = __uint_as_float(u.z << 16), f5 = __uint_as_float(u.z & 0xFFFF0000u);
  float f6 = __uint_as_float(u.w << 16), f7 = __uint_as_float(u.w & 0xFFFF0000u);
  uint2 o;
  o.x = enc8_pair<false>(f0, f1, 0); o.x = enc8_pair<true>(f2, f3, o.x);
  o.y = enc8_pair<false>(f4, f5, 0); o.y = enc8_pair<true>(f6, f7, o.y);
  *(uint2*)(h0q + (size_t)n*256 + c) = o;
}

// ---------------- weight transpose+concat (both layers, one launch) ----------------
extern "C" __global__ void k_wt2(const float* __restrict__ W0, const float* __restrict__ Wr0,
                                 const float* __restrict__ W1, const float* __restrict__ Wr1,
                                 unsigned short* __restrict__ WT0, unsigned short* __restrict__ WT1){
  int idx = blockIdx.x*256 + threadIdx.x;
  const int tot0 = 512*256;
  if(idx < tot0){
    int n = idx >> 8, k = idx & 255;
    const float* W = (n < 256) ? W0 : Wr0;
    int c = (n < 256) ? n : n - 256;
    WT0[idx] = f2b(W[(size_t)k*256 + c]);
  } else {
    idx -= tot0;
    if(idx >= 128*256) return;
    int n = idx >> 8, k = idx & 255;
    const float* W = (n < 64) ? W1 : Wr1;
    int c = (n < 64) ? n : n - 64;
    WT1[idx] = f2b(W[(size_t)k*64 + c]);
  }
}

// ---------------- bf16 MFMA GEMM: C[M][NC] = A[M][256] @ WT[NC][256]^T ----------------
// 1-D grid; for NCB=4 the 4 col-blocks of a row-tile get linear ids differing by 8
// (same XCD under round-robin dispatch) so the shared A tile stays in that XCD's L2.
__launch_bounds__(256)
extern "C" __global__ void k_mgemm(const unsigned short* __restrict__ A,
                                   const unsigned short* __restrict__ WT,
                                   unsigned short* __restrict__ C, int ldc, int M,
                                   int MB, int NCB){
  int id = blockIdx.x;
  int row_blk, col_blk;
  if(NCB == 4){
    int group = id >> 5;            // 32 blocks = 8 row-tiles x 4 col-tiles
    int r8 = id & 7;
    col_blk = (id >> 3) & 3;
    row_blk = group*8 + r8;
  } else {
    row_blk = id; col_blk = 0;
  }
  if(row_blk >= MB) return;

  __shared__ unsigned short As[128*64];
  __shared__ unsigned short Bs[128*64];
  int t = threadIdx.x;
  int lane = t & 63, wid = t >> 6;
  int wr = wid >> 1, wc = wid & 1;
  int row0 = row_blk*128, col0 = col_blk*128;
  f32x4 acc[4][4] = {};

  for(int k0 = 0; k0 < 256; k0 += 64){
    #pragma unroll
    for(int i=0; i<4; i++){
      int t2 = i*256 + t;
      int r = t2 >> 3;
      int dslot = (t2 & 7) ^ (r & 7);
      int gr = row0 + r; if(gr >= M) gr = M - 1;
      const unsigned short* ga = A + (size_t)gr*256 + k0 + dslot*8;
      __builtin_amdgcn_global_load_lds((const __attribute__((address_space(1))) unsigned*)ga,
          (__attribute__((address_space(3))) unsigned*)(As + i*2048 + wid*512), 16, 0, 0);
      const unsigned short* gb = WT + (size_t)(col0 + r)*256 + k0 + dslot*8;
      __builtin_amdgcn_global_load_lds((const __attribute__((address_space(1))) unsigned*)gb,
          (__attribute__((address_space(3))) unsigned*)(Bs + i*2048 + wid*512), 16, 0, 0);
    }
    __syncthreads();
    #pragma unroll
    for(int kc=0; kc<2; kc++){
      bf16x8 a[4], b[4];
      int kb = kc*4 + (lane >> 4);
      #pragma unroll
      for(int f=0; f<4; f++){
        int ar = wr*64 + f*16 + (lane & 15);
        a[f] = *(const bf16x8*)&As[ar*64 + ((kb ^ (ar & 7))*8)];
        int br = wc*64 + f*16 + (lane & 15);
        b[f] = *(const bf16x8*)&Bs[br*64 + ((kb ^ (br & 7))*8)];
      }
      #pragma unroll
      for(int fm=0; fm<4; fm++)
        #pragma unroll
        for(int fn=0; fn<4; fn++)
          acc[fm][fn] = __builtin_amdgcn_mfma_f32_16x16x32_bf16(a[fm], b[fn], acc[fm][fn], 0, 0, 0);
    }
    __syncthreads();
  }

  int rb = row0 + wr*64 + ((lane >> 4) << 2);
  int cb = col0 + wc*64 + (lane & 15);
  #pragma unroll
  for(int fm=0; fm<4; fm++){
    #pragma unroll
    for(int r=0; r<4; r++){
      int row = rb + fm*16 + r;
      if(row < M){
        #pragma unroll
        for(int fn=0; fn<4; fn++)
          C[(size_t)row*ldc + cb + fn*16] = f2b(acc[fm][fn][r]);
      }
    }
  }
}

// ---------------- attention logits layer0 (bf16 h0) ----------------
extern "C" __global__ void k_al0(const unsigned short* __restrict__ buf0b, const float* __restrict__ as0,
                                 const float* __restrict__ ad0, float* als0, float* ald0, int N){
  int i = blockIdx.x*blockDim.x + threadIdx.x;   // n*8+h
  if(i >= N*8) return;
  int n = i >> 3, h = i & 7;
  const uint4* hp = (const uint4*)(buf0b + (size_t)n*512 + h*32);
  const float* av = as0 + h*32;
  const float* dv = ad0 + h*32;
  float s = 0.f, d = 0.f;
  #pragma unroll
  for(int q=0; q<4; q++){
    uint4 u = hp[q];
    unsigned w[4] = {u.x, u.y, u.z, u.w};
    #pragma unroll
    for(int j=0; j<4; j++){
      float lo = __uint_as_float(w[j] << 16);
      float hi = __uint_as_float(w[j] & 0xFFFF0000u);
      int c = q*8 + j*2;
      s += lo*av[c] + hi*av[c+1];
      d += lo*dv[c] + hi*dv[c+1];
    }
  }
  als0[i] = s; ald0[i] = d;
}

// ---- gather layer0: fused LDS-alpha (chunked) + 4-wide gather over fp8 features ----
// block per node; lane owns channels c=lane*4..lane*4+3, head h=lane>>3.
// No max subtraction: logits are O(+-10) (unit-variance tensors), exp fp32-safe,
// softmax shift-invariant.
#define CH 64
__launch_bounds__(256)
extern "C" __global__ void k_gather0(const unsigned short* __restrict__ buf0b,
                                     const unsigned char* __restrict__ h0q,
                                     const float* __restrict__ als0, const float* __restrict__ ald0,
                                     const int* __restrict__ offs, const int* __restrict__ csr,
                                     const float* __restrict__ b0, const float* __restrict__ br0,
                                     unsigned short* __restrict__ h1b, int N){
  __shared__ float s_alpha[CH][8];
  __shared__ int   s_src[CH];
  __shared__ float s_den[8];
  __shared__ float4 smv[3][64];
  int n = blockIdx.x;
  int t = threadIdx.x;
  int lane = t & 63, w = t >> 6;
  int h = lane >> 3;
  int c = lane*4;
  int beg = offs[n], end = offs[n+1];
  int hh = t & 7;                       // head this thread computes alpha for
  float ald_n = ald0[n*8 + hh];

  if(t < 8) s_den[t] = 0.f;

  float a0=0.f, a1=0.f, a2=0.f, a3=0.f;

  for(int chunk = beg; chunk < end; chunk += CH){
    int m = end - chunk; if(m > CH) m = CH;
    __syncthreads();                    // den-init visible / prev phase B done
    // phase A: alpha for m edges x 8 heads (each computed exactly once)
    float dpart = 0.f;
    for(int idx = t; idx < m*8; idx += 256){
      int e = idx >> 3;
      int s = csr[chunk + e];
      if(hh == 0) s_src[e] = s;
      float v = als0[s*8 + hh] + ald_n;
      v = v > 0.f ? v : NEG_SLOPE*v;
      float p = expf(v);
      s_alpha[e][hh] = p;
      dpart += p;
    }
    // sum over lanes sharing hh within the wave (lanes l, l^8, l^16, l^32)
    dpart += __shfl_xor(dpart, 8);
    dpart += __shfl_xor(dpart, 16);
    dpart += __shfl_xor(dpart, 32);
    if(lane < 8) atomicAdd(&s_den[lane], dpart);   // 8 atomics per wave
    __syncthreads();
    // phase B: 4 edges per wave-iteration, fp8 feature loads issued before FMAs
    for(int base = w*4; base < m; base += 16){
      int e1 = base+1, e2 = base+2, e3 = base+3;
      int s0 = s_src[base];
      int s1 = (e1 < m) ? s_src[e1] : s0;
      int s2 = (e2 < m) ? s_src[e2] : s0;
      int s3 = (e3 < m) ? s_src[e3] : s0;
      float p0 = s_alpha[base][h];
      float p1 = (e1 < m) ? s_alpha[e1][h] : 0.f;
      float p2 = (e2 < m) ? s_alpha[e2][h] : 0.f;
      float p3 = (e3 < m) ? s_alpha[e3][h] : 0.f;
      unsigned q0 = *(const unsigned*)(h0q + (size_t)s0*256 + c);
      unsigned q1 = *(const unsigned*)(h0q + (size_t)s1*256 + c);
      unsigned q2 = *(const unsigned*)(h0q + (size_t)s2*256 + c);
      unsigned q3 = *(const unsigned*)(h0q + (size_t)s3*256 + c);
      float f0,f1,f2,f3;
      dec8x4(q0, f0,f1,f2,f3);
      a0 = fmaf(p0,f0,a0); a1 = fmaf(p0,f1,a1); a2 = fmaf(p0,f2,a2); a3 = fmaf(p0,f3,a3);
      dec8x4(q1, f0,f1,f2,f3);
      a0 = fmaf(p1,f0,a0); a1 = fmaf(p1,f1,a1); a2 = fmaf(p1,f2,a2); a3 = fmaf(p1,f3,a3);
      dec8x4(q2, f0,f1,f2,f3);
      a0 = fmaf(p2,f0,a0); a1 = fmaf(p2,f1,a1); a2 = fmaf(p2,f2,a2); a3 = fmaf(p2,f3,a3);
      dec8x4(q3, f0,f1,f2,f3);
      a0 = fmaf(p3,f0,a0); a1 = fmaf(p3,f1,a1); a2 = fmaf(p3,f2,a2); a3 = fmaf(p3,f3,a3);
    }
  }

  if(w != 0){
    float4 v; v.x=a0; v.y=a1; v.z=a2; v.w=a3;
    smv[w-1][lane] = v;
  }
  __syncthreads();
  if(w != 0) return;
  #pragma unroll
  for(int jj=0; jj<3; jj++){
    float4 v = smv[jj][lane];
    a0 += v.x; a1 += v.y; a2 += v.z; a3 += v.w;
  }
  float rden = 1.f/(s_den[h] + 1e-16f);
  a0 *= rden; a1 *= rden; a2 *= rden; a3 *= rden;

  float4 bb = *(const float4*)(b0 + c);
  float4 rb = *(const float4*)(br0 + c);
  uint2 ru = *(const uint2*)(buf0b + (size_t)n*512 + 256 + c);
  float o0 = a0 + bb.x + __uint_as_float(ru.x << 16)         + rb.x;
  float o1 = a1 + bb.y + __uint_as_float(ru.x & 0xFFFF0000u) + rb.y;
  float o2 = a2 + bb.z + __uint_as_float(ru.y << 16)         + rb.z;
  float o3 = a3 + bb.w + __uint_as_float(ru.y & 0xFFFF0000u) + rb.w;
  ushort4v o;
  o[0] = f2b(o0 > 0.f ? o0 : expf(o0) - 1.f);
  o[1] = f2b(o1 > 0.f ? o1 : expf(o1) - 1.f);
  o[2] = f2b(o2 > 0.f ? o2 : expf(o2) - 1.f);
  o[3] = f2b(o3 > 0.f ? o3 : expf(o3) - 1.f);
  *(ushort4v*)(h1b + (size_t)n*256 + c) = o;
}

// ---------------- layer1 logits (bf16 g1) ----------------
extern "C" __global__ void k_al1(const unsigned short* __restrict__ buf1b, const float* __restrict__ as1,
                                 const float* __restrict__ ad1, float* als1, float* ald1, int N){
  int n = blockIdx.x*4 + (threadIdx.x >> 6);
  if(n >= N) return;
  int lane = threadIdx.x & 63;
  float g = b2f(buf1b[(size_t)n*128 + lane]);
  float s = g*as1[lane], d = g*ad1[lane];
  #pragma unroll
  for(int o=32; o>0; o>>=1){ s += __shfl_xor(s,o); d += __shfl_xor(d,o); }
  if(lane == 0){ als1[n] = s; ald1[n] = d; }
}

// ---- gather layer1: fused LDS-alpha + 4-wide gather + bias + residual + log_softmax ----
__launch_bounds__(256)
extern "C" __global__ void k_gather1(const unsigned short* __restrict__ buf1b,
                                     const float* __restrict__ als1, const float* __restrict__ ald1,
                                     const int* __restrict__ offs, const int* __restrict__ csr,
                                     const float* __restrict__ b1, const float* __restrict__ br1,
                                     float* __restrict__ out, int N){
  __shared__ float s_alpha[CH];
  __shared__ int   s_src[CH];
  __shared__ float s_den[1];
  __shared__ float smv[3][64];
  int n = blockIdx.x;
  int t = threadIdx.x;
  int lane = t & 63, w = t >> 6;
  int beg = offs[n], end = offs[n+1];
  float ald_n = ald1[n];

  if(t == 0) s_den[0] = 0.f;

  float acc = 0.f;

  for(int chunk = beg; chunk < end; chunk += CH){
    int m = end - chunk; if(m > CH) m = CH;
    __syncthreads();
    float dpart = 0.f;
    if(t < m){
      int s = csr[chunk + t];
      s_src[t] = s;
      float v = als1[s] + ald_n;
      v = v > 0.f ? v : NEG_SLOPE*v;
      float p = expf(v);
      s_alpha[t] = p;
      dpart = p;
    }
    #pragma unroll
    for(int o=32; o>0; o>>=1) dpart += __shfl_xor(dpart, o);
    if(lane == 0 && w == 0) atomicAdd(&s_den[0], dpart);
    __syncthreads();
    for(int base = w*4; base < m; base += 16){
      int e1 = base+1, e2 = base+2, e3 = base+3;
      int s0 = s_src[base];
      int s1 = (e1 < m) ? s_src[e1] : s0;
      int s2 = (e2 < m) ? s_src[e2] : s0;
      int s3 = (e3 < m) ? s_src[e3] : s0;
      float p0 = s_alpha[base];
      float p1 = (e1 < m) ? s_alpha[e1] : 0.f;
      float p2 = (e2 < m) ? s_alpha[e2] : 0.f;
      float p3 = (e3 < m) ? s_alpha[e3] : 0.f;
      unsigned short f0 = buf1b[(size_t)s0*128 + lane];
      unsigned short f1 = buf1b[(size_t)s1*128 + lane];
      unsigned short f2 = buf1b[(size_t)s2*128 + lane];
      unsigned short f3 = buf1b[(size_t)s3*128 + lane];
      acc = fmaf(p0, b2f(f0), acc);
      acc = fmaf(p1, b2f(f1), acc);
      acc = fmaf(p2, b2f(f2), acc);
      acc = fmaf(p3, b2f(f3), acc);
    }
  }

  if(w != 0) smv[w-1][lane] = acc;
  __syncthreads();
  if(w != 0) return;
  #pragma unroll
  for(int jj=0; jj<3; jj++) acc += smv[jj][lane];
  acc *= 1.f/(s_den[0] + 1e-16f);

  float val = acc + b1[lane] + b2f(buf1b[(size_t)n*128 + 64 + lane]) + br1[lane];
  float mx = val;
  #pragma unroll
  for(int o=32; o>0; o>>=1) mx = fmaxf(mx, __shfl_xor(mx,o));
  float ex = expf(val - mx), smn = ex;
  #pragma unroll
  for(int o=32; o>0; o>>=1) smn += __shfl_xor(smn,o);
  out[(size_t)n*64 + lane] = val - mx - logf(smn);
}

// ---------------- launch ----------------
extern "C" void kernel_launch(void* const* d_in, const int* in_sizes, int n_in,
                              void* d_out, int out_size, void* d_ws, size_t ws_size,
                              hipStream_t stream){
  const float* x   = (const float*)d_in[0];
  const int*   ei  = (const int*)  d_in[1];
  const float* W0  = (const float*)d_in[2];
  const float* as0 = (const float*)d_in[3];
  const float* ad0 = (const float*)d_in[4];
  const float* b0  = (const float*)d_in[5];
  const float* Wr0 = (const float*)d_in[6];
  const float* br0 = (const float*)d_in[7];
  const float* W1  = (const float*)d_in[8];
  const float* as1 = (const float*)d_in[9];
  const float* ad1 = (const float*)d_in[10];
  const float* b1  = (const float*)d_in[11];
  const float* Wr1 = (const float*)d_in[12];
  const float* br1 = (const float*)d_in[13];
  int N = in_sizes[0] / 256;
  int E = in_sizes[1] / 2;
  const int* srcs = ei;
  const int* dsts = ei + E;
  float* out = (float*)d_out;

  // workspace layout (bf16 feature buffers)
  unsigned short* buf0b = (unsigned short*)d_ws;        // N*512 bf16 (h0 | r0)
  unsigned short* xb    = buf0b + (size_t)N*512;        // N*256 bf16 (dead after mgemm0)
  unsigned short* h1b   = xb    + (size_t)N*256;        // N*256 bf16
  unsigned short* buf1b = h1b   + (size_t)N*256;        // N*128 bf16 (g1 | r1)
  unsigned short* WT0   = buf1b + (size_t)N*128;        // 512*256 bf16
  unsigned short* WT1   = WT0   + 512*256;              // 128*256 bf16
  float*    als0 = (float*)(WT1 + 128*256);             // N*8
  float*    ald0 = als0 + (size_t)N*8;                  // N*8
  float*    als1 = ald0 + (size_t)N*8;                  // N
  float*    ald1 = als1 + N;                            // N
  int*      cnt  = (int*)(ald1 + N);                    // N (also cursor)
  int*      offs = cnt + N;                             // N+1
  int*      part = offs + N + 1;                        // 256
  int*      csr  = part + 256;                          // E+N
  // fp8 h0 copy overlays xb (xb dead once mgemm0 has consumed it)
  unsigned char* h0q = (unsigned char*)xb;              // N*256 bytes

  int NB = (N + 255) / 256;
  int ET = E + N;

  // CSR build
  hipLaunchKernelGGL(k_init, dim3((N+255)/256), dim3(256), 0, stream, N, cnt);
  hipLaunchKernelGGL(k_count, dim3((E+255)/256), dim3(256), 0, stream, dsts, E, cnt);
  hipLaunchKernelGGL(k_scan_partial, dim3(NB), dim3(256), 0, stream, cnt, part, N);
  hipLaunchKernelGGL(k_scan_ex, dim3(1), dim3(256), 0, stream, part, NB);
  hipLaunchKernelGGL(k_scan_final, dim3(NB), dim3(256), 0, stream, cnt, part, offs, cnt, N);
  hipLaunchKernelGGL(k_scatter, dim3((ET+255)/256), dim3(256), 0, stream, srcs, dsts, E, N, cnt, csr);

  // casts / weight prep
  int n8 = N*256/8;
  hipLaunchKernelGGL(k_cast_x, dim3((n8+255)/256), dim3(256), 0, stream, x, xb, n8);
  hipLaunchKernelGGL(k_wt2, dim3((512*256+128*256+255)/256), dim3(256), 0, stream, W0, Wr0, W1, Wr1, WT0, WT1);

  int MB = (N + 127) / 128;
  int g0 = ((MB + 7) / 8) * 32;
  // layer0: buf0b[N][512] = xb @ [W0|Wr0]
  hipLaunchKernelGGL(k_mgemm, dim3(g0), dim3(256), 0, stream, xb, WT0, buf0b, 512, N, MB, 4);
  hipLaunchKernelGGL(k_al0, dim3((N*8+255)/256), dim3(256), 0, stream, buf0b, as0, ad0, als0, ald0, N);
  hipLaunchKernelGGL(k_cast8, dim3((n8+255)/256), dim3(256), 0, stream, buf0b, h0q, n8);
  hipLaunchKernelGGL(k_gather0, dim3(N), dim3(256), 0, stream, buf0b, h0q, als0, ald0, offs, csr, b0, br0, h1b, N);

  // layer1: buf1b[N][128] = h1b @ [W1|Wr1]
  hipLaunchKernelGGL(k_mgemm, dim3(MB), dim3(256), 0, stream, h1b, WT1, buf1b, 128, N, MB, 1);
  hipLaunchKernelGGL(k_al1, dim3((N+3)/4), dim3(256), 0, stream, buf1b, as1, ad1, als1, ald1, N);
  hipLaunchKernelGGL(k_gather1, dim3(N), dim3(256), 0, stream, buf1b, als1, ald1, offs, csr, b1, br1, out, N);
}

// Round 14
// 333.394 us; speedup vs baseline: 1.0207x; 1.0054x over previous
//
#include <hip/hip_runtime.h>
#include <math.h>

#define NEG_SLOPE 0.2f

typedef __attribute__((ext_vector_type(8))) short bf16x8;
typedef __attribute__((ext_vector_type(4))) float f32x4;
typedef __attribute__((ext_vector_type(2))) float f32x2;
typedef __attribute__((ext_vector_type(8))) unsigned short ushort8;
typedef __attribute__((ext_vector_type(4))) unsigned short ushort4v;

__device__ __forceinline__ float b2f(unsigned short u){
  return __uint_as_float(((unsigned)u) << 16);
}
__device__ __forceinline__ unsigned short f2b(float f){
  unsigned u = __float_as_uint(f);
  return (unsigned short)((u + 0x7FFFu + ((u >> 16) & 1u)) >> 16);
}

// ---- fp8 e4m3fn helpers (hardware cvt if available, bit-twiddle fallback) ----
#if __has_builtin(__builtin_amdgcn_cvt_pk_f32_fp8) && __has_builtin(__builtin_amdgcn_cvt_pk_fp8_f32)
#define HW_FP8 1
#else
#define HW_FP8 0
#endif

#if !HW_FP8
__device__ __forceinline__ unsigned enc8_one(float f){
  unsigned bits = __float_as_uint(f);
  unsigned s = bits >> 31;
  unsigned e = (bits >> 23) & 255;
  unsigned mant = bits & 0x7FFFFF;
  if(e < 121){
    float af = fabsf(f);
    int m = (int)(af * 512.f + 0.5f);
    if(m > 7) m = 7;
    return (s << 7) | (unsigned)m;
  }
  unsigned lsb = (mant >> 20) & 1;
  mant += 0x7FFFF + lsb;
  if(mant >> 23){ e += 1; mant = 0; }
  unsigned m3 = mant >> 20;
  unsigned e8 = e - 120;
  if(e8 > 15 || (e8 == 15 && m3 == 7)) return (s << 7) | 0x7E;
  return (s << 7) | (e8 << 3) | m3;
}
#endif

template<bool HI>
__device__ __forceinline__ unsigned enc8_pair(float a, float b, unsigned old){
#if HW_FP8
  return __builtin_amdgcn_cvt_pk_fp8_f32(a, b, old, HI);  // HI literal (op_sel)
#else
  unsigned p = enc8_one(a) | (enc8_one(b) << 8);
  return HI ? ((old & 0x0000FFFFu) | (p << 16)) : ((old & 0xFFFF0000u) | p);
#endif
}

__device__ __forceinline__ unsigned char enc8b(float v){
  return (unsigned char)(enc8_pair<false>(v, v, 0u) & 0xFFu);
}

__device__ __forceinline__ void dec8x4v(unsigned q, f32x2& lo, f32x2& hi){
#if HW_FP8
  lo = __builtin_amdgcn_cvt_pk_f32_fp8(q, false);
  hi = __builtin_amdgcn_cvt_pk_f32_fp8(q, true);
#else
  auto dec1 = [](unsigned b)->float{
    unsigned s = (b >> 7) & 1, e = (b >> 3) & 15, m = b & 7;
    float v = (e == 0) ? (float)m * 0.001953125f
                       : __uint_as_float(((e + 120) << 23) | (m << 20));
    return s ? -v : v;
  };
  lo[0] = dec1(q & 255); lo[1] = dec1((q >> 8) & 255);
  hi[0] = dec1((q >> 16) & 255); hi[1] = dec1(q >> 24);
#endif
}

// ---------------- CSR build (cnt zeroed by hipMemsetAsync; deg = cnt+1 self loop) ----------------
extern "C" __global__ void k_count(const int* __restrict__ dsts, int E, int* cnt){
  int e = blockIdx.x*blockDim.x + threadIdx.x;
  if(e >= E) return;
  atomicAdd(&cnt[dsts[e]], 1);
}

extern "C" __global__ void k_scan_partial(const int* __restrict__ cnt, int* part, int N){
  __shared__ int sh[256];
  int t = threadIdx.x, i = blockIdx.x*256 + t;
  sh[t] = (i < N) ? cnt[i] + 1 : 0;
  __syncthreads();
  for(int s=128; s>0; s>>=1){
    if(t < s) sh[t] += sh[t+s];
    __syncthreads();
  }
  if(t == 0) part[blockIdx.x] = sh[0];
}

extern "C" __global__ void k_scan_ex(int* part, int NB){
  __shared__ int sh[256];
  int t = threadIdx.x;
  int v = (t < NB) ? part[t] : 0;
  sh[t] = v; __syncthreads();
  for(int s=1; s<256; s<<=1){
    int u = (t >= s) ? sh[t-s] : 0;
    __syncthreads();
    sh[t] += u;
    __syncthreads();
  }
  if(t < NB) part[t] = sh[t] - v;  // exclusive
}

extern "C" __global__ void k_scan_final(const int* __restrict__ cnt, const int* __restrict__ part,
                                        int* offs, int* cur, int N){
  __shared__ int sh[256];
  int t = threadIdx.x, i = blockIdx.x*256 + t;
  int v = (i < N) ? cnt[i] + 1 : 0;
  sh[t] = v; __syncthreads();
  for(int s=1; s<256; s<<=1){
    int u = (t >= s) ? sh[t-s] : 0;
    __syncthreads();
    sh[t] += u;
    __syncthreads();
  }
  int ex = part[blockIdx.x] + sh[t] - v;
  if(i < N){ offs[i] = ex; cur[i] = ex; }
  if(i == N-1) offs[N] = ex + v;
}

extern "C" __global__ void k_scatter(const int* __restrict__ srcs, const int* __restrict__ dsts,
                                     int E, int N, int* cur, int* csr){
  int i = blockIdx.x*blockDim.x + threadIdx.x;
  if(i >= E + N) return;
  int s, d;
  if(i < E){ s = srcs[i]; d = dsts[i]; } else { s = d = i - E; }
  int pos = atomicAdd(&cur[d], 1);
  csr[pos] = s;
}

// ---------------- fp32 -> bf16 cast (8 elems/thread) ----------------
extern "C" __global__ void k_cast_x(const float* __restrict__ x, unsigned short* __restrict__ xb, int n8){
  int i = blockIdx.x*blockDim.x + threadIdx.x;
  if(i >= n8) return;
  const float4* p = (const float4*)(x + (size_t)i*8);
  float4 v0 = p[0], v1 = p[1];
  ushort8 o;
  o[0]=f2b(v0.x); o[1]=f2b(v0.y); o[2]=f2b(v0.z); o[3]=f2b(v0.w);
  o[4]=f2b(v1.x); o[5]=f2b(v1.y); o[6]=f2b(v1.z); o[7]=f2b(v1.w);
  *(ushort8*)(xb + (size_t)i*8) = o;
}

// ---------------- weight transpose+concat (both layers, one launch) ----------------
extern "C" __global__ void k_wt2(const float* __restrict__ W0, const float* __restrict__ Wr0,
                                 const float* __restrict__ W1, const float* __restrict__ Wr1,
                                 unsigned short* __restrict__ WT0, unsigned short* __restrict__ WT1){
  int idx = blockIdx.x*256 + threadIdx.x;
  const int tot0 = 512*256;
  if(idx < tot0){
    int n = idx >> 8, k = idx & 255;
    const float* W = (n < 256) ? W0 : Wr0;
    int c = (n < 256) ? n : n - 256;
    WT0[idx] = f2b(W[(size_t)k*256 + c]);
  } else {
    idx -= tot0;
    if(idx >= 128*256) return;
    int n = idx >> 8, k = idx & 255;
    const float* W = (n < 64) ? W1 : Wr1;
    int c = (n < 64) ? n : n - 64;
    WT1[idx] = f2b(W[(size_t)k*64 + c]);
  }
}

// ---------------- bf16 MFMA GEMM + optional fp8 side-output for cols<256 ----------------
__launch_bounds__(256)
extern "C" __global__ void k_mgemm(const unsigned short* __restrict__ A,
                                   const unsigned short* __restrict__ WT,
                                   unsigned short* __restrict__ C, int ldc, int M,
                                   int MB, int NCB, unsigned char* __restrict__ qout){
  int id = blockIdx.x;
  int row_blk, col_blk;
  if(NCB == 4){
    int group = id >> 5;
    int r8 = id & 7;
    col_blk = (id >> 3) & 3;
    row_blk = group*8 + r8;
  } else {
    row_blk = id; col_blk = 0;
  }
  if(row_blk >= MB) return;

  __shared__ unsigned short As[128*64];
  __shared__ unsigned short Bs[128*64];
  int t = threadIdx.x;
  int lane = t & 63, wid = t >> 6;
  int wr = wid >> 1, wc = wid & 1;
  int row0 = row_blk*128, col0 = col_blk*128;
  f32x4 acc[4][4] = {};

  for(int k0 = 0; k0 < 256; k0 += 64){
    #pragma unroll
    for(int i=0; i<4; i++){
      int t2 = i*256 + t;
      int r = t2 >> 3;
      int dslot = (t2 & 7) ^ (r & 7);
      int gr = row0 + r; if(gr >= M) gr = M - 1;
      const unsigned short* ga = A + (size_t)gr*256 + k0 + dslot*8;
      __builtin_amdgcn_global_load_lds((const __attribute__((address_space(1))) unsigned*)ga,
          (__attribute__((address_space(3))) unsigned*)(As + i*2048 + wid*512), 16, 0, 0);
      const unsigned short* gb = WT + (size_t)(col0 + r)*256 + k0 + dslot*8;
      __builtin_amdgcn_global_load_lds((const __attribute__((address_space(1))) unsigned*)gb,
          (__attribute__((address_space(3))) unsigned*)(Bs + i*2048 + wid*512), 16, 0, 0);
    }
    __syncthreads();
    #pragma unroll
    for(int kc=0; kc<2; kc++){
      bf16x8 a[4], b[4];
      int kb = kc*4 + (lane >> 4);
      #pragma unroll
      for(int f=0; f<4; f++){
        int ar = wr*64 + f*16 + (lane & 15);
        a[f] = *(const bf16x8*)&As[ar*64 + ((kb ^ (ar & 7))*8)];
        int br = wc*64 + f*16 + (lane & 15);
        b[f] = *(const bf16x8*)&Bs[br*64 + ((kb ^ (br & 7))*8)];
      }
      #pragma unroll
      for(int fm=0; fm<4; fm++)
        #pragma unroll
        for(int fn=0; fn<4; fn++)
          acc[fm][fn] = __builtin_amdgcn_mfma_f32_16x16x32_bf16(a[fm], b[fn], acc[fm][fn], 0, 0, 0);
    }
    __syncthreads();
  }

  int rb = row0 + wr*64 + ((lane >> 4) << 2);
  int cb = col0 + wc*64 + (lane & 15);
  #pragma unroll
  for(int fm=0; fm<4; fm++){
    #pragma unroll
    for(int r=0; r<4; r++){
      int row = rb + fm*16 + r;
      if(row < M){
        #pragma unroll
        for(int fn=0; fn<4; fn++)
          C[(size_t)row*ldc + cb + fn*16] = f2b(acc[fm][fn][r]);
        if(qout){
          #pragma unroll
          for(int fn=0; fn<4; fn++){
            int col = cb + fn*16;
            if(col < 256) qout[(size_t)row*256 + col] = enc8b(acc[fm][fn][r]);
          }
        }
      }
    }
  }
}

// ---------------- attention logits layer0 (bf16 h0) ----------------
extern "C" __global__ void k_al0(const unsigned short* __restrict__ buf0b, const float* __restrict__ as0,
                                 const float* __restrict__ ad0, float* als0, float* ald0, int N){
  int i = blockIdx.x*blockDim.x + threadIdx.x;   // n*8+h
  if(i >= N*8) return;
  int n = i >> 3, h = i & 7;
  const uint4* hp = (const uint4*)(buf0b + (size_t)n*512 + h*32);
  const float* av = as0 + h*32;
  const float* dv = ad0 + h*32;
  float s = 0.f, d = 0.f;
  #pragma unroll
  for(int q=0; q<4; q++){
    uint4 u = hp[q];
    unsigned w[4] = {u.x, u.y, u.z, u.w};
    #pragma unroll
    for(int j=0; j<4; j++){
      float lo = __uint_as_float(w[j] << 16);
      float hi = __uint_as_float(w[j] & 0xFFFF0000u);
      int c = q*8 + j*2;
      s += lo*av[c] + hi*av[c+1];
      d += lo*dv[c] + hi*dv[c+1];
    }
  }
  als0[i] = s; ald0[i] = d;
}

// ---- gather layer0: fused LDS-alpha (chunked) + 4-wide fp8 gather, packed-f32 FMA ----
// block per node; lane owns channels c=lane*4..lane*4+3, head h=lane>>3.
// No max subtraction: logits are O(+-10) (unit-variance tensors), exp fp32-safe,
// softmax shift-invariant.
#define CH 64
__launch_bounds__(256)
extern "C" __global__ void k_gather0(const unsigned short* __restrict__ buf0b,
                                     const unsigned char* __restrict__ h0q,
                                     const float* __restrict__ als0, const float* __restrict__ ald0,
                                     const int* __restrict__ offs, const int* __restrict__ csr,
                                     const float* __restrict__ b0, const float* __restrict__ br0,
                                     unsigned short* __restrict__ h1b, int N){
  __shared__ float s_alpha[CH][8];
  __shared__ int   s_src[CH];
  __shared__ float s_den[8];
  __shared__ float4 smv[3][64];
  int n = blockIdx.x;
  int t = threadIdx.x;
  int lane = t & 63, w = t >> 6;
  int h = lane >> 3;
  int c = lane*4;
  int beg = offs[n], end = offs[n+1];
  int hh = t & 7;
  float ald_n = ald0[n*8 + hh];

  if(t < 8) s_den[t] = 0.f;

  f32x2 A01 = {0.f, 0.f}, A23 = {0.f, 0.f};

  for(int chunk = beg; chunk < end; chunk += CH){
    int m = end - chunk; if(m > CH) m = CH;
    __syncthreads();
    // phase A: alpha for m edges x 8 heads
    float dpart = 0.f;
    for(int idx = t; idx < m*8; idx += 256){
      int e = idx >> 3;
      int s = csr[chunk + e];
      if(hh == 0) s_src[e] = s;
      float v = als0[s*8 + hh] + ald_n;
      v = v > 0.f ? v : NEG_SLOPE*v;
      float p = expf(v);
      s_alpha[e][hh] = p;
      dpart += p;
    }
    dpart += __shfl_xor(dpart, 8);
    dpart += __shfl_xor(dpart, 16);
    dpart += __shfl_xor(dpart, 32);
    if(lane < 8) atomicAdd(&s_den[lane], dpart);
    __syncthreads();
    // phase B: 4 edges per wave-iteration, fp8 loads issued before FMAs
    for(int base = w*4; base < m; base += 16){
      int e1 = base+1, e2 = base+2, e3 = base+3;
      int s0 = s_src[base];
      int s1 = (e1 < m) ? s_src[e1] : s0;
      int s2 = (e2 < m) ? s_src[e2] : s0;
      int s3 = (e3 < m) ? s_src[e3] : s0;
      float p0 = s_alpha[base][h];
      float p1 = (e1 < m) ? s_alpha[e1][h] : 0.f;
      float p2 = (e2 < m) ? s_alpha[e2][h] : 0.f;
      float p3 = (e3 < m) ? s_alpha[e3][h] : 0.f;
      unsigned q0 = *(const unsigned*)(h0q + (size_t)s0*256 + c);
      unsigned q1 = *(const unsigned*)(h0q + (size_t)s1*256 + c);
      unsigned q2 = *(const unsigned*)(h0q + (size_t)s2*256 + c);
      unsigned q3 = *(const unsigned*)(h0q + (size_t)s3*256 + c);
      f32x2 lo, hi, pv;
      dec8x4v(q0, lo, hi); pv[0]=p0; pv[1]=p0; A01 += pv*lo; A23 += pv*hi;
      dec8x4v(q1, lo, hi); pv[0]=p1; pv[1]=p1; A01 += pv*lo; A23 += pv*hi;
      dec8x4v(q2, lo, hi); pv[0]=p2; pv[1]=p2; A01 += pv*lo; A23 += pv*hi;
      dec8x4v(q3, lo, hi); pv[0]=p3; pv[1]=p3; A01 += pv*lo; A23 += pv*hi;
    }
  }

  if(w != 0){
    float4 v; v.x=A01[0]; v.y=A01[1]; v.z=A23[0]; v.w=A23[1];
    smv[w-1][lane] = v;
  }
  __syncthreads();
  if(w != 0) return;
  float a0=A01[0], a1=A01[1], a2=A23[0], a3=A23[1];
  #pragma unroll
  for(int jj=0; jj<3; jj++){
    float4 v = smv[jj][lane];
    a0 += v.x; a1 += v.y; a2 += v.z; a3 += v.w;
  }
  float rden = 1.f/(s_den[h] + 1e-16f);
  a0 *= rden; a1 *= rden; a2 *= rden; a3 *= rden;

  float4 bb = *(const float4*)(b0 + c);
  float4 rb = *(const float4*)(br0 + c);
  uint2 ru = *(const uint2*)(buf0b + (size_t)n*512 + 256 + c);
  float o0 = a0 + bb.x + __uint_as_float(ru.x << 16)         + rb.x;
  float o1 = a1 + bb.y + __uint_as_float(ru.x & 0xFFFF0000u) + rb.y;
  float o2 = a2 + bb.z + __uint_as_float(ru.y << 16)         + rb.z;
  float o3 = a3 + bb.w + __uint_as_float(ru.y & 0xFFFF0000u) + rb.w;
  ushort4v o;
  o[0] = f2b(o0 > 0.f ? o0 : expf(o0) - 1.f);
  o[1] = f2b(o1 > 0.f ? o1 : expf(o1) - 1.f);
  o[2] = f2b(o2 > 0.f ? o2 : expf(o2) - 1.f);
  o[3] = f2b(o3 > 0.f ? o3 : expf(o3) - 1.f);
  *(ushort4v*)(h1b + (size_t)n*256 + c) = o;
}

// ---------------- layer1 logits (bf16 g1) ----------------
extern "C" __global__ void k_al1(const unsigned short* __restrict__ buf1b, const float* __restrict__ as1,
                                 const float* __restrict__ ad1, float* als1, float* ald1, int N){
  int n = blockIdx.x*4 + (threadIdx.x >> 6);
  if(n >= N) return;
  int lane = threadIdx.x & 63;
  float g = b2f(buf1b[(size_t)n*128 + lane]);
  float s = g*as1[lane], d = g*ad1[lane];
  #pragma unroll
  for(int o=32; o>0; o>>=1){ s += __shfl_xor(s,o); d += __shfl_xor(d,o); }
  if(lane == 0){ als1[n] = s; ald1[n] = d; }
}

// ---- gather layer1: 2 channels/lane (uint loads), 2 edges/wave-lane-half, 4-wide unroll ----
// lane: channel pair ch2=lane&31 (channels 2*ch2, 2*ch2+1), edge slot es=lane>>5.
__launch_bounds__(256)
extern "C" __global__ void k_gather1(const unsigned short* __restrict__ buf1b,
                                     const float* __restrict__ als1, const float* __restrict__ ald1,
                                     const int* __restrict__ offs, const int* __restrict__ csr,
                                     const float* __restrict__ b1, const float* __restrict__ br1,
                                     float* __restrict__ out, int N){
  __shared__ float s_alpha[CH];
  __shared__ int   s_src[CH];
  __shared__ float s_den[1];
  __shared__ float2 smv[3][32];
  int n = blockIdx.x;
  int t = threadIdx.x;
  int lane = t & 63, w = t >> 6;
  int ch2 = lane & 31;
  int es  = lane >> 5;
  int beg = offs[n], end = offs[n+1];
  float ald_n = ald1[n];

  if(t == 0) s_den[0] = 0.f;

  f32x2 acc = {0.f, 0.f};

  for(int chunk = beg; chunk < end; chunk += CH){
    int m = end - chunk; if(m > CH) m = CH;
    __syncthreads();
    float dpart = 0.f;
    if(t < m){
      int s = csr[chunk + t];
      s_src[t] = s;
      float v = als1[s] + ald_n;
      v = v > 0.f ? v : NEG_SLOPE*v;
      float p = expf(v);
      s_alpha[t] = p;
      dpart = p;
    }
    #pragma unroll
    for(int o=32; o>0; o>>=1) dpart += __shfl_xor(dpart, o);
    if(lane == 0 && w == 0) atomicAdd(&s_den[0], dpart);
    __syncthreads();
    // wave covers 8 edges per iter: 4 unroll x 2 lane-halves
    for(int base = w*8; base < m; base += 32){
      int sv[4]; float pv[4];
      #pragma unroll
      for(int i=0; i<4; i++){
        int e = base + 2*i + es;
        bool ok = e < m;
        sv[i] = ok ? s_src[e] : s_src[base];
        pv[i] = ok ? s_alpha[e] : 0.f;
      }
      unsigned uv[4];
      #pragma unroll
      for(int i=0; i<4; i++)
        uv[i] = *(const unsigned*)(buf1b + (size_t)sv[i]*128 + ch2*2);
      #pragma unroll
      for(int i=0; i<4; i++){
        f32x2 f, pp;
        f[0] = __uint_as_float(uv[i] << 16);
        f[1] = __uint_as_float(uv[i] & 0xFFFF0000u);
        pp[0] = pv[i]; pp[1] = pv[i];
        acc += pp*f;
      }
    }
  }

  // merge the two edge-slot halves (lane l <-> l^32)
  acc[0] += __shfl_xor(acc[0], 32);
  acc[1] += __shfl_xor(acc[1], 32);

  if(w != 0 && es == 0){
    float2 v; v.x = acc[0]; v.y = acc[1];
    smv[w-1][ch2] = v;
  }
  __syncthreads();
  if(w != 0) return;
  #pragma unroll
  for(int jj=0; jj<3; jj++){
    float2 v = smv[jj][ch2];
    acc[0] += v.x; acc[1] += v.y;
  }
  float rden = 1.f/(s_den[0] + 1e-16f);
  acc[0] *= rden; acc[1] *= rden;

  float2 bb = *(const float2*)(b1 + ch2*2);
  float2 rb = *(const float2*)(br1 + ch2*2);
  unsigned ru = *(const unsigned*)(buf1b + (size_t)n*128 + 64 + ch2*2);
  float vx = acc[0] + bb.x + __uint_as_float(ru << 16)         + rb.x;
  float vy = acc[1] + bb.y + __uint_as_float(ru & 0xFFFF0000u) + rb.y;

  float mx = fmaxf(vx, vy);
  #pragma unroll
  for(int o=16; o>0; o>>=1) mx = fmaxf(mx, __shfl_xor(mx, o));
  float sm = expf(vx - mx) + expf(vy - mx);
  #pragma unroll
  for(int o=16; o>0; o>>=1) sm += __shfl_xor(sm, o);
  float l = mx + logf(sm);
  if(es == 0){
    float2 ov; ov.x = vx - l; ov.y = vy - l;
    *(float2*)(out + (size_t)n*64 + ch2*2) = ov;
  }
}

// ---------------- launch ----------------
extern "C" void kernel_launch(void* const* d_in, const int* in_sizes, int n_in,
                              void* d_out, int out_size, void* d_ws, size_t ws_size,
                              hipStream_t stream){
  const float* x   = (const float*)d_in[0];
  const int*   ei  = (const int*)  d_in[1];
  const float* W0  = (const float*)d_in[2];
  const float* as0 = (const float*)d_in[3];
  const float* ad0 = (const float*)d_in[4];
  const float* b0  = (const float*)d_in[5];
  const float* Wr0 = (const float*)d_in[6];
  const float* br0 = (const float*)d_in[7];
  const float* W1  = (const float*)d_in[8];
  const float* as1 = (const float*)d_in[9];
  const float* ad1 = (const float*)d_in[10];
  const float* b1  = (const float*)d_in[11];
  const float* Wr1 = (const float*)d_in[12];
  const float* br1 = (const float*)d_in[13];
  int N = in_sizes[0] / 256;
  int E = in_sizes[1] / 2;
  const int* srcs = ei;
  const int* dsts = ei + E;
  float* out = (float*)d_out;

  // workspace layout (bf16 feature buffers)
  unsigned short* buf0b = (unsigned short*)d_ws;        // N*512 bf16 (h0 | r0)
  unsigned short* xb    = buf0b + (size_t)N*512;        // N*256 bf16 (dead after mgemm0)
  unsigned short* h1b   = xb    + (size_t)N*256;        // N*256 bf16
  unsigned short* buf1b = h1b   + (size_t)N*256;        // N*128 bf16 (g1 | r1)
  unsigned short* WT0   = buf1b + (size_t)N*128;        // 512*256 bf16
  unsigned short* WT1   = WT0   + 512*256;              // 128*256 bf16
  float*    als0 = (float*)(WT1 + 128*256);             // N*8
  float*    ald0 = als0 + (size_t)N*8;                  // N*8
  float*    als1 = ald0 + (size_t)N*8;                  // N
  float*    ald1 = als1 + N;                            // N
  int*      cnt  = (int*)(ald1 + N);                    // N (also cursor)
  int*      offs = cnt + N;                             // N+1
  int*      part = offs + N + 1;                        // 256
  int*      csr  = part + 256;                          // E+N
  // fp8 h0 copy overlays xb (xb dead once mgemm0 has consumed it)
  unsigned char* h0q = (unsigned char*)xb;              // N*256 bytes

  int NB = (N + 255) / 256;
  int ET = E + N;

  // CSR build (cnt zeroed via memset; self loop = +1 in scans)
  hipMemsetAsync(cnt, 0, (size_t)N*sizeof(int), stream);
  hipLaunchKernelGGL(k_count, dim3((E+255)/256), dim3(256), 0, stream, dsts, E, cnt);
  hipLaunchKernelGGL(k_scan_partial, dim3(NB), dim3(256), 0, stream, cnt, part, N);
  hipLaunchKernelGGL(k_scan_ex, dim3(1), dim3(256), 0, stream, part, NB);
  hipLaunchKernelGGL(k_scan_final, dim3(NB), dim3(256), 0, stream, cnt, part, offs, cnt, N);
  hipLaunchKernelGGL(k_scatter, dim3((ET+255)/256), dim3(256), 0, stream, srcs, dsts, E, N, cnt, csr);

  // casts / weight prep
  int n8 = N*256/8;
  hipLaunchKernelGGL(k_cast_x, dim3((n8+255)/256), dim3(256), 0, stream, x, xb, n8);
  hipLaunchKernelGGL(k_wt2, dim3((512*256+128*256+255)/256), dim3(256), 0, stream, W0, Wr0, W1, Wr1, WT0, WT1);

  int MB = (N + 127) / 128;
  int g0 = ((MB + 7) / 8) * 32;
  // layer0: buf0b[N][512] = xb @ [W0|Wr0]; epilogue also writes fp8 h0q (cols<256)
  hipLaunchKernelGGL(k_mgemm, dim3(g0), dim3(256), 0, stream, xb, WT0, buf0b, 512, N, MB, 4, h0q);
  hipLaunchKernelGGL(k_al0, dim3((N*8+255)/256), dim3(256), 0, stream, buf0b, as0, ad0, als0, ald0, N);
  hipLaunchKernelGGL(k_gather0, dim3(N), dim3(256), 0, stream, buf0b, h0q, als0, ald0, offs, csr, b0, br0, h1b, N);

  // layer1: buf1b[N][128] = h1b @ [W1|Wr1]
  hipLaunchKernelGGL(k_mgemm, dim3(MB), dim3(256), 0, stream, h1b, WT1, buf1b, 128, N, MB, 1, (unsigned char*)nullptr);
  hipLaunchKernelGGL(k_al1, dim3((N+3)/4), dim3(256), 0, stream, buf1b, as1, ad1, als1, ald1, N);
  hipLaunchKernelGGL(k_gather1, dim3(N), dim3(256), 0, stream, buf1b, als1, ald1, offs, csr, b1, br1, out, N);
}

// Round 15
// 271.121 us; speedup vs baseline: 1.2552x; 1.2297x over previous
//
#include <hip/hip_runtime.h>
#include <math.h>

#define NEG_SLOPE 0.2f

typedef __attribute__((ext_vector_type(8))) short bf16x8;
typedef __attribute__((ext_vector_type(4))) float f32x4;
typedef __attribute__((ext_vector_type(2))) float f32x2;
typedef __attribute__((ext_vector_type(8))) unsigned short ushort8;
typedef __attribute__((ext_vector_type(4))) unsigned short ushort4v;

__device__ __forceinline__ float b2f(unsigned short u){
  return __uint_as_float(((unsigned)u) << 16);
}
__device__ __forceinline__ unsigned short f2b(float f){
  unsigned u = __float_as_uint(f);
  return (unsigned short)((u + 0x7FFFu + ((u >> 16) & 1u)) >> 16);
}

// ---- fp8 e4m3fn helpers (hardware cvt if available, bit-twiddle fallback) ----
#if __has_builtin(__builtin_amdgcn_cvt_pk_f32_fp8) && __has_builtin(__builtin_amdgcn_cvt_pk_fp8_f32)
#define HW_FP8 1
#else
#define HW_FP8 0
#endif

#if !HW_FP8
__device__ __forceinline__ unsigned enc8_one(float f){
  unsigned bits = __float_as_uint(f);
  unsigned s = bits >> 31;
  unsigned e = (bits >> 23) & 255;
  unsigned mant = bits & 0x7FFFFF;
  if(e < 121){
    float af = fabsf(f);
    int m = (int)(af * 512.f + 0.5f);
    if(m > 7) m = 7;
    return (s << 7) | (unsigned)m;
  }
  unsigned lsb = (mant >> 20) & 1;
  mant += 0x7FFFF + lsb;
  if(mant >> 23){ e += 1; mant = 0; }
  unsigned m3 = mant >> 20;
  unsigned e8 = e - 120;
  if(e8 > 15 || (e8 == 15 && m3 == 7)) return (s << 7) | 0x7E;
  return (s << 7) | (e8 << 3) | m3;
}
#endif

template<bool HI>
__device__ __forceinline__ unsigned enc8_pair(float a, float b, unsigned old){
#if HW_FP8
  return __builtin_amdgcn_cvt_pk_fp8_f32(a, b, old, HI);  // HI literal (op_sel)
#else
  unsigned p = enc8_one(a) | (enc8_one(b) << 8);
  return HI ? ((old & 0x0000FFFFu) | (p << 16)) : ((old & 0xFFFF0000u) | p);
#endif
}

__device__ __forceinline__ unsigned char enc8b(float v){
  return (unsigned char)(enc8_pair<false>(v, v, 0u) & 0xFFu);
}

__device__ __forceinline__ void dec8x4v(unsigned q, f32x2& lo, f32x2& hi){
#if HW_FP8
  lo = __builtin_amdgcn_cvt_pk_f32_fp8(q, false);
  hi = __builtin_amdgcn_cvt_pk_f32_fp8(q, true);
#else
  auto dec1 = [](unsigned b)->float{
    unsigned s = (b >> 7) & 1, e = (b >> 3) & 15, m = b & 7;
    float v = (e == 0) ? (float)m * 0.001953125f
                       : __uint_as_float(((e + 120) << 23) | (m << 20));
    return s ? -v : v;
  };
  lo[0] = dec1(q & 255); lo[1] = dec1((q >> 8) & 255);
  hi[0] = dec1((q >> 16) & 255); hi[1] = dec1(q >> 24);
#endif
}

// ---------------- CSR build (cnt zeroed by hipMemsetAsync; deg = cnt+1 self loop) ----------------
extern "C" __global__ void k_count(const int* __restrict__ dsts, int E, int* cnt){
  int e = blockIdx.x*blockDim.x + threadIdx.x;
  if(e >= E) return;
  atomicAdd(&cnt[dsts[e]], 1);
}

extern "C" __global__ void k_scan_partial(const int* __restrict__ cnt, int* part, int N){
  __shared__ int sh[256];
  int t = threadIdx.x, i = blockIdx.x*256 + t;
  sh[t] = (i < N) ? cnt[i] + 1 : 0;
  __syncthreads();
  for(int s=128; s>0; s>>=1){
    if(t < s) sh[t] += sh[t+s];
    __syncthreads();
  }
  if(t == 0) part[blockIdx.x] = sh[0];
}

extern "C" __global__ void k_scan_ex(int* part, int NB){
  __shared__ int sh[256];
  int t = threadIdx.x;
  int v = (t < NB) ? part[t] : 0;
  sh[t] = v; __syncthreads();
  for(int s=1; s<256; s<<=1){
    int u = (t >= s) ? sh[t-s] : 0;
    __syncthreads();
    sh[t] += u;
    __syncthreads();
  }
  if(t < NB) part[t] = sh[t] - v;  // exclusive
}

extern "C" __global__ void k_scan_final(const int* __restrict__ cnt, const int* __restrict__ part,
                                        int* offs, int* cur, int N){
  __shared__ int sh[256];
  int t = threadIdx.x, i = blockIdx.x*256 + t;
  int v = (i < N) ? cnt[i] + 1 : 0;
  sh[t] = v; __syncthreads();
  for(int s=1; s<256; s<<=1){
    int u = (t >= s) ? sh[t-s] : 0;
    __syncthreads();
    sh[t] += u;
    __syncthreads();
  }
  int ex = part[blockIdx.x] + sh[t] - v;
  if(i < N){ offs[i] = ex; cur[i] = ex; }
  if(i == N-1) offs[N] = ex + v;
}

extern "C" __global__ void k_scatter(const int* __restrict__ srcs, const int* __restrict__ dsts,
                                     int E, int N, int* cur, int* csr){
  int i = blockIdx.x*blockDim.x + threadIdx.x;
  if(i >= E + N) return;
  int s, d;
  if(i < E){ s = srcs[i]; d = dsts[i]; } else { s = d = i - E; }
  int pos = atomicAdd(&cur[d], 1);
  csr[pos] = s;
}

// ---------------- fp32 -> bf16 cast (8 elems/thread) ----------------
extern "C" __global__ void k_cast_x(const float* __restrict__ x, unsigned short* __restrict__ xb, int n8){
  int i = blockIdx.x*blockDim.x + threadIdx.x;
  if(i >= n8) return;
  const float4* p = (const float4*)(x + (size_t)i*8);
  float4 v0 = p[0], v1 = p[1];
  ushort8 o;
  o[0]=f2b(v0.x); o[1]=f2b(v0.y); o[2]=f2b(v0.z); o[3]=f2b(v0.w);
  o[4]=f2b(v1.x); o[5]=f2b(v1.y); o[6]=f2b(v1.z); o[7]=f2b(v1.w);
  *(ushort8*)(xb + (size_t)i*8) = o;
}

// ---------------- weight transpose+concat (both layers, one launch) ----------------
extern "C" __global__ void k_wt2(const float* __restrict__ W0, const float* __restrict__ Wr0,
                                 const float* __restrict__ W1, const float* __restrict__ Wr1,
                                 unsigned short* __restrict__ WT0, unsigned short* __restrict__ WT1){
  int idx = blockIdx.x*256 + threadIdx.x;
  const int tot0 = 512*256;
  if(idx < tot0){
    int n = idx >> 8, k = idx & 255;
    const float* W = (n < 256) ? W0 : Wr0;
    int c = (n < 256) ? n : n - 256;
    WT0[idx] = f2b(W[(size_t)k*256 + c]);
  } else {
    idx -= tot0;
    if(idx >= 128*256) return;
    int n = idx >> 8, k = idx & 255;
    const float* W = (n < 64) ? W1 : Wr1;
    int c = (n < 64) ? n : n - 64;
    WT1[idx] = f2b(W[(size_t)k*64 + c]);
  }
}

// ---------------- bf16 MFMA GEMM + optional fp8 side-output for cols<256 ----------------
__launch_bounds__(256)
extern "C" __global__ void k_mgemm(const unsigned short* __restrict__ A,
                                   const unsigned short* __restrict__ WT,
                                   unsigned short* __restrict__ C, int ldc, int M,
                                   int MB, int NCB, unsigned char* __restrict__ qout){
  int id = blockIdx.x;
  int row_blk, col_blk;
  if(NCB == 4){
    int group = id >> 5;
    int r8 = id & 7;
    col_blk = (id >> 3) & 3;
    row_blk = group*8 + r8;
  } else {
    row_blk = id; col_blk = 0;
  }
  if(row_blk >= MB) return;

  __shared__ unsigned short As[128*64];
  __shared__ unsigned short Bs[128*64];
  int t = threadIdx.x;
  int lane = t & 63, wid = t >> 6;
  int wr = wid >> 1, wc = wid & 1;
  int row0 = row_blk*128, col0 = col_blk*128;
  f32x4 acc[4][4] = {};

  for(int k0 = 0; k0 < 256; k0 += 64){
    #pragma unroll
    for(int i=0; i<4; i++){
      int t2 = i*256 + t;
      int r = t2 >> 3;
      int dslot = (t2 & 7) ^ (r & 7);
      int gr = row0 + r; if(gr >= M) gr = M - 1;
      const unsigned short* ga = A + (size_t)gr*256 + k0 + dslot*8;
      __builtin_amdgcn_global_load_lds((const __attribute__((address_space(1))) unsigned*)ga,
          (__attribute__((address_space(3))) unsigned*)(As + i*2048 + wid*512), 16, 0, 0);
      const unsigned short* gb = WT + (size_t)(col0 + r)*256 + k0 + dslot*8;
      __builtin_amdgcn_global_load_lds((const __attribute__((address_space(1))) unsigned*)gb,
          (__attribute__((address_space(3))) unsigned*)(Bs + i*2048 + wid*512), 16, 0, 0);
    }
    __syncthreads();
    #pragma unroll
    for(int kc=0; kc<2; kc++){
      bf16x8 a[4], b[4];
      int kb = kc*4 + (lane >> 4);
      #pragma unroll
      for(int f=0; f<4; f++){
        int ar = wr*64 + f*16 + (lane & 15);
        a[f] = *(const bf16x8*)&As[ar*64 + ((kb ^ (ar & 7))*8)];
        int br = wc*64 + f*16 + (lane & 15);
        b[f] = *(const bf16x8*)&Bs[br*64 + ((kb ^ (br & 7))*8)];
      }
      #pragma unroll
      for(int fm=0; fm<4; fm++)
        #pragma unroll
        for(int fn=0; fn<4; fn++)
          acc[fm][fn] = __builtin_amdgcn_mfma_f32_16x16x32_bf16(a[fm], b[fn], acc[fm][fn], 0, 0, 0);
    }
    __syncthreads();
  }

  int rb = row0 + wr*64 + ((lane >> 4) << 2);
  int cb = col0 + wc*64 + (lane & 15);
  #pragma unroll
  for(int fm=0; fm<4; fm++){
    #pragma unroll
    for(int r=0; r<4; r++){
      int row = rb + fm*16 + r;
      if(row < M){
        #pragma unroll
        for(int fn=0; fn<4; fn++)
          C[(size_t)row*ldc + cb + fn*16] = f2b(acc[fm][fn][r]);
        if(qout){
          #pragma unroll
          for(int fn=0; fn<4; fn++){
            int col = cb + fn*16;
            if(col < 256) qout[(size_t)row*256 + col] = enc8b(acc[fm][fn][r]);
          }
        }
      }
    }
  }
}

// ---------------- attention logits layer0 (bf16 h0) ----------------
extern "C" __global__ void k_al0(const unsigned short* __restrict__ buf0b, const float* __restrict__ as0,
                                 const float* __restrict__ ad0, float* als0, float* ald0, int N){
  int i = blockIdx.x*blockDim.x + threadIdx.x;   // n*8+h
  if(i >= N*8) return;
  int n = i >> 3, h = i & 7;
  const uint4* hp = (const uint4*)(buf0b + (size_t)n*512 + h*32);
  const float* av = as0 + h*32;
  const float* dv = ad0 + h*32;
  float s = 0.f, d = 0.f;
  #pragma unroll
  for(int q=0; q<4; q++){
    uint4 u = hp[q];
    unsigned w[4] = {u.x, u.y, u.z, u.w};
    #pragma unroll
    for(int j=0; j<4; j++){
      float lo = __uint_as_float(w[j] << 16);
      float hi = __uint_as_float(w[j] & 0xFFFF0000u);
      int c = q*8 + j*2;
      s += lo*av[c] + hi*av[c+1];
      d += lo*dv[c] + hi*dv[c+1];
    }
  }
  als0[i] = s; ald0[i] = d;
}

// ---- gather layer0: WAVE-per-node, zero LDS / zero barriers ----
// lane = (edge slot es=lane>>3, head hh=lane&7). Channels: c=lane*4, head h=es.
// Per 8-edge chunk each lane computes one (edge,head) alpha; shfl redistributes.
// No max subtraction: logits are O(+-10) (unit-variance tensors), exp fp32-safe,
// softmax shift-invariant.
__launch_bounds__(256)
extern "C" __global__ void k_gather0(const unsigned short* __restrict__ buf0b,
                                     const unsigned char* __restrict__ h0q,
                                     const float* __restrict__ als0, const float* __restrict__ ald0,
                                     const int* __restrict__ offs, const int* __restrict__ csr,
                                     const float* __restrict__ b0, const float* __restrict__ br0,
                                     unsigned short* __restrict__ h1b, int N){
  int n = blockIdx.x*4 + (threadIdx.x >> 6);
  if(n >= N) return;
  int lane = threadIdx.x & 63;
  int hh = lane & 7;        // head for alpha compute
  int es = lane >> 3;       // edge slot == channel-head h
  int h  = es;
  int c  = lane*4;
  float ald_h = ald0[n*8 + hh];
  int beg = offs[n], end = offs[n+1];

  f32x2 A01 = {0.f, 0.f}, A23 = {0.f, 0.f};
  float den = 0.f;

  for(int chunk = beg; chunk < end; chunk += 8){
    int m = end - chunk; if(m > 8) m = 8;
    bool e_ok = es < m;
    int s = e_ok ? csr[chunk + es] : 0;
    float p = 0.f;
    if(e_ok){
      float v = als0[s*8 + hh] + ald_h;
      v = v > 0.f ? v : NEG_SLOPE*v;
      p = expf(v);
    }
    den += p;
    int sj[8]; float pj[8];
    #pragma unroll
    for(int j=0; j<8; j++){
      sj[j] = __shfl(s, j*8);
      pj[j] = __shfl(p, j*8 + h);
    }
    unsigned q[8];
    #pragma unroll
    for(int j=0; j<8; j++)
      q[j] = *(const unsigned*)(h0q + (size_t)sj[j]*256 + c);
    #pragma unroll
    for(int j=0; j<8; j++){
      f32x2 lo, hi, pv;
      dec8x4v(q[j], lo, hi);
      pv[0] = pj[j]; pv[1] = pj[j];
      A01 += pv*lo; A23 += pv*hi;
    }
  }

  // den: sum over edge slots (lanes sharing hh are stride-8)
  den += __shfl_xor(den, 8);
  den += __shfl_xor(den, 16);
  den += __shfl_xor(den, 32);
  float rden = 1.f/(den + 1e-16f);
  rden = __shfl(rden, h);   // lane h (0..7) holds hh==h

  float a0 = A01[0]*rden, a1 = A01[1]*rden, a2 = A23[0]*rden, a3 = A23[1]*rden;

  float4 bb = *(const float4*)(b0 + c);
  float4 rb = *(const float4*)(br0 + c);
  uint2 ru = *(const uint2*)(buf0b + (size_t)n*512 + 256 + c);
  float o0 = a0 + bb.x + __uint_as_float(ru.x << 16)         + rb.x;
  float o1 = a1 + bb.y + __uint_as_float(ru.x & 0xFFFF0000u) + rb.y;
  float o2 = a2 + bb.z + __uint_as_float(ru.y << 16)         + rb.z;
  float o3 = a3 + bb.w + __uint_as_float(ru.y & 0xFFFF0000u) + rb.w;
  ushort4v o;
  o[0] = f2b(o0 > 0.f ? o0 : expf(o0) - 1.f);
  o[1] = f2b(o1 > 0.f ? o1 : expf(o1) - 1.f);
  o[2] = f2b(o2 > 0.f ? o2 : expf(o2) - 1.f);
  o[3] = f2b(o3 > 0.f ? o3 : expf(o3) - 1.f);
  *(ushort4v*)(h1b + (size_t)n*256 + c) = o;
}

// ---------------- layer1 logits (bf16 g1) ----------------
extern "C" __global__ void k_al1(const unsigned short* __restrict__ buf1b, const float* __restrict__ as1,
                                 const float* __restrict__ ad1, float* als1, float* ald1, int N){
  int n = blockIdx.x*4 + (threadIdx.x >> 6);
  if(n >= N) return;
  int lane = threadIdx.x & 63;
  float g = b2f(buf1b[(size_t)n*128 + lane]);
  float s = g*as1[lane], d = g*ad1[lane];
  #pragma unroll
  for(int o=32; o>0; o>>=1){ s += __shfl_xor(s,o); d += __shfl_xor(d,o); }
  if(lane == 0){ als1[n] = s; ald1[n] = d; }
}

// ---- gather layer1: WAVE-per-node, zero LDS / zero barriers ----
// lane: channel pair ch2=lane&31, edge slot es=lane>>5. Alpha for a 64-edge chunk
// lives in registers (one per lane); shfl broadcasts 8 edges per iteration.
__launch_bounds__(256)
extern "C" __global__ void k_gather1(const unsigned short* __restrict__ buf1b,
                                     const float* __restrict__ als1, const float* __restrict__ ald1,
                                     const int* __restrict__ offs, const int* __restrict__ csr,
                                     const float* __restrict__ b1, const float* __restrict__ br1,
                                     float* __restrict__ out, int N){
  int n = blockIdx.x*4 + (threadIdx.x >> 6);
  if(n >= N) return;
  int lane = threadIdx.x & 63;
  int ch2 = lane & 31;
  int es  = lane >> 5;
  int beg = offs[n], end = offs[n+1];
  float ald_n = ald1[n];

  f32x2 acc = {0.f, 0.f};
  float den = 0.f;

  for(int chunk = beg; chunk < end; chunk += 64){
    int m = end - chunk; if(m > 64) m = 64;
    int s = (lane < m) ? csr[chunk + lane] : 0;
    float p = 0.f;
    if(lane < m){
      float v = als1[s] + ald_n;
      v = v > 0.f ? v : NEG_SLOPE*v;
      p = expf(v);
    }
    den += p;
    for(int base = 0; base < m; base += 8){
      int sv[4]; float pv[4];
      #pragma unroll
      for(int i=0; i<4; i++){
        int j = base + 2*i + es;
        int jj = j & 63;
        int   sx = __shfl(s, jj);
        float px = __shfl(p, jj);
        bool ok = j < m;
        sv[i] = ok ? sx : 0;
        pv[i] = ok ? px : 0.f;
      }
      unsigned uv[4];
      #pragma unroll
      for(int i=0; i<4; i++)
        uv[i] = *(const unsigned*)(buf1b + (size_t)sv[i]*128 + ch2*2);
      #pragma unroll
      for(int i=0; i<4; i++){
        f32x2 f, pp;
        f[0] = __uint_as_float(uv[i] << 16);
        f[1] = __uint_as_float(uv[i] & 0xFFFF0000u);
        pp[0] = pv[i]; pp[1] = pv[i];
        acc += pp*f;
      }
    }
  }

  // merge the two edge-slot halves (lane l <-> l^32)
  acc[0] += __shfl_xor(acc[0], 32);
  acc[1] += __shfl_xor(acc[1], 32);
  // den over all 64 lanes
  #pragma unroll
  for(int o=32; o>0; o>>=1) den += __shfl_xor(den, o);
  float rden = 1.f/(den + 1e-16f);
  acc[0] *= rden; acc[1] *= rden;

  float2 bb = *(const float2*)(b1 + ch2*2);
  float2 rb = *(const float2*)(br1 + ch2*2);
  unsigned ru = *(const unsigned*)(buf1b + (size_t)n*128 + 64 + ch2*2);
  float vx = acc[0] + bb.x + __uint_as_float(ru << 16)         + rb.x;
  float vy = acc[1] + bb.y + __uint_as_float(ru & 0xFFFF0000u) + rb.y;

  float mx = fmaxf(vx, vy);
  #pragma unroll
  for(int o=16; o>0; o>>=1) mx = fmaxf(mx, __shfl_xor(mx, o));
  float sm = expf(vx - mx) + expf(vy - mx);
  #pragma unroll
  for(int o=16; o>0; o>>=1) sm += __shfl_xor(sm, o);
  float l = mx + logf(sm);
  if(es == 0){
    float2 ov; ov.x = vx - l; ov.y = vy - l;
    *(float2*)(out + (size_t)n*64 + ch2*2) = ov;
  }
}

// ---------------- launch ----------------
extern "C" void kernel_launch(void* const* d_in, const int* in_sizes, int n_in,
                              void* d_out, int out_size, void* d_ws, size_t ws_size,
                              hipStream_t stream){
  const float* x   = (const float*)d_in[0];
  const int*   ei  = (const int*)  d_in[1];
  const float* W0  = (const float*)d_in[2];
  const float* as0 = (const float*)d_in[3];
  const float* ad0 = (const float*)d_in[4];
  const float* b0  = (const float*)d_in[5];
  const float* Wr0 = (const float*)d_in[6];
  const float* br0 = (const float*)d_in[7];
  const float* W1  = (const float*)d_in[8];
  const float* as1 = (const float*)d_in[9];
  const float* ad1 = (const float*)d_in[10];
  const float* b1  = (const float*)d_in[11];
  const float* Wr1 = (const float*)d_in[12];
  const float* br1 = (const float*)d_in[13];
  int N = in_sizes[0] / 256;
  int E = in_sizes[1] / 2;
  const int* srcs = ei;
  const int* dsts = ei + E;
  float* out = (float*)d_out;

  // workspace layout (bf16 feature buffers)
  unsigned short* buf0b = (unsigned short*)d_ws;        // N*512 bf16 (h0 | r0)
  unsigned short* xb    = buf0b + (size_t)N*512;        // N*256 bf16 (dead after mgemm0)
  unsigned short* h1b   = xb    + (size_t)N*256;        // N*256 bf16
  unsigned short* buf1b = h1b   + (size_t)N*256;        // N*128 bf16 (g1 | r1)
  unsigned short* WT0   = buf1b + (size_t)N*128;        // 512*256 bf16
  unsigned short* WT1   = WT0   + 512*256;              // 128*256 bf16
  float*    als0 = (float*)(WT1 + 128*256);             // N*8
  float*    ald0 = als0 + (size_t)N*8;                  // N*8
  float*    als1 = ald0 + (size_t)N*8;                  // N
  float*    ald1 = als1 + N;                            // N
  int*      cnt  = (int*)(ald1 + N);                    // N (also cursor)
  int*      offs = cnt + N;                             // N+1
  int*      part = offs + N + 1;                        // 256
  int*      csr  = part + 256;                          // E+N
  // fp8 h0 copy overlays xb (xb dead once mgemm0 has consumed it)
  unsigned char* h0q = (unsigned char*)xb;              // N*256 bytes

  int NB = (N + 255) / 256;
  int ET = E + N;

  // CSR build (cnt zeroed via memset; self loop = +1 in scans)
  hipMemsetAsync(cnt, 0, (size_t)N*sizeof(int), stream);
  hipLaunchKernelGGL(k_count, dim3((E+255)/256), dim3(256), 0, stream, dsts, E, cnt);
  hipLaunchKernelGGL(k_scan_partial, dim3(NB), dim3(256), 0, stream, cnt, part, N);
  hipLaunchKernelGGL(k_scan_ex, dim3(1), dim3(256), 0, stream, part, NB);
  hipLaunchKernelGGL(k_scan_final, dim3(NB), dim3(256), 0, stream, cnt, part, offs, cnt, N);
  hipLaunchKernelGGL(k_scatter, dim3((ET+255)/256), dim3(256), 0, stream, srcs, dsts, E, N, cnt, csr);

  // casts / weight prep
  int n8 = N*256/8;
  hipLaunchKernelGGL(k_cast_x, dim3((n8+255)/256), dim3(256), 0, stream, x, xb, n8);
  hipLaunchKernelGGL(k_wt2, dim3((512*256+128*256+255)/256), dim3(256), 0, stream, W0, Wr0, W1, Wr1, WT0, WT1);

  int MB = (N + 127) / 128;
  int g0 = ((MB + 7) / 8) * 32;
  // layer0: buf0b[N][512] = xb @ [W0|Wr0]; epilogue also writes fp8 h0q (cols<256)
  hipLaunchKernelGGL(k_mgemm, dim3(g0), dim3(256), 0, stream, xb, WT0, buf0b, 512, N, MB, 4, h0q);
  hipLaunchKernelGGL(k_al0, dim3((N*8+255)/256), dim3(256), 0, stream, buf0b, as0, ad0, als0, ald0, N);
  hipLaunchKernelGGL(k_gather0, dim3((N+3)/4), dim3(256), 0, stream, buf0b, h0q, als0, ald0, offs, csr, b0, br0, h1b, N);

  // layer1: buf1b[N][128] = h1b @ [W1|Wr1]
  hipLaunchKernelGGL(k_mgemm, dim3(MB), dim3(256), 0, stream, h1b, WT1, buf1b, 128, N, MB, 1, (unsigned char*)nullptr);
  hipLaunchKernelGGL(k_al1, dim3((N+3)/4), dim3(256), 0, stream, buf1b, as1, ad1, als1, ald1, N);
  hipLaunchKernelGGL(k_gather1, dim3((N+3)/4), dim3(256), 0, stream, buf1b, als1, ald1, offs, csr, b1, br1, out, N);
}

// Round 16
// 208.526 us; speedup vs baseline: 1.6319x; 1.3002x over previous
//
#include <hip/hip_runtime.h>
#include <math.h>

#define NEG_SLOPE 0.2f
#define BSH 7              // 128 nodes per bucket
#define NBLK_PART 256      // partition blocks

typedef __attribute__((ext_vector_type(8))) short bf16x8;
typedef __attribute__((ext_vector_type(4))) float f32x4;
typedef __attribute__((ext_vector_type(2))) float f32x2;
typedef __attribute__((ext_vector_type(8))) unsigned short ushort8;
typedef __attribute__((ext_vector_type(4))) unsigned short ushort4v;

__device__ __forceinline__ float b2f(unsigned short u){
  return __uint_as_float(((unsigned)u) << 16);
}
__device__ __forceinline__ unsigned short f2b(float f){
  unsigned u = __float_as_uint(f);
  return (unsigned short)((u + 0x7FFFu + ((u >> 16) & 1u)) >> 16);
}

// ---- fp8 e4m3fn helpers (hardware cvt if available, bit-twiddle fallback) ----
#if __has_builtin(__builtin_amdgcn_cvt_pk_f32_fp8) && __has_builtin(__builtin_amdgcn_cvt_pk_fp8_f32)
#define HW_FP8 1
#else
#define HW_FP8 0
#endif

#if !HW_FP8
__device__ __forceinline__ unsigned enc8_one(float f){
  unsigned bits = __float_as_uint(f);
  unsigned s = bits >> 31;
  unsigned e = (bits >> 23) & 255;
  unsigned mant = bits & 0x7FFFFF;
  if(e < 121){
    float af = fabsf(f);
    int m = (int)(af * 512.f + 0.5f);
    if(m > 7) m = 7;
    return (s << 7) | (unsigned)m;
  }
  unsigned lsb = (mant >> 20) & 1;
  mant += 0x7FFFF + lsb;
  if(mant >> 23){ e += 1; mant = 0; }
  unsigned m3 = mant >> 20;
  unsigned e8 = e - 120;
  if(e8 > 15 || (e8 == 15 && m3 == 7)) return (s << 7) | 0x7E;
  return (s << 7) | (e8 << 3) | m3;
}
#endif

template<bool HI>
__device__ __forceinline__ unsigned enc8_pair(float a, float b, unsigned old){
#if HW_FP8
  return __builtin_amdgcn_cvt_pk_fp8_f32(a, b, old, HI);  // HI literal (op_sel)
#else
  unsigned p = enc8_one(a) | (enc8_one(b) << 8);
  return HI ? ((old & 0x0000FFFFu) | (p << 16)) : ((old & 0xFFFF0000u) | p);
#endif
}

__device__ __forceinline__ unsigned char enc8b(float v){
  return (unsigned char)(enc8_pair<false>(v, v, 0u) & 0xFFu);
}

__device__ __forceinline__ void dec8x4v(unsigned q, f32x2& lo, f32x2& hi){
#if HW_FP8
  lo = __builtin_amdgcn_cvt_pk_f32_fp8(q, false);
  hi = __builtin_amdgcn_cvt_pk_f32_fp8(q, true);
#else
  auto dec1 = [](unsigned b)->float{
    unsigned s = (b >> 7) & 1, e = (b >> 3) & 15, m = b & 7;
    float v = (e == 0) ? (float)m * 0.001953125f
                       : __uint_as_float(((e + 120) << 23) | (m << 20));
    return s ? -v : v;
  };
  lo[0] = dec1(q & 255); lo[1] = dec1((q >> 8) & 255);
  hi[0] = dec1((q >> 16) & 255); hi[1] = dec1(q >> 24);
#endif
}

// ================= bucket-partitioned CSR build =================
// part1: per-block LDS bucket histogram + range reservation
extern "C" __global__ void k_part1(const int* __restrict__ dsts, int E, int N,
                                   int NBUCK, int* __restrict__ bcnt,
                                   int* __restrict__ blockbase){
  __shared__ int hist[512];
  int blk = blockIdx.x, tid = threadIdx.x;
  for(int b = tid; b < NBUCK; b += 256) hist[b] = 0;
  __syncthreads();
  int ET = E + N;
  int chunk = (ET + NBLK_PART - 1)/NBLK_PART;
  int s0 = blk*chunk, s1 = s0+chunk < ET ? s0+chunk : ET;
  for(int e = s0+tid; e < s1; e += 256){
    int d = (e < E) ? dsts[e] : e - E;
    atomicAdd(&hist[d >> BSH], 1);
  }
  __syncthreads();
  for(int b = tid; b < NBUCK; b += 256)
    blockbase[(size_t)blk*NBUCK + b] = atomicAdd(&bcnt[b], hist[b]);
}

// bscan: exclusive scan of bucket counts (NBUCK <= 512), one block of 512
extern "C" __global__ void k_bscan(const int* __restrict__ bcnt, int* __restrict__ boffs,
                                   int* __restrict__ offs_last, int NBUCK, int ET){
  __shared__ int sc[512], orig[512];
  int t = threadIdx.x;
  int v = (t < NBUCK) ? bcnt[t] : 0;
  sc[t] = v; orig[t] = v;
  __syncthreads();
  for(int st=1; st<512; st<<=1){
    int u = (t >= st) ? sc[t-st] : 0;
    __syncthreads();
    sc[t] += u;
    __syncthreads();
  }
  if(t < NBUCK) boffs[t] = sc[t] - orig[t];
  if(t == 0){ boffs[NBUCK] = ET; *offs_last = ET; }
}

// part2: scatter (dst,src) pairs into block-exclusive sub-ranges
extern "C" __global__ void k_part2(const int* __restrict__ srcs, const int* __restrict__ dsts,
                                   int E, int N, int NBUCK,
                                   const int* __restrict__ boffs, const int* __restrict__ blockbase,
                                   uint2* __restrict__ pairs){
  __shared__ int cur[512];
  int blk = blockIdx.x, tid = threadIdx.x;
  for(int b = tid; b < NBUCK; b += 256)
    cur[b] = boffs[b] + blockbase[(size_t)blk*NBUCK + b];
  __syncthreads();
  int ET = E + N;
  int chunk = (ET + NBLK_PART - 1)/NBLK_PART;
  int s0 = blk*chunk, s1 = s0+chunk < ET ? s0+chunk : ET;
  for(int e = s0+tid; e < s1; e += 256){
    int s, d;
    if(e < E){ s = srcs[e]; d = dsts[e]; } else { s = d = e - E; }
    int pos = atomicAdd(&cur[d >> BSH], 1);
    uint2 pr; pr.x = (unsigned)d; pr.y = (unsigned)s;
    pairs[pos] = pr;
  }
}

// bcsr: per-bucket node-level CSR (LDS hist + scan + scatter), exclusive segment
extern "C" __global__ void k_bcsr(const uint2* __restrict__ pairs, const int* __restrict__ boffs,
                                  int N, int* __restrict__ offs, int* __restrict__ csr){
  __shared__ int hist[128], sc[128], lcur[128];
  int b = blockIdx.x, tid = threadIdx.x;
  int node0 = b << BSH;
  int base = boffs[b], endp = boffs[b+1];
  if(tid < 128) hist[tid] = 0;
  __syncthreads();
  for(int i = base + tid; i < endp; i += 256)
    atomicAdd(&hist[pairs[i].x & 127], 1);
  __syncthreads();
  if(tid < 128) sc[tid] = hist[tid];
  __syncthreads();
  for(int st=1; st<128; st<<=1){
    int u = (tid < 128 && tid >= st) ? sc[tid-st] : 0;
    __syncthreads();
    if(tid < 128) sc[tid] += u;
    __syncthreads();
  }
  if(tid < 128){
    int ex = sc[tid] - hist[tid];
    lcur[tid] = ex;
    int n = node0 + tid;
    if(n < N) offs[n] = base + ex;
  }
  __syncthreads();
  for(int i = base + tid; i < endp; i += 256){
    uint2 pr = pairs[i];
    int pos = atomicAdd(&lcur[pr.x & 127], 1);
    csr[base + pos] = (int)pr.y;
  }
}

// ---------------- fp32 -> bf16 cast (8 elems/thread) ----------------
extern "C" __global__ void k_cast_x(const float* __restrict__ x, unsigned short* __restrict__ xb, int n8){
  int i = blockIdx.x*blockDim.x + threadIdx.x;
  if(i >= n8) return;
  const float4* p = (const float4*)(x + (size_t)i*8);
  float4 v0 = p[0], v1 = p[1];
  ushort8 o;
  o[0]=f2b(v0.x); o[1]=f2b(v0.y); o[2]=f2b(v0.z); o[3]=f2b(v0.w);
  o[4]=f2b(v1.x); o[5]=f2b(v1.y); o[6]=f2b(v1.z); o[7]=f2b(v1.w);
  *(ushort8*)(xb + (size_t)i*8) = o;
}

// ---------------- weight transpose+concat (both layers, one launch) ----------------
extern "C" __global__ void k_wt2(const float* __restrict__ W0, const float* __restrict__ Wr0,
                                 const float* __restrict__ W1, const float* __restrict__ Wr1,
                                 unsigned short* __restrict__ WT0, unsigned short* __restrict__ WT1){
  int idx = blockIdx.x*256 + threadIdx.x;
  const int tot0 = 512*256;
  if(idx < tot0){
    int n = idx >> 8, k = idx & 255;
    const float* W = (n < 256) ? W0 : Wr0;
    int c = (n < 256) ? n : n - 256;
    WT0[idx] = f2b(W[(size_t)k*256 + c]);
  } else {
    idx -= tot0;
    if(idx >= 128*256) return;
    int n = idx >> 8, k = idx & 255;
    const float* W = (n < 64) ? W1 : Wr1;
    int c = (n < 64) ? n : n - 64;
    WT1[idx] = f2b(W[(size_t)k*64 + c]);
  }
}

// ---------------- bf16 MFMA GEMM + optional fp8 side-output for cols<256 ----------------
__launch_bounds__(256)
extern "C" __global__ void k_mgemm(const unsigned short* __restrict__ A,
                                   const unsigned short* __restrict__ WT,
                                   unsigned short* __restrict__ C, int ldc, int M,
                                   int MB, int NCB, unsigned char* __restrict__ qout){
  int id = blockIdx.x;
  int row_blk, col_blk;
  if(NCB == 4){
    int group = id >> 5;
    int r8 = id & 7;
    col_blk = (id >> 3) & 3;
    row_blk = group*8 + r8;
  } else {
    row_blk = id; col_blk = 0;
  }
  if(row_blk >= MB) return;

  __shared__ unsigned short As[128*64];
  __shared__ unsigned short Bs[128*64];
  int t = threadIdx.x;
  int lane = t & 63, wid = t >> 6;
  int wr = wid >> 1, wc = wid & 1;
  int row0 = row_blk*128, col0 = col_blk*128;
  f32x4 acc[4][4] = {};

  for(int k0 = 0; k0 < 256; k0 += 64){
    #pragma unroll
    for(int i=0; i<4; i++){
      int t2 = i*256 + t;
      int r = t2 >> 3;
      int dslot = (t2 & 7) ^ (r & 7);
      int gr = row0 + r; if(gr >= M) gr = M - 1;
      const unsigned short* ga = A + (size_t)gr*256 + k0 + dslot*8;
      __builtin_amdgcn_global_load_lds((const __attribute__((address_space(1))) unsigned*)ga,
          (__attribute__((address_space(3))) unsigned*)(As + i*2048 + wid*512), 16, 0, 0);
      const unsigned short* gb = WT + (size_t)(col0 + r)*256 + k0 + dslot*8;
      __builtin_amdgcn_global_load_lds((const __attribute__((address_space(1))) unsigned*)gb,
          (__attribute__((address_space(3))) unsigned*)(Bs + i*2048 + wid*512), 16, 0, 0);
    }
    __syncthreads();
    #pragma unroll
    for(int kc=0; kc<2; kc++){
      bf16x8 a[4], b[4];
      int kb = kc*4 + (lane >> 4);
      #pragma unroll
      for(int f=0; f<4; f++){
        int ar = wr*64 + f*16 + (lane & 15);
        a[f] = *(const bf16x8*)&As[ar*64 + ((kb ^ (ar & 7))*8)];
        int br = wc*64 + f*16 + (lane & 15);
        b[f] = *(const bf16x8*)&Bs[br*64 + ((kb ^ (br & 7))*8)];
      }
      #pragma unroll
      for(int fm=0; fm<4; fm++)
        #pragma unroll
        for(int fn=0; fn<4; fn++)
          acc[fm][fn] = __builtin_amdgcn_mfma_f32_16x16x32_bf16(a[fm], b[fn], acc[fm][fn], 0, 0, 0);
    }
    __syncthreads();
  }

  int rb = row0 + wr*64 + ((lane >> 4) << 2);
  int cb = col0 + wc*64 + (lane & 15);
  #pragma unroll
  for(int fm=0; fm<4; fm++){
    #pragma unroll
    for(int r=0; r<4; r++){
      int row = rb + fm*16 + r;
      if(row < M){
        #pragma unroll
        for(int fn=0; fn<4; fn++)
          C[(size_t)row*ldc + cb + fn*16] = f2b(acc[fm][fn][r]);
        if(qout){
          #pragma unroll
          for(int fn=0; fn<4; fn++){
            int col = cb + fn*16;
            if(col < 256) qout[(size_t)row*256 + col] = enc8b(acc[fm][fn][r]);
          }
        }
      }
    }
  }
}

// ---------------- attention logits layer0 (bf16 h0) ----------------
extern "C" __global__ void k_al0(const unsigned short* __restrict__ buf0b, const float* __restrict__ as0,
                                 const float* __restrict__ ad0, float* als0, float* ald0, int N){
  int i = blockIdx.x*blockDim.x + threadIdx.x;   // n*8+h
  if(i >= N*8) return;
  int n = i >> 3, h = i & 7;
  const uint4* hp = (const uint4*)(buf0b + (size_t)n*512 + h*32);
  const float* av = as0 + h*32;
  const float* dv = ad0 + h*32;
  float s = 0.f, d = 0.f;
  #pragma unroll
  for(int q=0; q<4; q++){
    uint4 u = hp[q];
    unsigned w[4] = {u.x, u.y, u.z, u.w};
    #pragma unroll
    for(int j=0; j<4; j++){
      float lo = __uint_as_float(w[j] << 16);
      float hi = __uint_as_float(w[j] & 0xFFFF0000u);
      int c = q*8 + j*2;
      s += lo*av[c] + hi*av[c+1];
      d += lo*dv[c] + hi*dv[c+1];
    }
  }
  als0[i] = s; ald0[i] = d;
}

// ---- gather layer0: WAVE-per-node, zero LDS / zero barriers ----
// lane = (edge slot es=lane>>3, head hh=lane&7). Channels: c=lane*4, head h=es.
// No max subtraction: logits are O(+-10) (unit-variance tensors), exp fp32-safe,
// softmax shift-invariant.
__launch_bounds__(256)
extern "C" __global__ void k_gather0(const unsigned short* __restrict__ buf0b,
                                     const unsigned char* __restrict__ h0q,
                                     const float* __restrict__ als0, const float* __restrict__ ald0,
                                     const int* __restrict__ offs, const int* __restrict__ csr,
                                     const float* __restrict__ b0, const float* __restrict__ br0,
                                     unsigned short* __restrict__ h1b, int N){
  int n = blockIdx.x*4 + (threadIdx.x >> 6);
  if(n >= N) return;
  int lane = threadIdx.x & 63;
  int hh = lane & 7;        // head for alpha compute
  int es = lane >> 3;       // edge slot == channel-head h
  int h  = es;
  int c  = lane*4;
  float ald_h = ald0[n*8 + hh];
  int beg = offs[n], end = offs[n+1];

  f32x2 A01 = {0.f, 0.f}, A23 = {0.f, 0.f};
  float den = 0.f;

  for(int chunk = beg; chunk < end; chunk += 8){
    int m = end - chunk; if(m > 8) m = 8;
    bool e_ok = es < m;
    int s = e_ok ? csr[chunk + es] : 0;
    float p = 0.f;
    if(e_ok){
      float v = als0[s*8 + hh] + ald_h;
      v = v > 0.f ? v : NEG_SLOPE*v;
      p = expf(v);
    }
    den += p;
    int sj[8]; float pj[8];
    #pragma unroll
    for(int j=0; j<8; j++){
      sj[j] = __shfl(s, j*8);
      pj[j] = __shfl(p, j*8 + h);
    }
    unsigned q[8];
    #pragma unroll
    for(int j=0; j<8; j++)
      q[j] = *(const unsigned*)(h0q + (size_t)sj[j]*256 + c);
    #pragma unroll
    for(int j=0; j<8; j++){
      f32x2 lo, hi, pv;
      dec8x4v(q[j], lo, hi);
      pv[0] = pj[j]; pv[1] = pj[j];
      A01 += pv*lo; A23 += pv*hi;
    }
  }

  den += __shfl_xor(den, 8);
  den += __shfl_xor(den, 16);
  den += __shfl_xor(den, 32);
  float rden = 1.f/(den + 1e-16f);
  rden = __shfl(rden, h);

  float a0 = A01[0]*rden, a1 = A01[1]*rden, a2 = A23[0]*rden, a3 = A23[1]*rden;

  float4 bb = *(const float4*)(b0 + c);
  float4 rb = *(const float4*)(br0 + c);
  uint2 ru = *(const uint2*)(buf0b + (size_t)n*512 + 256 + c);
  float o0 = a0 + bb.x + __uint_as_float(ru.x << 16)         + rb.x;
  float o1 = a1 + bb.y + __uint_as_float(ru.x & 0xFFFF0000u) + rb.y;
  float o2 = a2 + bb.z + __uint_as_float(ru.y << 16)         + rb.z;
  float o3 = a3 + bb.w + __uint_as_float(ru.y & 0xFFFF0000u) + rb.w;
  ushort4v o;
  o[0] = f2b(o0 > 0.f ? o0 : expf(o0) - 1.f);
  o[1] = f2b(o1 > 0.f ? o1 : expf(o1) - 1.f);
  o[2] = f2b(o2 > 0.f ? o2 : expf(o2) - 1.f);
  o[3] = f2b(o3 > 0.f ? o3 : expf(o3) - 1.f);
  *(ushort4v*)(h1b + (size_t)n*256 + c) = o;
}

// ---------------- layer1 logits (bf16 g1) ----------------
extern "C" __global__ void k_al1(const unsigned short* __restrict__ buf1b, const float* __restrict__ as1,
                                 const float* __restrict__ ad1, float* als1, float* ald1, int N){
  int n = blockIdx.x*4 + (threadIdx.x >> 6);
  if(n >= N) return;
  int lane = threadIdx.x & 63;
  float g = b2f(buf1b[(size_t)n*128 + lane]);
  float s = g*as1[lane], d = g*ad1[lane];
  #pragma unroll
  for(int o=32; o>0; o>>=1){ s += __shfl_xor(s,o); d += __shfl_xor(d,o); }
  if(lane == 0){ als1[n] = s; ald1[n] = d; }
}

// ---- gather layer1: WAVE-per-node, zero LDS / zero barriers ----
__launch_bounds__(256)
extern "C" __global__ void k_gather1(const unsigned short* __restrict__ buf1b,
                                     const float* __restrict__ als1, const float* __restrict__ ald1,
                                     const int* __restrict__ offs, const int* __restrict__ csr,
                                     const float* __restrict__ b1, const float* __restrict__ br1,
                                     float* __restrict__ out, int N){
  int n = blockIdx.x*4 + (threadIdx.x >> 6);
  if(n >= N) return;
  int lane = threadIdx.x & 63;
  int ch2 = lane & 31;
  int es  = lane >> 5;
  int beg = offs[n], end = offs[n+1];
  float ald_n = ald1[n];

  f32x2 acc = {0.f, 0.f};
  float den = 0.f;

  for(int chunk = beg; chunk < end; chunk += 64){
    int m = end - chunk; if(m > 64) m = 64;
    int s = (lane < m) ? csr[chunk + lane] : 0;
    float p = 0.f;
    if(lane < m){
      float v = als1[s] + ald_n;
      v = v > 0.f ? v : NEG_SLOPE*v;
      p = expf(v);
    }
    den += p;
    for(int base = 0; base < m; base += 8){
      int sv[4]; float pv[4];
      #pragma unroll
      for(int i=0; i<4; i++){
        int j = base + 2*i + es;
        int jj = j & 63;
        int   sx = __shfl(s, jj);
        float px = __shfl(p, jj);
        bool ok = j < m;
        sv[i] = ok ? sx : 0;
        pv[i] = ok ? px : 0.f;
      }
      unsigned uv[4];
      #pragma unroll
      for(int i=0; i<4; i++)
        uv[i] = *(const unsigned*)(buf1b + (size_t)sv[i]*128 + ch2*2);
      #pragma unroll
      for(int i=0; i<4; i++){
        f32x2 f, pp;
        f[0] = __uint_as_float(uv[i] << 16);
        f[1] = __uint_as_float(uv[i] & 0xFFFF0000u);
        pp[0] = pv[i]; pp[1] = pv[i];
        acc += pp*f;
      }
    }
  }

  acc[0] += __shfl_xor(acc[0], 32);
  acc[1] += __shfl_xor(acc[1], 32);
  #pragma unroll
  for(int o=32; o>0; o>>=1) den += __shfl_xor(den, o);
  float rden = 1.f/(den + 1e-16f);
  acc[0] *= rden; acc[1] *= rden;

  float2 bb = *(const float2*)(b1 + ch2*2);
  float2 rb = *(const float2*)(br1 + ch2*2);
  unsigned ru = *(const unsigned*)(buf1b + (size_t)n*128 + 64 + ch2*2);
  float vx = acc[0] + bb.x + __uint_as_float(ru << 16)         + rb.x;
  float vy = acc[1] + bb.y + __uint_as_float(ru & 0xFFFF0000u) + rb.y;

  float mx = fmaxf(vx, vy);
  #pragma unroll
  for(int o=16; o>0; o>>=1) mx = fmaxf(mx, __shfl_xor(mx, o));
  float sm = expf(vx - mx) + expf(vy - mx);
  #pragma unroll
  for(int o=16; o>0; o>>=1) sm += __shfl_xor(sm, o);
  float l = mx + logf(sm);
  if(es == 0){
    float2 ov; ov.x = vx - l; ov.y = vy - l;
    *(float2*)(out + (size_t)n*64 + ch2*2) = ov;
  }
}

// ---------------- launch ----------------
extern "C" void kernel_launch(void* const* d_in, const int* in_sizes, int n_in,
                              void* d_out, int out_size, void* d_ws, size_t ws_size,
                              hipStream_t stream){
  const float* x   = (const float*)d_in[0];
  const int*   ei  = (const int*)  d_in[1];
  const float* W0  = (const float*)d_in[2];
  const float* as0 = (const float*)d_in[3];
  const float* ad0 = (const float*)d_in[4];
  const float* b0  = (const float*)d_in[5];
  const float* Wr0 = (const float*)d_in[6];
  const float* br0 = (const float*)d_in[7];
  const float* W1  = (const float*)d_in[8];
  const float* as1 = (const float*)d_in[9];
  const float* ad1 = (const float*)d_in[10];
  const float* b1  = (const float*)d_in[11];
  const float* Wr1 = (const float*)d_in[12];
  const float* br1 = (const float*)d_in[13];
  int N = in_sizes[0] / 256;
  int E = in_sizes[1] / 2;
  const int* srcs = ei;
  const int* dsts = ei + E;
  float* out = (float*)d_out;

  int ET = E + N;
  int NBUCK = (N + 127) >> BSH;   // 128 nodes per bucket

  // workspace layout
  unsigned short* buf0b = (unsigned short*)d_ws;        // N*512 bf16 (h0 | r0)
  unsigned short* xb    = buf0b + (size_t)N*512;        // N*256 bf16 (dead after mgemm0)
  unsigned short* h1b   = xb    + (size_t)N*256;        // N*256 bf16
  unsigned short* buf1b = h1b   + (size_t)N*256;        // N*128 bf16 (g1 | r1)
  unsigned short* WT0   = buf1b + (size_t)N*128;        // 512*256 bf16
  unsigned short* WT1   = WT0   + 512*256;              // 128*256 bf16
  float*    als0 = (float*)(WT1 + 128*256);             // N*8
  float*    ald0 = als0 + (size_t)N*8;                  // N*8
  float*    als1 = ald0 + (size_t)N*8;                  // N
  float*    ald1 = als1 + N;                            // N
  int*      offs = (int*)(ald1 + N);                    // N+1
  int*      bcnt = offs + N + 1;                        // NBUCK
  int*      boffs = bcnt + NBUCK;                       // NBUCK+1
  int*      blockbase = boffs + NBUCK + 1;              // NBLK_PART*NBUCK
  int*      csr  = blockbase + (size_t)NBLK_PART*NBUCK; // ET
  uint2*    pairs = (uint2*)(csr + ET);                 // ET uint2 (8B aligned: ET even-ish; force align)
  pairs = (uint2*)(((uintptr_t)pairs + 7) & ~(uintptr_t)7);
  // fp8 h0 copy overlays xb (xb dead once mgemm0 has consumed it)
  unsigned char* h0q = (unsigned char*)xb;              // N*256 bytes

  // ---- CSR build: bucket partition ----
  hipMemsetAsync(bcnt, 0, (size_t)NBUCK*sizeof(int), stream);
  hipLaunchKernelGGL(k_part1, dim3(NBLK_PART), dim3(256), 0, stream, dsts, E, N, NBUCK, bcnt, blockbase);
  hipLaunchKernelGGL(k_bscan, dim3(1), dim3(512), 0, stream, bcnt, boffs, offs + N, NBUCK, ET);
  hipLaunchKernelGGL(k_part2, dim3(NBLK_PART), dim3(256), 0, stream, srcs, dsts, E, N, NBUCK, boffs, blockbase, pairs);
  hipLaunchKernelGGL(k_bcsr, dim3(NBUCK), dim3(256), 0, stream, pairs, boffs, N, offs, csr);

  // casts / weight prep
  int n8 = N*256/8;
  hipLaunchKernelGGL(k_cast_x, dim3((n8+255)/256), dim3(256), 0, stream, x, xb, n8);
  hipLaunchKernelGGL(k_wt2, dim3((512*256+128*256+255)/256), dim3(256), 0, stream, W0, Wr0, W1, Wr1, WT0, WT1);

  int MB = (N + 127) / 128;
  int g0 = ((MB + 7) / 8) * 32;
  // layer0: buf0b[N][512] = xb @ [W0|Wr0]; epilogue also writes fp8 h0q (cols<256)
  hipLaunchKernelGGL(k_mgemm, dim3(g0), dim3(256), 0, stream, xb, WT0, buf0b, 512, N, MB, 4, h0q);
  hipLaunchKernelGGL(k_al0, dim3((N*8+255)/256), dim3(256), 0, stream, buf0b, as0, ad0, als0, ald0, N);
  hipLaunchKernelGGL(k_gather0, dim3((N+3)/4), dim3(256), 0, stream, buf0b, h0q, als0, ald0, offs, csr, b0, br0, h1b, N);

  // layer1: buf1b[N][128] = h1b @ [W1|Wr1]
  hipLaunchKernelGGL(k_mgemm, dim3(MB), dim3(256), 0, stream, h1b, WT1, buf1b, 128, N, MB, 1, (unsigned char*)nullptr);
  hipLaunchKernelGGL(k_al1, dim3((N+3)/4), dim3(256), 0, stream, buf1b, as1, ad1, als1, ald1, N);
  hipLaunchKernelGGL(k_gather1, dim3((N+3)/4), dim3(256), 0, stream, buf1b, als1, ald1, offs, csr, b1, br1, out, N);
}

// Round 17
// 201.616 us; speedup vs baseline: 1.6879x; 1.0343x over previous
//
#include <hip/hip_runtime.h>
#include <math.h>

#define NEG_SLOPE 0.2f
#define BSH 7              // 128 nodes per bucket
#define NBLK_PART 256      // partition blocks

typedef __attribute__((ext_vector_type(8))) short bf16x8;
typedef __attribute__((ext_vector_type(4))) float f32x4;
typedef __attribute__((ext_vector_type(2))) float f32x2;
typedef __attribute__((ext_vector_type(8))) unsigned short ushort8;
typedef __attribute__((ext_vector_type(4))) unsigned short ushort4v;

__device__ __forceinline__ float b2f(unsigned short u){
  return __uint_as_float(((unsigned)u) << 16);
}
__device__ __forceinline__ unsigned short f2b(float f){
  unsigned u = __float_as_uint(f);
  return (unsigned short)((u + 0x7FFFu + ((u >> 16) & 1u)) >> 16);
}

// ---- fp8 e4m3fn helpers (hardware cvt if available, bit-twiddle fallback) ----
#if __has_builtin(__builtin_amdgcn_cvt_pk_f32_fp8) && __has_builtin(__builtin_amdgcn_cvt_pk_fp8_f32)
#define HW_FP8 1
#else
#define HW_FP8 0
#endif

#if !HW_FP8
__device__ __forceinline__ unsigned enc8_one(float f){
  unsigned bits = __float_as_uint(f);
  unsigned s = bits >> 31;
  unsigned e = (bits >> 23) & 255;
  unsigned mant = bits & 0x7FFFFF;
  if(e < 121){
    float af = fabsf(f);
    int m = (int)(af * 512.f + 0.5f);
    if(m > 7) m = 7;
    return (s << 7) | (unsigned)m;
  }
  unsigned lsb = (mant >> 20) & 1;
  mant += 0x7FFFF + lsb;
  if(mant >> 23){ e += 1; mant = 0; }
  unsigned m3 = mant >> 20;
  unsigned e8 = e - 120;
  if(e8 > 15 || (e8 == 15 && m3 == 7)) return (s << 7) | 0x7E;
  return (s << 7) | (e8 << 3) | m3;
}
#endif

template<bool HI>
__device__ __forceinline__ unsigned enc8_pair(float a, float b, unsigned old){
#if HW_FP8
  return __builtin_amdgcn_cvt_pk_fp8_f32(a, b, old, HI);  // HI literal (op_sel)
#else
  unsigned p = enc8_one(a) | (enc8_one(b) << 8);
  return HI ? ((old & 0x0000FFFFu) | (p << 16)) : ((old & 0xFFFF0000u) | p);
#endif
}

__device__ __forceinline__ unsigned char enc8b(float v){
  return (unsigned char)(enc8_pair<false>(v, v, 0u) & 0xFFu);
}

__device__ __forceinline__ void dec8x4v(unsigned q, f32x2& lo, f32x2& hi){
#if HW_FP8
  lo = __builtin_amdgcn_cvt_pk_f32_fp8(q, false);
  hi = __builtin_amdgcn_cvt_pk_f32_fp8(q, true);
#else
  auto dec1 = [](unsigned b)->float{
    unsigned s = (b >> 7) & 1, e = (b >> 3) & 15, m = b & 7;
    float v = (e == 0) ? (float)m * 0.001953125f
                       : __uint_as_float(((e + 120) << 23) | (m << 20));
    return s ? -v : v;
  };
  lo[0] = dec1(q & 255); lo[1] = dec1((q >> 8) & 255);
  hi[0] = dec1((q >> 16) & 255); hi[1] = dec1(q >> 24);
#endif
}

// ================= bucket-partitioned CSR build =================
extern "C" __global__ void k_part1(const int* __restrict__ dsts, int E, int N,
                                   int NBUCK, int* __restrict__ bcnt,
                                   int* __restrict__ blockbase){
  __shared__ int hist[512];
  int blk = blockIdx.x, tid = threadIdx.x;
  for(int b = tid; b < NBUCK; b += 256) hist[b] = 0;
  __syncthreads();
  int ET = E + N;
  int chunk = (ET + NBLK_PART - 1)/NBLK_PART;
  int s0 = blk*chunk, s1 = s0+chunk < ET ? s0+chunk : ET;
  for(int e = s0+tid; e < s1; e += 256){
    int d = (e < E) ? dsts[e] : e - E;
    atomicAdd(&hist[d >> BSH], 1);
  }
  __syncthreads();
  for(int b = tid; b < NBUCK; b += 256)
    blockbase[(size_t)blk*NBUCK + b] = atomicAdd(&bcnt[b], hist[b]);
}

extern "C" __global__ void k_bscan(const int* __restrict__ bcnt, int* __restrict__ boffs,
                                   int* __restrict__ offs_last, int NBUCK, int ET){
  __shared__ int sc[512], orig[512];
  int t = threadIdx.x;
  int v = (t < NBUCK) ? bcnt[t] : 0;
  sc[t] = v; orig[t] = v;
  __syncthreads();
  for(int st=1; st<512; st<<=1){
    int u = (t >= st) ? sc[t-st] : 0;
    __syncthreads();
    sc[t] += u;
    __syncthreads();
  }
  if(t < NBUCK) boffs[t] = sc[t] - orig[t];
  if(t == 0){ boffs[NBUCK] = ET; *offs_last = ET; }
}

extern "C" __global__ void k_part2(const int* __restrict__ srcs, const int* __restrict__ dsts,
                                   int E, int N, int NBUCK,
                                   const int* __restrict__ boffs, const int* __restrict__ blockbase,
                                   uint2* __restrict__ pairs){
  __shared__ int cur[512];
  int blk = blockIdx.x, tid = threadIdx.x;
  for(int b = tid; b < NBUCK; b += 256)
    cur[b] = boffs[b] + blockbase[(size_t)blk*NBUCK + b];
  __syncthreads();
  int ET = E + N;
  int chunk = (ET + NBLK_PART - 1)/NBLK_PART;
  int s0 = blk*chunk, s1 = s0+chunk < ET ? s0+chunk : ET;
  for(int e = s0+tid; e < s1; e += 256){
    int s, d;
    if(e < E){ s = srcs[e]; d = dsts[e]; } else { s = d = e - E; }
    int pos = atomicAdd(&cur[d >> BSH], 1);
    uint2 pr; pr.x = (unsigned)d; pr.y = (unsigned)s;
    pairs[pos] = pr;
  }
}

extern "C" __global__ void k_bcsr(const uint2* __restrict__ pairs, const int* __restrict__ boffs,
                                  int N, int* __restrict__ offs, int* __restrict__ csr){
  __shared__ int hist[128], sc[128], lcur[128];
  int b = blockIdx.x, tid = threadIdx.x;
  int node0 = b << BSH;
  int base = boffs[b], endp = boffs[b+1];
  if(tid < 128) hist[tid] = 0;
  __syncthreads();
  for(int i = base + tid; i < endp; i += 256)
    atomicAdd(&hist[pairs[i].x & 127], 1);
  __syncthreads();
  if(tid < 128) sc[tid] = hist[tid];
  __syncthreads();
  for(int st=1; st<128; st<<=1){
    int u = (tid < 128 && tid >= st) ? sc[tid-st] : 0;
    __syncthreads();
    if(tid < 128) sc[tid] += u;
    __syncthreads();
  }
  if(tid < 128){
    int ex = sc[tid] - hist[tid];
    lcur[tid] = ex;
    int n = node0 + tid;
    if(n < N) offs[n] = base + ex;
  }
  __syncthreads();
  for(int i = base + tid; i < endp; i += 256){
    uint2 pr = pairs[i];
    int pos = atomicAdd(&lcur[pr.x & 127], 1);
    csr[base + pos] = (int)pr.y;
  }
}

// ---------------- weight transpose+concat (both layers, one launch) ----------------
extern "C" __global__ void k_wt2(const float* __restrict__ W0, const float* __restrict__ Wr0,
                                 const float* __restrict__ W1, const float* __restrict__ Wr1,
                                 unsigned short* __restrict__ WT0, unsigned short* __restrict__ WT1){
  int idx = blockIdx.x*256 + threadIdx.x;
  const int tot0 = 512*256;
  if(idx < tot0){
    int n = idx >> 8, k = idx & 255;
    const float* W = (n < 256) ? W0 : Wr0;
    int c = (n < 256) ? n : n - 256;
    WT0[idx] = f2b(W[(size_t)k*256 + c]);
  } else {
    idx -= tot0;
    if(idx >= 128*256) return;
    int n = idx >> 8, k = idx & 255;
    const float* W = (n < 64) ? W1 : Wr1;
    int c = (n < 64) ? n : n - 64;
    WT1[idx] = f2b(W[(size_t)k*64 + c]);
  }
}

// ---------------- bf16 MFMA GEMM; A from bf16 (gload_lds) or fp32 (reg-convert) ----------------
// optional fp8 side-output for cols < qcols.
__launch_bounds__(256)
extern "C" __global__ void k_mgemm(const unsigned short* __restrict__ A,
                                   const float* __restrict__ Afp,
                                   const unsigned short* __restrict__ WT,
                                   unsigned short* __restrict__ C, int ldc, int M,
                                   int MB, int NCB,
                                   unsigned char* __restrict__ qout, int qcols){
  int id = blockIdx.x;
  int row_blk, col_blk;
  if(NCB == 4){
    int group = id >> 5;
    int r8 = id & 7;
    col_blk = (id >> 3) & 3;
    row_blk = group*8 + r8;
  } else {
    row_blk = id; col_blk = 0;
  }
  if(row_blk >= MB) return;

  __shared__ unsigned short As[128*64];
  __shared__ unsigned short Bs[128*64];
  int t = threadIdx.x;
  int lane = t & 63, wid = t >> 6;
  int wr = wid >> 1, wc = wid & 1;
  int row0 = row_blk*128, col0 = col_blk*128;
  f32x4 acc[4][4] = {};

  for(int k0 = 0; k0 < 256; k0 += 64){
    if(Afp){
      // reg-staged fp32 A -> bf16 -> LDS (same swizzled placement as gload_lds path)
      #pragma unroll
      for(int i=0; i<4; i++){
        int t2 = i*256 + t;
        int r = t2 >> 3;
        int dslot = (t2 & 7) ^ (r & 7);
        int gr = row0 + r; if(gr >= M) gr = M - 1;
        const float* ga = Afp + (size_t)gr*256 + k0 + dslot*8;
        float4 v0 = *(const float4*)ga;
        float4 v1 = *(const float4*)(ga + 4);
        ushort8 o;
        o[0]=f2b(v0.x); o[1]=f2b(v0.y); o[2]=f2b(v0.z); o[3]=f2b(v0.w);
        o[4]=f2b(v1.x); o[5]=f2b(v1.y); o[6]=f2b(v1.z); o[7]=f2b(v1.w);
        *(ushort8*)(As + i*2048 + wid*512 + lane*8) = o;
      }
    } else {
      #pragma unroll
      for(int i=0; i<4; i++){
        int t2 = i*256 + t;
        int r = t2 >> 3;
        int dslot = (t2 & 7) ^ (r & 7);
        int gr = row0 + r; if(gr >= M) gr = M - 1;
        const unsigned short* ga = A + (size_t)gr*256 + k0 + dslot*8;
        __builtin_amdgcn_global_load_lds((const __attribute__((address_space(1))) unsigned*)ga,
            (__attribute__((address_space(3))) unsigned*)(As + i*2048 + wid*512), 16, 0, 0);
      }
    }
    #pragma unroll
    for(int i=0; i<4; i++){
      int t2 = i*256 + t;
      int r = t2 >> 3;
      int dslot = (t2 & 7) ^ (r & 7);
      const unsigned short* gb = WT + (size_t)(col0 + r)*256 + k0 + dslot*8;
      __builtin_amdgcn_global_load_lds((const __attribute__((address_space(1))) unsigned*)gb,
          (__attribute__((address_space(3))) unsigned*)(Bs + i*2048 + wid*512), 16, 0, 0);
    }
    __syncthreads();
    #pragma unroll
    for(int kc=0; kc<2; kc++){
      bf16x8 a[4], b[4];
      int kb = kc*4 + (lane >> 4);
      #pragma unroll
      for(int f=0; f<4; f++){
        int ar = wr*64 + f*16 + (lane & 15);
        a[f] = *(const bf16x8*)&As[ar*64 + ((kb ^ (ar & 7))*8)];
        int br = wc*64 + f*16 + (lane & 15);
        b[f] = *(const bf16x8*)&Bs[br*64 + ((kb ^ (br & 7))*8)];
      }
      #pragma unroll
      for(int fm=0; fm<4; fm++)
        #pragma unroll
        for(int fn=0; fn<4; fn++)
          acc[fm][fn] = __builtin_amdgcn_mfma_f32_16x16x32_bf16(a[fm], b[fn], acc[fm][fn], 0, 0, 0);
    }
    __syncthreads();
  }

  int rb = row0 + wr*64 + ((lane >> 4) << 2);
  int cb = col0 + wc*64 + (lane & 15);
  #pragma unroll
  for(int fm=0; fm<4; fm++){
    #pragma unroll
    for(int r=0; r<4; r++){
      int row = rb + fm*16 + r;
      if(row < M){
        #pragma unroll
        for(int fn=0; fn<4; fn++)
          C[(size_t)row*ldc + cb + fn*16] = f2b(acc[fm][fn][r]);
        if(qout){
          #pragma unroll
          for(int fn=0; fn<4; fn++){
            int col = cb + fn*16;
            if(col < qcols) qout[(size_t)row*qcols + col] = enc8b(acc[fm][fn][r]);
          }
        }
      }
    }
  }
}

// ---------------- attention logits layer0 (bf16 h0) ----------------
extern "C" __global__ void k_al0(const unsigned short* __restrict__ buf0b, const float* __restrict__ as0,
                                 const float* __restrict__ ad0, float* als0, float* ald0, int N){
  int i = blockIdx.x*blockDim.x + threadIdx.x;   // n*8+h
  if(i >= N*8) return;
  int n = i >> 3, h = i & 7;
  const uint4* hp = (const uint4*)(buf0b + (size_t)n*512 + h*32);
  const float* av = as0 + h*32;
  const float* dv = ad0 + h*32;
  float s = 0.f, d = 0.f;
  #pragma unroll
  for(int q=0; q<4; q++){
    uint4 u = hp[q];
    unsigned w[4] = {u.x, u.y, u.z, u.w};
    #pragma unroll
    for(int j=0; j<4; j++){
      float lo = __uint_as_float(w[j] << 16);
      float hi = __uint_as_float(w[j] & 0xFFFF0000u);
      int c = q*8 + j*2;
      s += lo*av[c] + hi*av[c+1];
      d += lo*dv[c] + hi*dv[c+1];
    }
  }
  als0[i] = s; ald0[i] = d;
}

// ---- gather layer0: WAVE-per-node, zero LDS / zero barriers ----
__launch_bounds__(256)
extern "C" __global__ void k_gather0(const unsigned short* __restrict__ buf0b,
                                     const unsigned char* __restrict__ h0q,
                                     const float* __restrict__ als0, const float* __restrict__ ald0,
                                     const int* __restrict__ offs, const int* __restrict__ csr,
                                     const float* __restrict__ b0, const float* __restrict__ br0,
                                     unsigned short* __restrict__ h1b, int N){
  int n = blockIdx.x*4 + (threadIdx.x >> 6);
  if(n >= N) return;
  int lane = threadIdx.x & 63;
  int hh = lane & 7;
  int es = lane >> 3;
  int h  = es;
  int c  = lane*4;
  float ald_h = ald0[n*8 + hh];
  int beg = offs[n], end = offs[n+1];

  f32x2 A01 = {0.f, 0.f}, A23 = {0.f, 0.f};
  float den = 0.f;

  for(int chunk = beg; chunk < end; chunk += 8){
    int m = end - chunk; if(m > 8) m = 8;
    bool e_ok = es < m;
    int s = e_ok ? csr[chunk + es] : 0;
    float p = 0.f;
    if(e_ok){
      float v = als0[s*8 + hh] + ald_h;
      v = v > 0.f ? v : NEG_SLOPE*v;
      p = expf(v);
    }
    den += p;
    int sj[8]; float pj[8];
    #pragma unroll
    for(int j=0; j<8; j++){
      sj[j] = __shfl(s, j*8);
      pj[j] = __shfl(p, j*8 + h);
    }
    unsigned q[8];
    #pragma unroll
    for(int j=0; j<8; j++)
      q[j] = *(const unsigned*)(h0q + (size_t)sj[j]*256 + c);
    #pragma unroll
    for(int j=0; j<8; j++){
      f32x2 lo, hi, pv;
      dec8x4v(q[j], lo, hi);
      pv[0] = pj[j]; pv[1] = pj[j];
      A01 += pv*lo; A23 += pv*hi;
    }
  }

  den += __shfl_xor(den, 8);
  den += __shfl_xor(den, 16);
  den += __shfl_xor(den, 32);
  float rden = 1.f/(den + 1e-16f);
  rden = __shfl(rden, h);

  float a0 = A01[0]*rden, a1 = A01[1]*rden, a2 = A23[0]*rden, a3 = A23[1]*rden;

  float4 bb = *(const float4*)(b0 + c);
  float4 rb = *(const float4*)(br0 + c);
  uint2 ru = *(const uint2*)(buf0b + (size_t)n*512 + 256 + c);
  float o0 = a0 + bb.x + __uint_as_float(ru.x << 16)         + rb.x;
  float o1 = a1 + bb.y + __uint_as_float(ru.x & 0xFFFF0000u) + rb.y;
  float o2 = a2 + bb.z + __uint_as_float(ru.y << 16)         + rb.z;
  float o3 = a3 + bb.w + __uint_as_float(ru.y & 0xFFFF0000u) + rb.w;
  ushort4v o;
  o[0] = f2b(o0 > 0.f ? o0 : expf(o0) - 1.f);
  o[1] = f2b(o1 > 0.f ? o1 : expf(o1) - 1.f);
  o[2] = f2b(o2 > 0.f ? o2 : expf(o2) - 1.f);
  o[3] = f2b(o3 > 0.f ? o3 : expf(o3) - 1.f);
  *(ushort4v*)(h1b + (size_t)n*256 + c) = o;
}

// ---------------- layer1 logits (bf16 g1) ----------------
extern "C" __global__ void k_al1(const unsigned short* __restrict__ buf1b, const float* __restrict__ as1,
                                 const float* __restrict__ ad1, float* als1, float* ald1, int N){
  int n = blockIdx.x*4 + (threadIdx.x >> 6);
  if(n >= N) return;
  int lane = threadIdx.x & 63;
  float g = b2f(buf1b[(size_t)n*128 + lane]);
  float s = g*as1[lane], d = g*ad1[lane];
  #pragma unroll
  for(int o=32; o>0; o>>=1){ s += __shfl_xor(s,o); d += __shfl_xor(d,o); }
  if(lane == 0){ als1[n] = s; ald1[n] = d; }
}

// ---- gather layer1: WAVE-per-node over fp8 g1; 4 channels/lane, 4 edge slots ----
// lane: ch4=lane&15 (channels 4*ch4..+3), edge slot es=lane>>4 (0..3).
__launch_bounds__(256)
extern "C" __global__ void k_gather1(const unsigned short* __restrict__ buf1b,
                                     const unsigned char* __restrict__ g1q,
                                     const float* __restrict__ als1, const float* __restrict__ ald1,
                                     const int* __restrict__ offs, const int* __restrict__ csr,
                                     const float* __restrict__ b1, const float* __restrict__ br1,
                                     float* __restrict__ out, int N){
  int n = blockIdx.x*4 + (threadIdx.x >> 6);
  if(n >= N) return;
  int lane = threadIdx.x & 63;
  int ch4 = lane & 15;
  int es  = lane >> 4;
  int c   = ch4*4;
  int beg = offs[n], end = offs[n+1];
  float ald_n = ald1[n];

  f32x2 A01 = {0.f, 0.f}, A23 = {0.f, 0.f};
  float den = 0.f;

  for(int chunk = beg; chunk < end; chunk += 64){
    int m = end - chunk; if(m > 64) m = 64;
    int s = (lane < m) ? csr[chunk + lane] : 0;
    float p = 0.f;
    if(lane < m){
      float v = als1[s] + ald_n;
      v = v > 0.f ? v : NEG_SLOPE*v;
      p = expf(v);
    }
    den += p;
    for(int base = 0; base < m; base += 16){
      int sv[4]; float pv[4];
      #pragma unroll
      for(int i=0; i<4; i++){
        int j = base + 4*i + es;          // j <= 63 always (base step 16, base < m <= 64)
        int jj = j & 63;
        sv[i] = __shfl(s, jj);
        pv[i] = __shfl(p, jj);            // 0 for invalid edges
      }
      unsigned qv[4];
      #pragma unroll
      for(int i=0; i<4; i++)
        qv[i] = *(const unsigned*)(g1q + (size_t)sv[i]*64 + c);
      #pragma unroll
      for(int i=0; i<4; i++){
        f32x2 lo, hi, pp;
        dec8x4v(qv[i], lo, hi);
        pp[0] = pv[i]; pp[1] = pv[i];
        A01 += pp*lo; A23 += pp*hi;
      }
    }
  }

  // merge the 4 edge slots (same ch4 at lane^16, lane^32)
  A01[0] += __shfl_xor(A01[0], 16); A01[1] += __shfl_xor(A01[1], 16);
  A23[0] += __shfl_xor(A23[0], 16); A23[1] += __shfl_xor(A23[1], 16);
  A01[0] += __shfl_xor(A01[0], 32); A01[1] += __shfl_xor(A01[1], 32);
  A23[0] += __shfl_xor(A23[0], 32); A23[1] += __shfl_xor(A23[1], 32);
  #pragma unroll
  for(int o=32; o>0; o>>=1) den += __shfl_xor(den, o);
  float rden = 1.f/(den + 1e-16f);

  float4 bb = *(const float4*)(b1 + c);
  float4 rb = *(const float4*)(br1 + c);
  uint2 ru = *(const uint2*)(buf1b + (size_t)n*128 + 64 + c);
  float v0 = A01[0]*rden + bb.x + __uint_as_float(ru.x << 16)         + rb.x;
  float v1 = A01[1]*rden + bb.y + __uint_as_float(ru.x & 0xFFFF0000u) + rb.y;
  float v2 = A23[0]*rden + bb.z + __uint_as_float(ru.y << 16)         + rb.z;
  float v3 = A23[1]*rden + bb.w + __uint_as_float(ru.y & 0xFFFF0000u) + rb.w;

  float mx = fmaxf(fmaxf(v0, v1), fmaxf(v2, v3));
  #pragma unroll
  for(int o=1; o<16; o<<=1) mx = fmaxf(mx, __shfl_xor(mx, o));
  float sm = expf(v0-mx) + expf(v1-mx) + expf(v2-mx) + expf(v3-mx);
  #pragma unroll
  for(int o=1; o<16; o<<=1) sm += __shfl_xor(sm, o);
  float l = mx + logf(sm);
  if(es == 0){
    float4 ov; ov.x = v0-l; ov.y = v1-l; ov.z = v2-l; ov.w = v3-l;
    *(float4*)(out + (size_t)n*64 + c) = ov;
  }
}

// ---------------- launch ----------------
extern "C" void kernel_launch(void* const* d_in, const int* in_sizes, int n_in,
                              void* d_out, int out_size, void* d_ws, size_t ws_size,
                              hipStream_t stream){
  const float* x   = (const float*)d_in[0];
  const int*   ei  = (const int*)  d_in[1];
  const float* W0  = (const float*)d_in[2];
  const float* as0 = (const float*)d_in[3];
  const float* ad0 = (const float*)d_in[4];
  const float* b0  = (const float*)d_in[5];
  const float* Wr0 = (const float*)d_in[6];
  const float* br0 = (const float*)d_in[7];
  const float* W1  = (const float*)d_in[8];
  const float* as1 = (const float*)d_in[9];
  const float* ad1 = (const float*)d_in[10];
  const float* b1  = (const float*)d_in[11];
  const float* Wr1 = (const float*)d_in[12];
  const float* br1 = (const float*)d_in[13];
  int N = in_sizes[0] / 256;
  int E = in_sizes[1] / 2;
  const int* srcs = ei;
  const int* dsts = ei + E;
  float* out = (float*)d_out;

  int ET = E + N;
  int NBUCK = (N + 127) >> BSH;

  // workspace layout
  unsigned short* buf0b = (unsigned short*)d_ws;        // N*512 bf16 (h0 | r0)
  unsigned short* xb    = buf0b + (size_t)N*512;        // region reused for h0q
  unsigned short* h1b   = xb    + (size_t)N*256;        // N*256 bf16
  unsigned short* buf1b = h1b   + (size_t)N*256;        // N*128 bf16 (g1 | r1)
  unsigned short* WT0   = buf1b + (size_t)N*128;        // 512*256 bf16
  unsigned short* WT1   = WT0   + 512*256;              // 128*256 bf16
  float*    als0 = (float*)(WT1 + 128*256);             // N*8
  float*    ald0 = als0 + (size_t)N*8;                  // N*8
  float*    als1 = ald0 + (size_t)N*8;                  // N
  float*    ald1 = als1 + N;                            // N
  int*      offs = (int*)(ald1 + N);                    // N+1
  int*      bcnt = offs + N + 1;                        // NBUCK
  int*      boffs = bcnt + NBUCK;                       // NBUCK+1
  int*      blockbase = boffs + NBUCK + 1;              // NBLK_PART*NBUCK
  int*      csr  = blockbase + (size_t)NBLK_PART*NBUCK; // ET
  uint2*    pairs = (uint2*)(csr + ET);
  pairs = (uint2*)(((uintptr_t)pairs + 7) & ~(uintptr_t)7);
  unsigned char* g1q = (unsigned char*)(pairs + ET);    // N*64 bytes
  unsigned char* h0q = (unsigned char*)xb;              // N*256 bytes

  // ---- CSR build: bucket partition ----
  hipMemsetAsync(bcnt, 0, (size_t)NBUCK*sizeof(int), stream);
  hipLaunchKernelGGL(k_part1, dim3(NBLK_PART), dim3(256), 0, stream, dsts, E, N, NBUCK, bcnt, blockbase);
  hipLaunchKernelGGL(k_bscan, dim3(1), dim3(512), 0, stream, bcnt, boffs, offs + N, NBUCK, ET);
  hipLaunchKernelGGL(k_part2, dim3(NBLK_PART), dim3(256), 0, stream, srcs, dsts, E, N, NBUCK, boffs, blockbase, pairs);
  hipLaunchKernelGGL(k_bcsr, dim3(NBUCK), dim3(256), 0, stream, pairs, boffs, N, offs, csr);

  // weight prep
  hipLaunchKernelGGL(k_wt2, dim3((512*256+128*256+255)/256), dim3(256), 0, stream, W0, Wr0, W1, Wr1, WT0, WT1);

  int MB = (N + 127) / 128;
  int g0 = ((MB + 7) / 8) * 32;
  // layer0: buf0b[N][512] = x(fp32) @ [W0|Wr0]; epilogue writes fp8 h0q (cols<256)
  hipLaunchKernelGGL(k_mgemm, dim3(g0), dim3(256), 0, stream,
                     (const unsigned short*)nullptr, x, WT0, buf0b, 512, N, MB, 4, h0q, 256);
  hipLaunchKernelGGL(k_al0, dim3((N*8+255)/256), dim3(256), 0, stream, buf0b, as0, ad0, als0, ald0, N);
  hipLaunchKernelGGL(k_gather0, dim3((N+3)/4), dim3(256), 0, stream, buf0b, h0q, als0, ald0, offs, csr, b0, br0, h1b, N);

  // layer1: buf1b[N][128] = h1b @ [W1|Wr1]; epilogue writes fp8 g1q (cols<64)
  hipLaunchKernelGGL(k_mgemm, dim3(MB), dim3(256), 0, stream,
                     h1b, (const float*)nullptr, WT1, buf1b, 128, N, MB, 1, g1q, 64);
  hipLaunchKernelGGL(k_al1, dim3((N+3)/4), dim3(256), 0, stream, buf1b, as1, ad1, als1, ald1, N);
  hipLaunchKernelGGL(k_gather1, dim3((N+3)/4), dim3(256), 0, stream, buf1b, g1q, als1, ald1, offs, csr, b1, br1, out, N);
}

// Round 18
// 197.575 us; speedup vs baseline: 1.7224x; 1.0205x over previous
//
#include <hip/hip_runtime.h>
#include <math.h>

#define NEG_SLOPE 0.2f
#define BSH 7              // 128 nodes per bucket
#define NBLK_PART 256      // partition blocks

typedef __attribute__((ext_vector_type(8))) short bf16x8;
typedef __attribute__((ext_vector_type(4))) float f32x4;
typedef __attribute__((ext_vector_type(2))) float f32x2;
typedef __attribute__((ext_vector_type(8))) unsigned short ushort8;
typedef __attribute__((ext_vector_type(4))) unsigned short ushort4v;

__device__ __forceinline__ float b2f(unsigned short u){
  return __uint_as_float(((unsigned)u) << 16);
}
__device__ __forceinline__ unsigned short f2b(float f){
  unsigned u = __float_as_uint(f);
  return (unsigned short)((u + 0x7FFFu + ((u >> 16) & 1u)) >> 16);
}

// ---- fp8 e4m3fn helpers (hardware cvt if available, bit-twiddle fallback) ----
#if __has_builtin(__builtin_amdgcn_cvt_pk_f32_fp8) && __has_builtin(__builtin_amdgcn_cvt_pk_fp8_f32)
#define HW_FP8 1
#else
#define HW_FP8 0
#endif

#if !HW_FP8
__device__ __forceinline__ unsigned enc8_one(float f){
  unsigned bits = __float_as_uint(f);
  unsigned s = bits >> 31;
  unsigned e = (bits >> 23) & 255;
  unsigned mant = bits & 0x7FFFFF;
  if(e < 121){
    float af = fabsf(f);
    int m = (int)(af * 512.f + 0.5f);
    if(m > 7) m = 7;
    return (s << 7) | (unsigned)m;
  }
  unsigned lsb = (mant >> 20) & 1;
  mant += 0x7FFFF + lsb;
  if(mant >> 23){ e += 1; mant = 0; }
  unsigned m3 = mant >> 20;
  unsigned e8 = e - 120;
  if(e8 > 15 || (e8 == 15 && m3 == 7)) return (s << 7) | 0x7E;
  return (s << 7) | (e8 << 3) | m3;
}
#endif

template<bool HI>
__device__ __forceinline__ unsigned enc8_pair(float a, float b, unsigned old){
#if HW_FP8
  return __builtin_amdgcn_cvt_pk_fp8_f32(a, b, old, HI);  // HI literal (op_sel)
#else
  unsigned p = enc8_one(a) | (enc8_one(b) << 8);
  return HI ? ((old & 0x0000FFFFu) | (p << 16)) : ((old & 0xFFFF0000u) | p);
#endif
}

__device__ __forceinline__ unsigned char enc8b(float v){
  return (unsigned char)(enc8_pair<false>(v, v, 0u) & 0xFFu);
}

__device__ __forceinline__ void dec8x4v(unsigned q, f32x2& lo, f32x2& hi){
#if HW_FP8
  lo = __builtin_amdgcn_cvt_pk_f32_fp8(q, false);
  hi = __builtin_amdgcn_cvt_pk_f32_fp8(q, true);
#else
  auto dec1 = [](unsigned b)->float{
    unsigned s = (b >> 7) & 1, e = (b >> 3) & 15, m = b & 7;
    float v = (e == 0) ? (float)m * 0.001953125f
                       : __uint_as_float(((e + 120) << 23) | (m << 20));
    return s ? -v : v;
  };
  lo[0] = dec1(q & 255); lo[1] = dec1((q >> 8) & 255);
  hi[0] = dec1((q >> 16) & 255); hi[1] = dec1(q >> 24);
#endif
}

// ================= bucket-partitioned CSR build =================
extern "C" __global__ void k_part1(const int* __restrict__ dsts, int E, int N,
                                   int NBUCK, int* __restrict__ bcnt,
                                   int* __restrict__ blockbase){
  __shared__ int hist[512];
  int blk = blockIdx.x, tid = threadIdx.x;
  for(int b = tid; b < NBUCK; b += 256) hist[b] = 0;
  __syncthreads();
  int ET = E + N;
  int chunk = (ET + NBLK_PART - 1)/NBLK_PART;
  int s0 = blk*chunk, s1 = s0+chunk < ET ? s0+chunk : ET;
  for(int e = s0+tid; e < s1; e += 256){
    int d = (e < E) ? dsts[e] : e - E;
    atomicAdd(&hist[d >> BSH], 1);
  }
  __syncthreads();
  for(int b = tid; b < NBUCK; b += 256)
    blockbase[(size_t)blk*NBUCK + b] = atomicAdd(&bcnt[b], hist[b]);
}

extern "C" __global__ void k_bscan(const int* __restrict__ bcnt, int* __restrict__ boffs,
                                   int* __restrict__ offs_last, int NBUCK, int ET){
  __shared__ int sc[512], orig[512];
  int t = threadIdx.x;
  int v = (t < NBUCK) ? bcnt[t] : 0;
  sc[t] = v; orig[t] = v;
  __syncthreads();
  for(int st=1; st<512; st<<=1){
    int u = (t >= st) ? sc[t-st] : 0;
    __syncthreads();
    sc[t] += u;
    __syncthreads();
  }
  if(t < NBUCK) boffs[t] = sc[t] - orig[t];
  if(t == 0){ boffs[NBUCK] = ET; *offs_last = ET; }
}

extern "C" __global__ void k_part2(const int* __restrict__ srcs, const int* __restrict__ dsts,
                                   int E, int N, int NBUCK,
                                   const int* __restrict__ boffs, const int* __restrict__ blockbase,
                                   uint2* __restrict__ pairs){
  __shared__ int cur[512];
  int blk = blockIdx.x, tid = threadIdx.x;
  for(int b = tid; b < NBUCK; b += 256)
    cur[b] = boffs[b] + blockbase[(size_t)blk*NBUCK + b];
  __syncthreads();
  int ET = E + N;
  int chunk = (ET + NBLK_PART - 1)/NBLK_PART;
  int s0 = blk*chunk, s1 = s0+chunk < ET ? s0+chunk : ET;
  for(int e = s0+tid; e < s1; e += 256){
    int s, d;
    if(e < E){ s = srcs[e]; d = dsts[e]; } else { s = d = e - E; }
    int pos = atomicAdd(&cur[d >> BSH], 1);
    uint2 pr; pr.x = (unsigned)d; pr.y = (unsigned)s;
    pairs[pos] = pr;
  }
}

extern "C" __global__ void k_bcsr(const uint2* __restrict__ pairs, const int* __restrict__ boffs,
                                  int N, int* __restrict__ offs, int* __restrict__ csr){
  __shared__ int hist[128], sc[128], lcur[128];
  int b = blockIdx.x, tid = threadIdx.x;
  int node0 = b << BSH;
  int base = boffs[b], endp = boffs[b+1];
  if(tid < 128) hist[tid] = 0;
  __syncthreads();
  for(int i = base + tid; i < endp; i += 256)
    atomicAdd(&hist[pairs[i].x & 127], 1);
  __syncthreads();
  if(tid < 128) sc[tid] = hist[tid];
  __syncthreads();
  for(int st=1; st<128; st<<=1){
    int u = (tid < 128 && tid >= st) ? sc[tid-st] : 0;
    __syncthreads();
    if(tid < 128) sc[tid] += u;
    __syncthreads();
  }
  if(tid < 128){
    int ex = sc[tid] - hist[tid];
    lcur[tid] = ex;
    int n = node0 + tid;
    if(n < N) offs[n] = base + ex;
  }
  __syncthreads();
  for(int i = base + tid; i < endp; i += 256){
    uint2 pr = pairs[i];
    int pos = atomicAdd(&lcur[pr.x & 127], 1);
    csr[base + pos] = (int)pr.y;
  }
}

// ---------------- weight transpose+concat (both layers, one launch) ----------------
extern "C" __global__ void k_wt2(const float* __restrict__ W0, const float* __restrict__ Wr0,
                                 const float* __restrict__ W1, const float* __restrict__ Wr1,
                                 unsigned short* __restrict__ WT0, unsigned short* __restrict__ WT1){
  int idx = blockIdx.x*256 + threadIdx.x;
  const int tot0 = 512*256;
  if(idx < tot0){
    int n = idx >> 8, k = idx & 255;
    const float* W = (n < 256) ? W0 : Wr0;
    int c = (n < 256) ? n : n - 256;
    WT0[idx] = f2b(W[(size_t)k*256 + c]);
  } else {
    idx -= tot0;
    if(idx >= 128*256) return;
    int n = idx >> 8, k = idx & 255;
    const float* W = (n < 64) ? W1 : Wr1;
    int c = (n < 64) ? n : n - 64;
    WT1[idx] = f2b(W[(size_t)k*64 + c]);
  }
}

// ---------------- bf16 MFMA GEMM; A from bf16 (gload_lds) or fp32 (pipelined reg-stage) ----------------
// optional fp8 side-output for cols < qcols.
__launch_bounds__(256)
extern "C" __global__ void k_mgemm(const unsigned short* __restrict__ A,
                                   const float* __restrict__ Afp,
                                   const unsigned short* __restrict__ WT,
                                   unsigned short* __restrict__ C, int ldc, int M,
                                   int MB, int NCB,
                                   unsigned char* __restrict__ qout, int qcols){
  int id = blockIdx.x;
  int row_blk, col_blk;
  if(NCB == 4){
    int group = id >> 5;
    int r8 = id & 7;
    col_blk = (id >> 3) & 3;
    row_blk = group*8 + r8;
  } else {
    row_blk = id; col_blk = 0;
  }
  if(row_blk >= MB) return;

  __shared__ unsigned short As[128*64];
  __shared__ unsigned short Bs[128*64];
  int t = threadIdx.x;
  int lane = t & 63, wid = t >> 6;
  int wr = wid >> 1, wc = wid & 1;
  int row0 = row_blk*128, col0 = col_blk*128;
  f32x4 acc[4][4] = {};

  // fp32 A path: pipelined reg staging (issue-early / write-late, T14)
  float4 v0s[4], v1s[4];
  const float* abase[4];
  if(Afp){
    #pragma unroll
    for(int i=0; i<4; i++){
      int t2 = i*256 + t;
      int r = t2 >> 3;
      int dslot = (t2 & 7) ^ (r & 7);
      int gr = row0 + r; if(gr >= M) gr = M - 1;
      abase[i] = Afp + (size_t)gr*256 + dslot*8;
      v0s[i] = *(const float4*)(abase[i]);
      v1s[i] = *(const float4*)(abase[i] + 4);
    }
  }

  for(int k0 = 0; k0 < 256; k0 += 64){
    if(Afp){
      // write staged regs (convert fp32->bf16 here; loads were issued last iter)
      #pragma unroll
      for(int i=0; i<4; i++){
        ushort8 o;
        o[0]=f2b(v0s[i].x); o[1]=f2b(v0s[i].y); o[2]=f2b(v0s[i].z); o[3]=f2b(v0s[i].w);
        o[4]=f2b(v1s[i].x); o[5]=f2b(v1s[i].y); o[6]=f2b(v1s[i].z); o[7]=f2b(v1s[i].w);
        *(ushort8*)(As + i*2048 + wid*512 + lane*8) = o;
      }
    } else {
      #pragma unroll
      for(int i=0; i<4; i++){
        int t2 = i*256 + t;
        int r = t2 >> 3;
        int dslot = (t2 & 7) ^ (r & 7);
        int gr = row0 + r; if(gr >= M) gr = M - 1;
        const unsigned short* ga = A + (size_t)gr*256 + k0 + dslot*8;
        __builtin_amdgcn_global_load_lds((const __attribute__((address_space(1))) unsigned*)ga,
            (__attribute__((address_space(3))) unsigned*)(As + i*2048 + wid*512), 16, 0, 0);
      }
    }
    #pragma unroll
    for(int i=0; i<4; i++){
      int t2 = i*256 + t;
      int r = t2 >> 3;
      int dslot = (t2 & 7) ^ (r & 7);
      const unsigned short* gb = WT + (size_t)(col0 + r)*256 + k0 + dslot*8;
      __builtin_amdgcn_global_load_lds((const __attribute__((address_space(1))) unsigned*)gb,
          (__attribute__((address_space(3))) unsigned*)(Bs + i*2048 + wid*512), 16, 0, 0);
    }
    __syncthreads();
    // prefetch next K-step's A (in flight during MFMA below)
    if(Afp && k0 < 192){
      #pragma unroll
      for(int i=0; i<4; i++){
        v0s[i] = *(const float4*)(abase[i] + k0 + 64);
        v1s[i] = *(const float4*)(abase[i] + k0 + 68);
      }
    }
    #pragma unroll
    for(int kc=0; kc<2; kc++){
      bf16x8 a[4], b[4];
      int kb = kc*4 + (lane >> 4);
      #pragma unroll
      for(int f=0; f<4; f++){
        int ar = wr*64 + f*16 + (lane & 15);
        a[f] = *(const bf16x8*)&As[ar*64 + ((kb ^ (ar & 7))*8)];
        int br = wc*64 + f*16 + (lane & 15);
        b[f] = *(const bf16x8*)&Bs[br*64 + ((kb ^ (br & 7))*8)];
      }
      #pragma unroll
      for(int fm=0; fm<4; fm++)
        #pragma unroll
        for(int fn=0; fn<4; fn++)
          acc[fm][fn] = __builtin_amdgcn_mfma_f32_16x16x32_bf16(a[fm], b[fn], acc[fm][fn], 0, 0, 0);
    }
    __syncthreads();
  }

  int rb = row0 + wr*64 + ((lane >> 4) << 2);
  int cb = col0 + wc*64 + (lane & 15);
  #pragma unroll
  for(int fm=0; fm<4; fm++){
    #pragma unroll
    for(int r=0; r<4; r++){
      int row = rb + fm*16 + r;
      if(row < M){
        #pragma unroll
        for(int fn=0; fn<4; fn++)
          C[(size_t)row*ldc + cb + fn*16] = f2b(acc[fm][fn][r]);
        if(qout){
          #pragma unroll
          for(int fn=0; fn<4; fn++){
            int col = cb + fn*16;
            if(col < qcols) qout[(size_t)row*qcols + col] = enc8b(acc[fm][fn][r]);
          }
        }
      }
    }
  }
}

// ---------------- attention logits layer0 (bf16 h0) ----------------
extern "C" __global__ void k_al0(const unsigned short* __restrict__ buf0b, const float* __restrict__ as0,
                                 const float* __restrict__ ad0, float* als0, float* ald0, int N){
  int i = blockIdx.x*blockDim.x + threadIdx.x;   // n*8+h
  if(i >= N*8) return;
  int n = i >> 3, h = i & 7;
  const uint4* hp = (const uint4*)(buf0b + (size_t)n*512 + h*32);
  const float* av = as0 + h*32;
  const float* dv = ad0 + h*32;
  float s = 0.f, d = 0.f;
  #pragma unroll
  for(int q=0; q<4; q++){
    uint4 u = hp[q];
    unsigned w[4] = {u.x, u.y, u.z, u.w};
    #pragma unroll
    for(int j=0; j<4; j++){
      float lo = __uint_as_float(w[j] << 16);
      float hi = __uint_as_float(w[j] & 0xFFFF0000u);
      int c = q*8 + j*2;
      s += lo*av[c] + hi*av[c+1];
      d += lo*dv[c] + hi*dv[c+1];
    }
  }
  als0[i] = s; ald0[i] = d;
}

// ---- gather layer0: WAVE-per-node, zero LDS / zero barriers ----
__launch_bounds__(256)
extern "C" __global__ void k_gather0(const unsigned short* __restrict__ buf0b,
                                     const unsigned char* __restrict__ h0q,
                                     const float* __restrict__ als0, const float* __restrict__ ald0,
                                     const int* __restrict__ offs, const int* __restrict__ csr,
                                     const float* __restrict__ b0, const float* __restrict__ br0,
                                     unsigned short* __restrict__ h1b, int N){
  int n = blockIdx.x*4 + (threadIdx.x >> 6);
  if(n >= N) return;
  int lane = threadIdx.x & 63;
  int hh = lane & 7;
  int es = lane >> 3;
  int h  = es;
  int c  = lane*4;
  float ald_h = ald0[n*8 + hh];
  int beg = offs[n], end = offs[n+1];

  f32x2 A01 = {0.f, 0.f}, A23 = {0.f, 0.f};
  float den = 0.f;

  for(int chunk = beg; chunk < end; chunk += 8){
    int m = end - chunk; if(m > 8) m = 8;
    bool e_ok = es < m;
    int s = e_ok ? csr[chunk + es] : 0;
    float p = 0.f;
    if(e_ok){
      float v = als0[s*8 + hh] + ald_h;
      v = v > 0.f ? v : NEG_SLOPE*v;
      p = expf(v);
    }
    den += p;
    int sj[8]; float pj[8];
    #pragma unroll
    for(int j=0; j<8; j++){
      sj[j] = __shfl(s, j*8);
      pj[j] = __shfl(p, j*8 + h);
    }
    unsigned q[8];
    #pragma unroll
    for(int j=0; j<8; j++)
      q[j] = *(const unsigned*)(h0q + (size_t)sj[j]*256 + c);
    #pragma unroll
    for(int j=0; j<8; j++){
      f32x2 lo, hi, pv;
      dec8x4v(q[j], lo, hi);
      pv[0] = pj[j]; pv[1] = pj[j];
      A01 += pv*lo; A23 += pv*hi;
    }
  }

  den += __shfl_xor(den, 8);
  den += __shfl_xor(den, 16);
  den += __shfl_xor(den, 32);
  float rden = 1.f/(den + 1e-16f);
  rden = __shfl(rden, h);

  float a0 = A01[0]*rden, a1 = A01[1]*rden, a2 = A23[0]*rden, a3 = A23[1]*rden;

  float4 bb = *(const float4*)(b0 + c);
  float4 rb = *(const float4*)(br0 + c);
  uint2 ru = *(const uint2*)(buf0b + (size_t)n*512 + 256 + c);
  float o0 = a0 + bb.x + __uint_as_float(ru.x << 16)         + rb.x;
  float o1 = a1 + bb.y + __uint_as_float(ru.x & 0xFFFF0000u) + rb.y;
  float o2 = a2 + bb.z + __uint_as_float(ru.y << 16)         + rb.z;
  float o3 = a3 + bb.w + __uint_as_float(ru.y & 0xFFFF0000u) + rb.w;
  ushort4v o;
  o[0] = f2b(o0 > 0.f ? o0 : expf(o0) - 1.f);
  o[1] = f2b(o1 > 0.f ? o1 : expf(o1) - 1.f);
  o[2] = f2b(o2 > 0.f ? o2 : expf(o2) - 1.f);
  o[3] = f2b(o3 > 0.f ? o3 : expf(o3) - 1.f);
  *(ushort4v*)(h1b + (size_t)n*256 + c) = o;
}

// ---------------- layer1 logits (bf16 g1) ----------------
extern "C" __global__ void k_al1(const unsigned short* __restrict__ buf1b, const float* __restrict__ as1,
                                 const float* __restrict__ ad1, float* als1, float* ald1, int N){
  int n = blockIdx.x*4 + (threadIdx.x >> 6);
  if(n >= N) return;
  int lane = threadIdx.x & 63;
  float g = b2f(buf1b[(size_t)n*128 + lane]);
  float s = g*as1[lane], d = g*ad1[lane];
  #pragma unroll
  for(int o=32; o>0; o>>=1){ s += __shfl_xor(s,o); d += __shfl_xor(d,o); }
  if(lane == 0){ als1[n] = s; ald1[n] = d; }
}

// ---- gather layer1: WAVE-per-node over fp8 g1; 4 channels/lane, 4 edge slots ----
__launch_bounds__(256)
extern "C" __global__ void k_gather1(const unsigned short* __restrict__ buf1b,
                                     const unsigned char* __restrict__ g1q,
                                     const float* __restrict__ als1, const float* __restrict__ ald1,
                                     const int* __restrict__ offs, const int* __restrict__ csr,
                                     const float* __restrict__ b1, const float* __restrict__ br1,
                                     float* __restrict__ out, int N){
  int n = blockIdx.x*4 + (threadIdx.x >> 6);
  if(n >= N) return;
  int lane = threadIdx.x & 63;
  int ch4 = lane & 15;
  int es  = lane >> 4;
  int c   = ch4*4;
  int beg = offs[n], end = offs[n+1];
  float ald_n = ald1[n];

  f32x2 A01 = {0.f, 0.f}, A23 = {0.f, 0.f};
  float den = 0.f;

  for(int chunk = beg; chunk < end; chunk += 64){
    int m = end - chunk; if(m > 64) m = 64;
    int s = (lane < m) ? csr[chunk + lane] : 0;
    float p = 0.f;
    if(lane < m){
      float v = als1[s] + ald_n;
      v = v > 0.f ? v : NEG_SLOPE*v;
      p = expf(v);
    }
    den += p;
    for(int base = 0; base < m; base += 16){
      int sv[4]; float pv[4];
      #pragma unroll
      for(int i=0; i<4; i++){
        int j = base + 4*i + es;
        int jj = j & 63;
        sv[i] = __shfl(s, jj);
        pv[i] = __shfl(p, jj);
      }
      unsigned qv[4];
      #pragma unroll
      for(int i=0; i<4; i++)
        qv[i] = *(const unsigned*)(g1q + (size_t)sv[i]*64 + c);
      #pragma unroll
      for(int i=0; i<4; i++){
        f32x2 lo, hi, pp;
        dec8x4v(qv[i], lo, hi);
        pp[0] = pv[i]; pp[1] = pv[i];
        A01 += pp*lo; A23 += pp*hi;
      }
    }
  }

  A01[0] += __shfl_xor(A01[0], 16); A01[1] += __shfl_xor(A01[1], 16);
  A23[0] += __shfl_xor(A23[0], 16); A23[1] += __shfl_xor(A23[1], 16);
  A01[0] += __shfl_xor(A01[0], 32); A01[1] += __shfl_xor(A01[1], 32);
  A23[0] += __shfl_xor(A23[0], 32); A23[1] += __shfl_xor(A23[1], 32);
  #pragma unroll
  for(int o=32; o>0; o>>=1) den += __shfl_xor(den, o);
  float rden = 1.f/(den + 1e-16f);

  float4 bb = *(const float4*)(b1 + c);
  float4 rb = *(const float4*)(br1 + c);
  uint2 ru = *(const uint2*)(buf1b + (size_t)n*128 + 64 + c);
  float v0 = A01[0]*rden + bb.x + __uint_as_float(ru.x << 16)         + rb.x;
  float v1 = A01[1]*rden + bb.y + __uint_as_float(ru.x & 0xFFFF0000u) + rb.y;
  float v2 = A23[0]*rden + bb.z + __uint_as_float(ru.y << 16)         + rb.z;
  float v3 = A23[1]*rden + bb.w + __uint_as_float(ru.y & 0xFFFF0000u) + rb.w;

  float mx = fmaxf(fmaxf(v0, v1), fmaxf(v2, v3));
  #pragma unroll
  for(int o=1; o<16; o<<=1) mx = fmaxf(mx, __shfl_xor(mx, o));
  float sm = expf(v0-mx) + expf(v1-mx) + expf(v2-mx) + expf(v3-mx);
  #pragma unroll
  for(int o=1; o<16; o<<=1) sm += __shfl_xor(sm, o);
  float l = mx + logf(sm);
  if(es == 0){
    float4 ov; ov.x = v0-l; ov.y = v1-l; ov.z = v2-l; ov.w = v3-l;
    *(float4*)(out + (size_t)n*64 + c) = ov;
  }
}

// ---------------- launch ----------------
extern "C" void kernel_launch(void* const* d_in, const int* in_sizes, int n_in,
                              void* d_out, int out_size, void* d_ws, size_t ws_size,
                              hipStream_t stream){
  const float* x   = (const float*)d_in[0];
  const int*   ei  = (const int*)  d_in[1];
  const float* W0  = (const float*)d_in[2];
  const float* as0 = (const float*)d_in[3];
  const float* ad0 = (const float*)d_in[4];
  const float* b0  = (const float*)d_in[5];
  const float* Wr0 = (const float*)d_in[6];
  const float* br0 = (const float*)d_in[7];
  const float* W1  = (const float*)d_in[8];
  const float* as1 = (const float*)d_in[9];
  const float* ad1 = (const float*)d_in[10];
  const float* b1  = (const float*)d_in[11];
  const float* Wr1 = (const float*)d_in[12];
  const float* br1 = (const float*)d_in[13];
  int N = in_sizes[0] / 256;
  int E = in_sizes[1] / 2;
  const int* srcs = ei;
  const int* dsts = ei + E;
  float* out = (float*)d_out;

  int ET = E + N;
  int NBUCK = (N + 127) >> BSH;

  // workspace layout
  unsigned short* buf0b = (unsigned short*)d_ws;        // N*512 bf16 (h0 | r0)
  unsigned short* xb    = buf0b + (size_t)N*512;        // region reused for h0q
  unsigned short* h1b   = xb    + (size_t)N*256;        // N*256 bf16
  unsigned short* buf1b = h1b   + (size_t)N*256;        // N*128 bf16 (g1 | r1)
  unsigned short* WT0   = buf1b + (size_t)N*128;        // 512*256 bf16
  unsigned short* WT1   = WT0   + 512*256;              // 128*256 bf16
  float*    als0 = (float*)(WT1 + 128*256);             // N*8
  float*    ald0 = als0 + (size_t)N*8;                  // N*8
  float*    als1 = ald0 + (size_t)N*8;                  // N
  float*    ald1 = als1 + N;                            // N
  int*      offs = (int*)(ald1 + N);                    // N+1
  int*      bcnt = offs + N + 1;                        // NBUCK
  int*      boffs = bcnt + NBUCK;                       // NBUCK+1
  int*      blockbase = boffs + NBUCK + 1;              // NBLK_PART*NBUCK
  int*      csr  = blockbase + (size_t)NBLK_PART*NBUCK; // ET
  uint2*    pairs = (uint2*)(csr + ET);
  pairs = (uint2*)(((uintptr_t)pairs + 7) & ~(uintptr_t)7);
  unsigned char* g1q = (unsigned char*)(pairs + ET);    // N*64 bytes
  unsigned char* h0q = (unsigned char*)xb;              // N*256 bytes

  // ---- CSR build: bucket partition ----
  hipMemsetAsync(bcnt, 0, (size_t)NBUCK*sizeof(int), stream);
  hipLaunchKernelGGL(k_part1, dim3(NBLK_PART), dim3(256), 0, stream, dsts, E, N, NBUCK, bcnt, blockbase);
  hipLaunchKernelGGL(k_bscan, dim3(1), dim3(512), 0, stream, bcnt, boffs, offs + N, NBUCK, ET);
  hipLaunchKernelGGL(k_part2, dim3(NBLK_PART), dim3(256), 0, stream, srcs, dsts, E, N, NBUCK, boffs, blockbase, pairs);
  hipLaunchKernelGGL(k_bcsr, dim3(NBUCK), dim3(256), 0, stream, pairs, boffs, N, offs, csr);

  // weight prep
  hipLaunchKernelGGL(k_wt2, dim3((512*256+128*256+255)/256), dim3(256), 0, stream, W0, Wr0, W1, Wr1, WT0, WT1);

  int MB = (N + 127) / 128;
  int g0 = ((MB + 7) / 8) * 32;
  // layer0: buf0b[N][512] = x(fp32) @ [W0|Wr0]; epilogue writes fp8 h0q (cols<256)
  hipLaunchKernelGGL(k_mgemm, dim3(g0), dim3(256), 0, stream,
                     (const unsigned short*)nullptr, x, WT0, buf0b, 512, N, MB, 4, h0q, 256);
  hipLaunchKernelGGL(k_al0, dim3((N*8+255)/256), dim3(256), 0, stream, buf0b, as0, ad0, als0, ald0, N);
  hipLaunchKernelGGL(k_gather0, dim3((N+3)/4), dim3(256), 0, stream, buf0b, h0q, als0, ald0, offs, csr, b0, br0, h1b, N);

  // layer1: buf1b[N][128] = h1b @ [W1|Wr1]; epilogue writes fp8 g1q (cols<64)
  hipLaunchKernelGGL(k_mgemm, dim3(MB), dim3(256), 0, stream,
                     h1b, (const float*)nullptr, WT1, buf1b, 128, N, MB, 1, g1q, 64);
  hipLaunchKernelGGL(k_al1, dim3((N+3)/4), dim3(256), 0, stream, buf1b, as1, ad1, als1, ald1, N);
  hipLaunchKernelGGL(k_gather1, dim3((N+3)/4), dim3(256), 0, stream, buf1b, g1q, als1, ald1, offs, csr, b1, br1, out, N);
}

// Round 19
// 181.429 us; speedup vs baseline: 1.8757x; 1.0890x over previous
//
#include <hip/hip_runtime.h>
#include <math.h>

#define NEG_SLOPE 0.2f
#define BSH 7              // 128 nodes per bucket
#define NBLK_PART 256      // partition blocks

typedef __attribute__((ext_vector_type(8))) short bf16x8;
typedef __attribute__((ext_vector_type(4))) float f32x4;
typedef __attribute__((ext_vector_type(2))) float f32x2;
typedef __attribute__((ext_vector_type(8))) unsigned short ushort8;
typedef __attribute__((ext_vector_type(4))) unsigned short ushort4v;

__device__ __forceinline__ float b2f(unsigned short u){
  return __uint_as_float(((unsigned)u) << 16);
}
__device__ __forceinline__ unsigned short f2b(float f){
  unsigned u = __float_as_uint(f);
  return (unsigned short)((u + 0x7FFFu + ((u >> 16) & 1u)) >> 16);
}

// ---- fp8 e4m3fn helpers (hardware cvt if available, bit-twiddle fallback) ----
#if __has_builtin(__builtin_amdgcn_cvt_pk_f32_fp8) && __has_builtin(__builtin_amdgcn_cvt_pk_fp8_f32)
#define HW_FP8 1
#else
#define HW_FP8 0
#endif

#if !HW_FP8
__device__ __forceinline__ unsigned enc8_one(float f){
  unsigned bits = __float_as_uint(f);
  unsigned s = bits >> 31;
  unsigned e = (bits >> 23) & 255;
  unsigned mant = bits & 0x7FFFFF;
  if(e < 121){
    float af = fabsf(f);
    int m = (int)(af * 512.f + 0.5f);
    if(m > 7) m = 7;
    return (s << 7) | (unsigned)m;
  }
  unsigned lsb = (mant >> 20) & 1;
  mant += 0x7FFFF + lsb;
  if(mant >> 23){ e += 1; mant = 0; }
  unsigned m3 = mant >> 20;
  unsigned e8 = e - 120;
  if(e8 > 15 || (e8 == 15 && m3 == 7)) return (s << 7) | 0x7E;
  return (s << 7) | (e8 << 3) | m3;
}
#endif

template<bool HI>
__device__ __forceinline__ unsigned enc8_pair(float a, float b, unsigned old){
#if HW_FP8
  return __builtin_amdgcn_cvt_pk_fp8_f32(a, b, old, HI);  // HI literal (op_sel)
#else
  unsigned p = enc8_one(a) | (enc8_one(b) << 8);
  return HI ? ((old & 0x0000FFFFu) | (p << 16)) : ((old & 0xFFFF0000u) | p);
#endif
}

__device__ __forceinline__ void dec8x4v(unsigned q, f32x2& lo, f32x2& hi){
#if HW_FP8
  lo = __builtin_amdgcn_cvt_pk_f32_fp8(q, false);
  hi = __builtin_amdgcn_cvt_pk_f32_fp8(q, true);
#else
  auto dec1 = [](unsigned b)->float{
    unsigned s = (b >> 7) & 1, e = (b >> 3) & 15, m = b & 7;
    float v = (e == 0) ? (float)m * 0.001953125f
                       : __uint_as_float(((e + 120) << 23) | (m << 20));
    return s ? -v : v;
  };
  lo[0] = dec1(q & 255); lo[1] = dec1((q >> 8) & 255);
  hi[0] = dec1((q >> 16) & 255); hi[1] = dec1(q >> 24);
#endif
}

// ================= bucket-partitioned CSR build =================
extern "C" __global__ void k_part1(const int* __restrict__ dsts, int E, int N,
                                   int NBUCK, int* __restrict__ bcnt,
                                   int* __restrict__ blockbase){
  __shared__ int hist[512];
  int blk = blockIdx.x, tid = threadIdx.x;
  for(int b = tid; b < NBUCK; b += 256) hist[b] = 0;
  __syncthreads();
  int ET = E + N;
  int chunk = (ET + NBLK_PART - 1)/NBLK_PART;
  int s0 = blk*chunk, s1 = s0+chunk < ET ? s0+chunk : ET;
  for(int e = s0+tid; e < s1; e += 256){
    int d = (e < E) ? dsts[e] : e - E;
    atomicAdd(&hist[d >> BSH], 1);
  }
  __syncthreads();
  for(int b = tid; b < NBUCK; b += 256)
    blockbase[(size_t)blk*NBUCK + b] = atomicAdd(&bcnt[b], hist[b]);
}

extern "C" __global__ void k_bscan(const int* __restrict__ bcnt, int* __restrict__ boffs,
                                   int* __restrict__ offs_last, int NBUCK, int ET){
  __shared__ int sc[512], orig[512];
  int t = threadIdx.x;
  int v = (t < NBUCK) ? bcnt[t] : 0;
  sc[t] = v; orig[t] = v;
  __syncthreads();
  for(int st=1; st<512; st<<=1){
    int u = (t >= st) ? sc[t-st] : 0;
    __syncthreads();
    sc[t] += u;
    __syncthreads();
  }
  if(t < NBUCK) boffs[t] = sc[t] - orig[t];
  if(t == 0){ boffs[NBUCK] = ET; *offs_last = ET; }
}

extern "C" __global__ void k_part2(const int* __restrict__ srcs, const int* __restrict__ dsts,
                                   int E, int N, int NBUCK,
                                   const int* __restrict__ boffs, const int* __restrict__ blockbase,
                                   uint2* __restrict__ pairs){
  __shared__ int cur[512];
  int blk = blockIdx.x, tid = threadIdx.x;
  for(int b = tid; b < NBUCK; b += 256)
    cur[b] = boffs[b] + blockbase[(size_t)blk*NBUCK + b];
  __syncthreads();
  int ET = E + N;
  int chunk = (ET + NBLK_PART - 1)/NBLK_PART;
  int s0 = blk*chunk, s1 = s0+chunk < ET ? s0+chunk : ET;
  for(int e = s0+tid; e < s1; e += 256){
    int s, d;
    if(e < E){ s = srcs[e]; d = dsts[e]; } else { s = d = e - E; }
    int pos = atomicAdd(&cur[d >> BSH], 1);
    uint2 pr; pr.x = (unsigned)d; pr.y = (unsigned)s;
    pairs[pos] = pr;
  }
}

extern "C" __global__ void k_bcsr(const uint2* __restrict__ pairs, const int* __restrict__ boffs,
                                  int N, int* __restrict__ offs, int* __restrict__ csr){
  __shared__ int hist[128], sc[128], lcur[128];
  int b = blockIdx.x, tid = threadIdx.x;
  int node0 = b << BSH;
  int base = boffs[b], endp = boffs[b+1];
  if(tid < 128) hist[tid] = 0;
  __syncthreads();
  for(int i = base + tid; i < endp; i += 256)
    atomicAdd(&hist[pairs[i].x & 127], 1);
  __syncthreads();
  if(tid < 128) sc[tid] = hist[tid];
  __syncthreads();
  for(int st=1; st<128; st<<=1){
    int u = (tid < 128 && tid >= st) ? sc[tid-st] : 0;
    __syncthreads();
    if(tid < 128) sc[tid] += u;
    __syncthreads();
  }
  if(tid < 128){
    int ex = sc[tid] - hist[tid];
    lcur[tid] = ex;
    int n = node0 + tid;
    if(n < N) offs[n] = base + ex;
  }
  __syncthreads();
  for(int i = base + tid; i < endp; i += 256){
    uint2 pr = pairs[i];
    int pos = atomicAdd(&lcur[pr.x & 127], 1);
    csr[base + pos] = (int)pr.y;
  }
}

// ---------------- weight transpose+concat (both layers, one launch) ----------------
extern "C" __global__ void k_wt2(const float* __restrict__ W0, const float* __restrict__ Wr0,
                                 const float* __restrict__ W1, const float* __restrict__ Wr1,
                                 unsigned short* __restrict__ WT0, unsigned short* __restrict__ WT1){
  int idx = blockIdx.x*256 + threadIdx.x;
  const int tot0 = 512*256;
  if(idx < tot0){
    int n = idx >> 8, k = idx & 255;
    const float* W = (n < 256) ? W0 : Wr0;
    int c = (n < 256) ? n : n - 256;
    WT0[idx] = f2b(W[(size_t)k*256 + c]);
  } else {
    idx -= tot0;
    if(idx >= 128*256) return;
    int n = idx >> 8, k = idx & 255;
    const float* W = (n < 64) ? W1 : Wr1;
    int c = (n < 64) ? n : n - 64;
    WT1[idx] = f2b(W[(size_t)k*64 + c]);
  }
}

// ---------------- bf16 MFMA GEMM with LDS-restaged coalesced epilogue ----------------
// mode 0 (layer0): col_blk 0,1 -> fp8 h0q + fused als/ald; col_blk 2,3 -> bf16 r0b.
// mode 1 (layer1): bf16 C (ldc=128) + fp8 g1q (cols<64).
__launch_bounds__(256)
extern "C" __global__ void k_mgemm(const unsigned short* __restrict__ A,
                                   const float* __restrict__ Afp,
                                   const unsigned short* __restrict__ WT,
                                   unsigned short* __restrict__ C, int M,
                                   int MB, int NCB, int mode,
                                   unsigned char* __restrict__ qout,
                                   unsigned short* __restrict__ rout,
                                   const float* __restrict__ as0v, const float* __restrict__ ad0v,
                                   float* __restrict__ alsout, float* __restrict__ aldout){
  int id = blockIdx.x;
  int row_blk, col_blk;
  if(NCB == 4){
    int group = id >> 5;
    int r8 = id & 7;
    col_blk = (id >> 3) & 3;
    row_blk = group*8 + r8;
  } else {
    row_blk = id; col_blk = 0;
  }
  if(row_blk >= MB) return;

  __shared__ unsigned short SH[128*128];   // staging (As|Bs) then C tile
  unsigned short* As = SH;
  unsigned short* Bs = SH + 128*64;
  int t = threadIdx.x;
  int lane = t & 63, wid = t >> 6;
  int wr = wid >> 1, wc = wid & 1;
  int row0 = row_blk*128, col0 = col_blk*128;
  f32x4 acc[4][4] = {};

  // fp32 A path: pipelined reg staging (issue-early / write-late)
  float4 v0s[4], v1s[4];
  const float* abase[4];
  if(Afp){
    #pragma unroll
    for(int i=0; i<4; i++){
      int t2 = i*256 + t;
      int r = t2 >> 3;
      int dslot = (t2 & 7) ^ (r & 7);
      int gr = row0 + r; if(gr >= M) gr = M - 1;
      abase[i] = Afp + (size_t)gr*256 + dslot*8;
      v0s[i] = *(const float4*)(abase[i]);
      v1s[i] = *(const float4*)(abase[i] + 4);
    }
  }

  for(int k0 = 0; k0 < 256; k0 += 64){
    if(Afp){
      #pragma unroll
      for(int i=0; i<4; i++){
        ushort8 o;
        o[0]=f2b(v0s[i].x); o[1]=f2b(v0s[i].y); o[2]=f2b(v0s[i].z); o[3]=f2b(v0s[i].w);
        o[4]=f2b(v1s[i].x); o[5]=f2b(v1s[i].y); o[6]=f2b(v1s[i].z); o[7]=f2b(v1s[i].w);
        *(ushort8*)(As + i*2048 + wid*512 + lane*8) = o;
      }
    } else {
      #pragma unroll
      for(int i=0; i<4; i++){
        int t2 = i*256 + t;
        int r = t2 >> 3;
        int dslot = (t2 & 7) ^ (r & 7);
        int gr = row0 + r; if(gr >= M) gr = M - 1;
        const unsigned short* ga = A + (size_t)gr*256 + k0 + dslot*8;
        __builtin_amdgcn_global_load_lds((const __attribute__((address_space(1))) unsigned*)ga,
            (__attribute__((address_space(3))) unsigned*)(As + i*2048 + wid*512), 16, 0, 0);
      }
    }
    #pragma unroll
    for(int i=0; i<4; i++){
      int t2 = i*256 + t;
      int r = t2 >> 3;
      int dslot = (t2 & 7) ^ (r & 7);
      const unsigned short* gb = WT + (size_t)(col0 + r)*256 + k0 + dslot*8;
      __builtin_amdgcn_global_load_lds((const __attribute__((address_space(1))) unsigned*)gb,
          (__attribute__((address_space(3))) unsigned*)(Bs + i*2048 + wid*512), 16, 0, 0);
    }
    __syncthreads();
    if(Afp && k0 < 192){
      #pragma unroll
      for(int i=0; i<4; i++){
        v0s[i] = *(const float4*)(abase[i] + k0 + 64);
        v1s[i] = *(const float4*)(abase[i] + k0 + 68);
      }
    }
    #pragma unroll
    for(int kc=0; kc<2; kc++){
      bf16x8 a[4], b[4];
      int kb = kc*4 + (lane >> 4);
      #pragma unroll
      for(int f=0; f<4; f++){
        int ar = wr*64 + f*16 + (lane & 15);
        a[f] = *(const bf16x8*)&As[ar*64 + ((kb ^ (ar & 7))*8)];
        int br = wc*64 + f*16 + (lane & 15);
        b[f] = *(const bf16x8*)&Bs[br*64 + ((kb ^ (br & 7))*8)];
      }
      #pragma unroll
      for(int fm=0; fm<4; fm++)
        #pragma unroll
        for(int fn=0; fn<4; fn++)
          acc[fm][fn] = __builtin_amdgcn_mfma_f32_16x16x32_bf16(a[fm], b[fn], acc[fm][fn], 0, 0, 0);
    }
    __syncthreads();
  }

  // ---- epilogue: restage C tile (bf16) through LDS for coalesced output ----
  #pragma unroll
  for(int fm=0; fm<4; fm++){
    int rl = wr*64 + fm*16 + ((lane>>4)<<2);
    #pragma unroll
    for(int r=0; r<4; r++)
      #pragma unroll
      for(int fn=0; fn<4; fn++)
        SH[(rl+r)*128 + wc*64 + (lane&15) + fn*16] = f2b(acc[fm][fn][r]);
  }
  __syncthreads();

  int cg = t & 15;                 // col group (8 cols each)
  if(mode == 0){
    bool attn = col_blk < 2;       // cols 0..255 = h0 (heads); 256..511 = r0
    int colbase = col0 + cg*8;
    float4 as_lo, as_hi, ad_lo, ad_hi;
    if(attn){
      as_lo = *(const float4*)(as0v + colbase);
      as_hi = *(const float4*)(as0v + colbase + 4);
      ad_lo = *(const float4*)(ad0v + colbase);
      ad_hi = *(const float4*)(ad0v + colbase + 4);
    }
    #pragma unroll
    for(int it=0; it<8; it++){
      int rl = it*16 + (t>>4);
      int row = row0 + rl;
      ushort8 vr = *(ushort8*)&SH[rl*128 + cg*8];
      if(attn){
        float f0=b2f(vr[0]),f1=b2f(vr[1]),f2=b2f(vr[2]),f3=b2f(vr[3]);
        float f4=b2f(vr[4]),f5=b2f(vr[5]),f6=b2f(vr[6]),f7=b2f(vr[7]);
        float sd = f0*as_lo.x+f1*as_lo.y+f2*as_lo.z+f3*as_lo.w
                 + f4*as_hi.x+f5*as_hi.y+f6*as_hi.z+f7*as_hi.w;
        float dd = f0*ad_lo.x+f1*ad_lo.y+f2*ad_lo.z+f3*ad_lo.w
                 + f4*ad_hi.x+f5*ad_hi.y+f6*ad_hi.z+f7*ad_hi.w;
        sd += __shfl_xor(sd,1); sd += __shfl_xor(sd,2);   // 4 lanes = 32 cols = 1 head
        dd += __shfl_xor(dd,1); dd += __shfl_xor(dd,2);
        uint2 q;
        q.x = enc8_pair<false>(f0,f1,0u); q.x = enc8_pair<true>(f2,f3,q.x);
        q.y = enc8_pair<false>(f4,f5,0u); q.y = enc8_pair<true>(f6,f7,q.y);
        if(row < M){
          *(uint2*)(qout + (size_t)row*256 + colbase) = q;
          if((lane&3)==0){
            int head = colbase >> 5;
            alsout[row*8 + head] = sd;
            aldout[row*8 + head] = dd;
          }
        }
      } else {
        if(row < M)
          *(ushort8*)(rout + (size_t)row*256 + (colbase - 256)) = vr;
      }
    }
  } else {
    #pragma unroll
    for(int it=0; it<8; it++){
      int rl = it*16 + (t>>4);
      int row = row0 + rl;
      ushort8 vr = *(ushort8*)&SH[rl*128 + cg*8];
      if(row < M){
        *(ushort8*)(C + (size_t)row*128 + cg*8) = vr;
        if(cg < 8){
          float f0=b2f(vr[0]),f1=b2f(vr[1]),f2=b2f(vr[2]),f3=b2f(vr[3]);
          float f4=b2f(vr[4]),f5=b2f(vr[5]),f6=b2f(vr[6]),f7=b2f(vr[7]);
          uint2 q;
          q.x = enc8_pair<false>(f0,f1,0u); q.x = enc8_pair<true>(f2,f3,q.x);
          q.y = enc8_pair<false>(f4,f5,0u); q.y = enc8_pair<true>(f6,f7,q.y);
          *(uint2*)(qout + (size_t)row*64 + cg*8) = q;
        }
      }
    }
  }
}

// ---- gather layer0: WAVE-per-node, zero LDS / zero barriers ----
__launch_bounds__(256)
extern "C" __global__ void k_gather0(const unsigned short* __restrict__ r0b,
                                     const unsigned char* __restrict__ h0q,
                                     const float* __restrict__ als0, const float* __restrict__ ald0,
                                     const int* __restrict__ offs, const int* __restrict__ csr,
                                     const float* __restrict__ b0, const float* __restrict__ br0,
                                     unsigned short* __restrict__ h1b, int N){
  int n = blockIdx.x*4 + (threadIdx.x >> 6);
  if(n >= N) return;
  int lane = threadIdx.x & 63;
  int hh = lane & 7;
  int es = lane >> 3;
  int h  = es;
  int c  = lane*4;
  float ald_h = ald0[n*8 + hh];
  int beg = offs[n], end = offs[n+1];

  f32x2 A01 = {0.f, 0.f}, A23 = {0.f, 0.f};
  float den = 0.f;

  for(int chunk = beg; chunk < end; chunk += 8){
    int m = end - chunk; if(m > 8) m = 8;
    bool e_ok = es < m;
    int s = e_ok ? csr[chunk + es] : 0;
    float p = 0.f;
    if(e_ok){
      float v = als0[s*8 + hh] + ald_h;
      v = v > 0.f ? v : NEG_SLOPE*v;
      p = expf(v);
    }
    den += p;
    int sj[8]; float pj[8];
    #pragma unroll
    for(int j=0; j<8; j++){
      sj[j] = __shfl(s, j*8);
      pj[j] = __shfl(p, j*8 + h);
    }
    unsigned q[8];
    #pragma unroll
    for(int j=0; j<8; j++)
      q[j] = *(const unsigned*)(h0q + (size_t)sj[j]*256 + c);
    #pragma unroll
    for(int j=0; j<8; j++){
      f32x2 lo, hi, pv;
      dec8x4v(q[j], lo, hi);
      pv[0] = pj[j]; pv[1] = pj[j];
      A01 += pv*lo; A23 += pv*hi;
    }
  }

  den += __shfl_xor(den, 8);
  den += __shfl_xor(den, 16);
  den += __shfl_xor(den, 32);
  float rden = 1.f/(den + 1e-16f);
  rden = __shfl(rden, h);

  float a0 = A01[0]*rden, a1 = A01[1]*rden, a2 = A23[0]*rden, a3 = A23[1]*rden;

  float4 bb = *(const float4*)(b0 + c);
  float4 rb = *(const float4*)(br0 + c);
  uint2 ru = *(const uint2*)(r0b + (size_t)n*256 + c);
  float o0 = a0 + bb.x + __uint_as_float(ru.x << 16)         + rb.x;
  float o1 = a1 + bb.y + __uint_as_float(ru.x & 0xFFFF0000u) + rb.y;
  float o2 = a2 + bb.z + __uint_as_float(ru.y << 16)         + rb.z;
  float o3 = a3 + bb.w + __uint_as_float(ru.y & 0xFFFF0000u) + rb.w;
  ushort4v o;
  o[0] = f2b(o0 > 0.f ? o0 : expf(o0) - 1.f);
  o[1] = f2b(o1 > 0.f ? o1 : expf(o1) - 1.f);
  o[2] = f2b(o2 > 0.f ? o2 : expf(o2) - 1.f);
  o[3] = f2b(o3 > 0.f ? o3 : expf(o3) - 1.f);
  *(ushort4v*)(h1b + (size_t)n*256 + c) = o;
}

// ---------------- layer1 logits (bf16 g1) ----------------
extern "C" __global__ void k_al1(const unsigned short* __restrict__ buf1b, const float* __restrict__ as1,
                                 const float* __restrict__ ad1, float* als1, float* ald1, int N){
  int n = blockIdx.x*4 + (threadIdx.x >> 6);
  if(n >= N) return;
  int lane = threadIdx.x & 63;
  float g = b2f(buf1b[(size_t)n*128 + lane]);
  float s = g*as1[lane], d = g*ad1[lane];
  #pragma unroll
  for(int o=32; o>0; o>>=1){ s += __shfl_xor(s,o); d += __shfl_xor(d,o); }
  if(lane == 0){ als1[n] = s; ald1[n] = d; }
}

// ---- gather layer1: WAVE-per-node over fp8 g1; 4 channels/lane, 4 edge slots ----
__launch_bounds__(256)
extern "C" __global__ void k_gather1(const unsigned short* __restrict__ buf1b,
                                     const unsigned char* __restrict__ g1q,
                                     const float* __restrict__ als1, const float* __restrict__ ald1,
                                     const int* __restrict__ offs, const int* __restrict__ csr,
                                     const float* __restrict__ b1, const float* __restrict__ br1,
                                     float* __restrict__ out, int N){
  int n = blockIdx.x*4 + (threadIdx.x >> 6);
  if(n >= N) return;
  int lane = threadIdx.x & 63;
  int ch4 = lane & 15;
  int es  = lane >> 4;
  int c   = ch4*4;
  int beg = offs[n], end = offs[n+1];
  float ald_n = ald1[n];

  f32x2 A01 = {0.f, 0.f}, A23 = {0.f, 0.f};
  float den = 0.f;

  for(int chunk = beg; chunk < end; chunk += 64){
    int m = end - chunk; if(m > 64) m = 64;
    int s = (lane < m) ? csr[chunk + lane] : 0;
    float p = 0.f;
    if(lane < m){
      float v = als1[s] + ald_n;
      v = v > 0.f ? v : NEG_SLOPE*v;
      p = expf(v);
    }
    den += p;
    for(int base = 0; base < m; base += 16){
      int sv[4]; float pv[4];
      #pragma unroll
      for(int i=0; i<4; i++){
        int j = base + 4*i + es;
        int jj = j & 63;
        sv[i] = __shfl(s, jj);
        pv[i] = __shfl(p, jj);
      }
      unsigned qv[4];
      #pragma unroll
      for(int i=0; i<4; i++)
        qv[i] = *(const unsigned*)(g1q + (size_t)sv[i]*64 + c);
      #pragma unroll
      for(int i=0; i<4; i++){
        f32x2 lo, hi, pp;
        dec8x4v(qv[i], lo, hi);
        pp[0] = pv[i]; pp[1] = pv[i];
        A01 += pp*lo; A23 += pp*hi;
      }
    }
  }

  A01[0] += __shfl_xor(A01[0], 16); A01[1] += __shfl_xor(A01[1], 16);
  A23[0] += __shfl_xor(A23[0], 16); A23[1] += __shfl_xor(A23[1], 16);
  A01[0] += __shfl_xor(A01[0], 32); A01[1] += __shfl_xor(A01[1], 32);
  A23[0] += __shfl_xor(A23[0], 32); A23[1] += __shfl_xor(A23[1], 32);
  #pragma unroll
  for(int o=32; o>0; o>>=1) den += __shfl_xor(den, o);
  float rden = 1.f/(den + 1e-16f);

  float4 bb = *(const float4*)(b1 + c);
  float4 rb = *(const float4*)(br1 + c);
  uint2 ru = *(const uint2*)(buf1b + (size_t)n*128 + 64 + c);
  float v0 = A01[0]*rden + bb.x + __uint_as_float(ru.x << 16)         + rb.x;
  float v1 = A01[1]*rden + bb.y + __uint_as_float(ru.x & 0xFFFF0000u) + rb.y;
  float v2 = A23[0]*rden + bb.z + __uint_as_float(ru.y << 16)         + rb.z;
  float v3 = A23[1]*rden + bb.w + __uint_as_float(ru.y & 0xFFFF0000u) + rb.w;

  float mx = fmaxf(fmaxf(v0, v1), fmaxf(v2, v3));
  #pragma unroll
  for(int o=1; o<16; o<<=1) mx = fmaxf(mx, __shfl_xor(mx, o));
  float sm = expf(v0-mx) + expf(v1-mx) + expf(v2-mx) + expf(v3-mx);
  #pragma unroll
  for(int o=1; o<16; o<<=1) sm += __shfl_xor(sm, o);
  float l = mx + logf(sm);
  if(es == 0){
    float4 ov; ov.x = v0-l; ov.y = v1-l; ov.z = v2-l; ov.w = v3-l;
    *(float4*)(out + (size_t)n*64 + c) = ov;
  }
}

// ---------------- launch ----------------
extern "C" void kernel_launch(void* const* d_in, const int* in_sizes, int n_in,
                              void* d_out, int out_size, void* d_ws, size_t ws_size,
                              hipStream_t stream){
  const float* x   = (const float*)d_in[0];
  const int*   ei  = (const int*)  d_in[1];
  const float* W0  = (const float*)d_in[2];
  const float* as0 = (const float*)d_in[3];
  const float* ad0 = (const float*)d_in[4];
  const float* b0  = (const float*)d_in[5];
  const float* Wr0 = (const float*)d_in[6];
  const float* br0 = (const float*)d_in[7];
  const float* W1  = (const float*)d_in[8];
  const float* as1 = (const float*)d_in[9];
  const float* ad1 = (const float*)d_in[10];
  const float* b1  = (const float*)d_in[11];
  const float* Wr1 = (const float*)d_in[12];
  const float* br1 = (const float*)d_in[13];
  int N = in_sizes[0] / 256;
  int E = in_sizes[1] / 2;
  const int* srcs = ei;
  const int* dsts = ei + E;
  float* out = (float*)d_out;

  int ET = E + N;
  int NBUCK = (N + 127) >> BSH;

  // workspace layout
  unsigned short* r0b   = (unsigned short*)d_ws;        // N*256 bf16 (residual r0)
  unsigned char*  h0q   = (unsigned char*)(r0b + (size_t)N*256);  // N*256 fp8
  unsigned short* h1b   = (unsigned short*)(h0q + (size_t)N*256); // N*256 bf16
  unsigned short* buf1b = h1b + (size_t)N*256;          // N*128 bf16 (g1 | r1)
  unsigned short* WT0   = buf1b + (size_t)N*128;        // 512*256 bf16
  unsigned short* WT1   = WT0   + 512*256;              // 128*256 bf16
  float*    als0 = (float*)(WT1 + 128*256);             // N*8
  float*    ald0 = als0 + (size_t)N*8;                  // N*8
  float*    als1 = ald0 + (size_t)N*8;                  // N
  float*    ald1 = als1 + N;                            // N
  int*      offs = (int*)(ald1 + N);                    // N+1
  int*      bcnt = offs + N + 1;                        // NBUCK
  int*      boffs = bcnt + NBUCK;                       // NBUCK+1
  int*      blockbase = boffs + NBUCK + 1;              // NBLK_PART*NBUCK
  int*      csr  = blockbase + (size_t)NBLK_PART*NBUCK; // ET
  uint2*    pairs = (uint2*)(csr + ET);
  pairs = (uint2*)(((uintptr_t)pairs + 7) & ~(uintptr_t)7);
  unsigned char* g1q = (unsigned char*)(pairs + ET);    // N*64 bytes

  // ---- CSR build: bucket partition ----
  hipMemsetAsync(bcnt, 0, (size_t)NBUCK*sizeof(int), stream);
  hipLaunchKernelGGL(k_part1, dim3(NBLK_PART), dim3(256), 0, stream, dsts, E, N, NBUCK, bcnt, blockbase);
  hipLaunchKernelGGL(k_bscan, dim3(1), dim3(512), 0, stream, bcnt, boffs, offs + N, NBUCK, ET);
  hipLaunchKernelGGL(k_part2, dim3(NBLK_PART), dim3(256), 0, stream, srcs, dsts, E, N, NBUCK, boffs, blockbase, pairs);
  hipLaunchKernelGGL(k_bcsr, dim3(NBUCK), dim3(256), 0, stream, pairs, boffs, N, offs, csr);

  // weight prep
  hipLaunchKernelGGL(k_wt2, dim3((512*256+128*256+255)/256), dim3(256), 0, stream, W0, Wr0, W1, Wr1, WT0, WT1);

  int MB = (N + 127) / 128;
  int g0 = ((MB + 7) / 8) * 32;
  // layer0: x(fp32) @ [W0|Wr0] -> fp8 h0q + bf16 r0b + fused als0/ald0
  hipLaunchKernelGGL(k_mgemm, dim3(g0), dim3(256), 0, stream,
                     (const unsigned short*)nullptr, x, WT0,
                     (unsigned short*)nullptr, N, MB, 4, 0,
                     h0q, r0b, as0, ad0, als0, ald0);
  hipLaunchKernelGGL(k_gather0, dim3((N+3)/4), dim3(256), 0, stream, r0b, h0q, als0, ald0, offs, csr, b0, br0, h1b, N);

  // layer1: h1b @ [W1|Wr1] -> bf16 buf1b + fp8 g1q
  hipLaunchKernelGGL(k_mgemm, dim3(MB), dim3(256), 0, stream,
                     h1b, (const float*)nullptr, WT1,
                     buf1b, N, MB, 1, 1,
                     g1q, (unsigned short*)nullptr,
                     (const float*)nullptr, (const float*)nullptr,
                     (float*)nullptr, (float*)nullptr);
  hipLaunchKernelGGL(k_al1, dim3((N+3)/4), dim3(256), 0, stream, buf1b, as1, ad1, als1, ald1, N);
  hipLaunchKernelGGL(k_gather1, dim3((N+3)/4), dim3(256), 0, stream, buf1b, g1q, als1, ald1, offs, csr, b1, br1, out, N);
}